// Round 1
// baseline (1073.084 us; speedup 1.0000x reference)
//
#include <hip/hip_runtime.h>
#include <hip/hip_bf16.h>

#define DI __device__ __forceinline__

constexpr int B_ = 16, N_ = 4096, C_ = 256, H_ = 4;
constexpr size_t QSZ = (size_t)4096 * 4096;   // elements in one [4096][4096] bf16 plane

DI float bfu2f(unsigned short u) { return __uint_as_float(((unsigned)u) << 16); }
DI void bfu2x2(unsigned u, float& lo, float& hi) {
  lo = __uint_as_float(u << 16);
  hi = __uint_as_float(u & 0xffff0000u);
}
DI unsigned short f2bfu(float f) {   // RNE f32->bf16 (finite inputs)
  unsigned u = __float_as_uint(f);
  unsigned r = 0x7fffu + ((u >> 16) & 1u);
  return (unsigned short)((u + r) >> 16);
}

// ---------------------------------------------------------------------------
// Projection GEMM: out = A[M,256] @ W[ncols,256]^T + bias, written transposed
// to bf16 channel-major planes: row = (j>>8)*4096 + b*256 + (j&255), col = n.
// grid = (M/64, ncols/64), block = 256.
// ---------------------------------------------------------------------------
__global__ __launch_bounds__(256) void gemm_proj(
    const float* __restrict__ A, const float* __restrict__ W,
    const float* __restrict__ bias, unsigned short* __restrict__ outT)
{
  __shared__ float As[32][65];
  __shared__ float Bs[32][65];
  const int tid = threadIdx.x;
  const int tx = tid & 15, ty = tid >> 4;
  const int m0 = blockIdx.x * 64;
  const int j0 = blockIdx.y * 64;
  float acc[4][4] = {};
  for (int k0 = 0; k0 < 256; k0 += 32) {
#pragma unroll
    for (int i = 0; i < 2; ++i) {
      const int idx = tid + i * 256;
      const int r = idx >> 3;
      const int kv = (idx & 7) << 2;
      const float4 av = *reinterpret_cast<const float4*>(&A[(size_t)(m0 + r) * 256 + k0 + kv]);
      As[kv + 0][r] = av.x; As[kv + 1][r] = av.y; As[kv + 2][r] = av.z; As[kv + 3][r] = av.w;
      const float4 wv = *reinterpret_cast<const float4*>(&W[(size_t)(j0 + r) * 256 + k0 + kv]);
      Bs[kv + 0][r] = wv.x; Bs[kv + 1][r] = wv.y; Bs[kv + 2][r] = wv.z; Bs[kv + 3][r] = wv.w;
    }
    __syncthreads();
#pragma unroll
    for (int kk = 0; kk < 32; ++kk) {
      float a[4], b[4];
#pragma unroll
      for (int i = 0; i < 4; ++i) a[i] = As[kk][ty * 4 + i];
#pragma unroll
      for (int j = 0; j < 4; ++j) b[j] = Bs[kk][tx * 4 + j];
#pragma unroll
      for (int i = 0; i < 4; ++i)
#pragma unroll
        for (int j = 0; j < 4; ++j) acc[i][j] += a[i] * b[j];
    }
    __syncthreads();
  }
  const int b_idx = m0 >> 12;            // batch
  const int n0 = (m0 & 4095) + ty * 4;   // token
#pragma unroll
  for (int j = 0; j < 4; ++j) {
    const int jj = j0 + tx * 4 + j;
    const float bv = bias[jj];
    const int rowT = ((jj >> 8) * B_ + b_idx) * 256 + (jj & 255);
    union { ushort4 v; unsigned short u[4]; } pk;
#pragma unroll
    for (int i = 0; i < 4; ++i) pk.u[i] = f2bfu(acc[i][j] + bv);
    *reinterpret_cast<ushort4*>(&outT[(size_t)rowT * N_ + n0]) = pk.v;
  }
}

// ---------------------------------------------------------------------------
// Per-channel 1/max(||row||,eps) over N tokens. blocks 0..4095 -> qT rows,
// 4096..8191 -> kT rows.
// ---------------------------------------------------------------------------
__global__ __launch_bounds__(256) void norm_kernel(
    const unsigned short* __restrict__ qT, const unsigned short* __restrict__ kT,
    float* __restrict__ rq, float* __restrict__ rk)
{
  const int row = blockIdx.x;
  const unsigned short* src = (row < 4096) ? (qT + (size_t)row * N_)
                                           : (kT + (size_t)(row - 4096) * N_);
  float s = 0.f;
  for (int i = threadIdx.x; i < N_ / 8; i += 256) {
    const uint4 u = *reinterpret_cast<const uint4*>(&src[i * 8]);
    float a, b;
    bfu2x2(u.x, a, b); s += a * a + b * b;
    bfu2x2(u.y, a, b); s += a * a + b * b;
    bfu2x2(u.z, a, b); s += a * a + b * b;
    bfu2x2(u.w, a, b); s += a * a + b * b;
  }
#pragma unroll
  for (int off = 32; off > 0; off >>= 1) s += __shfl_xor(s, off);
  __shared__ float ws4[4];
  if ((threadIdx.x & 63) == 0) ws4[threadIdx.x >> 6] = s;
  __syncthreads();
  if (threadIdx.x == 0) {
    const float tot = ws4[0] + ws4[1] + ws4[2] + ws4[3];
    const float r = 1.f / fmaxf(sqrtf(tot), 1e-12f);
    (row < 4096 ? rq : rk)[row & 4095] = r;
  }
}

DI void store16(float (*dst)[68], int seg, int col, uint4 u0, uint4 u1) {
  float lo, hi;
  const int r = seg * 16;
  bfu2x2(u0.x, lo, hi); dst[r + 0][col] = lo;  dst[r + 1][col] = hi;
  bfu2x2(u0.y, lo, hi); dst[r + 2][col] = lo;  dst[r + 3][col] = hi;
  bfu2x2(u0.z, lo, hi); dst[r + 4][col] = lo;  dst[r + 5][col] = hi;
  bfu2x2(u0.w, lo, hi); dst[r + 6][col] = lo;  dst[r + 7][col] = hi;
  bfu2x2(u1.x, lo, hi); dst[r + 8][col] = lo;  dst[r + 9][col] = hi;
  bfu2x2(u1.y, lo, hi); dst[r + 10][col] = lo; dst[r + 11][col] = hi;
  bfu2x2(u1.z, lo, hi); dst[r + 12][col] = lo; dst[r + 13][col] = hi;
  bfu2x2(u1.w, lo, hi); dst[r + 14][col] = lo; dst[r + 15][col] = hi;
}

// ---------------------------------------------------------------------------
// Fused per-(b,h) 64x64 stats over token chunks: S=q·k^T, Kp=k·WE^T, Vp=v·WE^T.
// grid = (64 bh, 8 chunks); partials to part[chunk][bh][3][64][64].
// ---------------------------------------------------------------------------
__global__ __launch_bounds__(256) void stats_kernel(
    const unsigned short* __restrict__ qT, const unsigned short* __restrict__ kT,
    const unsigned short* __restrict__ vT, const float* __restrict__ WE,
    float* __restrict__ part)
{
  __shared__ float qs[64][68], ks[64][68], vs[64][68], ws[64][68];
  const int tid = threadIdx.x;
  const int bh = blockIdx.x, chunk = blockIdx.y;
  const int tx = tid & 15, ty = tid >> 4;
  const int lrow = tid >> 2, seg = tid & 3;
  float as[4][4] = {}, ak[4][4] = {}, av[4][4] = {};
  const size_t rbase = (size_t)(bh * 64 + lrow) * N_;
  for (int sub = 0; sub < 8; ++sub) {
    const int nn = chunk * 512 + sub * 64 + seg * 16;
    {
      uint4 u0 = *reinterpret_cast<const uint4*>(&qT[rbase + nn]);
      uint4 u1 = *reinterpret_cast<const uint4*>(&qT[rbase + nn + 8]);
      store16(qs, seg, lrow, u0, u1);
      u0 = *reinterpret_cast<const uint4*>(&kT[rbase + nn]);
      u1 = *reinterpret_cast<const uint4*>(&kT[rbase + nn + 8]);
      store16(ks, seg, lrow, u0, u1);
      u0 = *reinterpret_cast<const uint4*>(&vT[rbase + nn]);
      u1 = *reinterpret_cast<const uint4*>(&vT[rbase + nn + 8]);
      store16(vs, seg, lrow, u0, u1);
      const float* wrow = &WE[(size_t)lrow * N_ + nn];
#pragma unroll
      for (int t = 0; t < 4; ++t) {
        const float4 f = *reinterpret_cast<const float4*>(&wrow[t * 4]);
        const int r = seg * 16 + t * 4;
        ws[r + 0][lrow] = f.x; ws[r + 1][lrow] = f.y;
        ws[r + 2][lrow] = f.z; ws[r + 3][lrow] = f.w;
      }
    }
    __syncthreads();
#pragma unroll 8
    for (int kk = 0; kk < 64; ++kk) {
      float qr[4], kr[4], vr[4], kc[4], wc[4];
#pragma unroll
      for (int i = 0; i < 4; ++i) {
        qr[i] = qs[kk][ty * 4 + i];
        kr[i] = ks[kk][ty * 4 + i];
        vr[i] = vs[kk][ty * 4 + i];
        kc[i] = ks[kk][tx * 4 + i];
        wc[i] = ws[kk][tx * 4 + i];
      }
#pragma unroll
      for (int i = 0; i < 4; ++i)
#pragma unroll
        for (int j = 0; j < 4; ++j) {
          as[i][j] += qr[i] * kc[j];
          ak[i][j] += kr[i] * wc[j];
          av[i][j] += vr[i] * wc[j];
        }
    }
    __syncthreads();
  }
  float* base = &part[((size_t)chunk * 64 + bh) * 12288];
#pragma unroll
  for (int i = 0; i < 4; ++i) {
    const int r = ty * 4 + i;
    *reinterpret_cast<float4*>(&base[r * 64 + tx * 4]) =
        make_float4(as[i][0], as[i][1], as[i][2], as[i][3]);
    *reinterpret_cast<float4*>(&base[4096 + r * 64 + tx * 4]) =
        make_float4(ak[i][0], ak[i][1], ak[i][2], ak[i][3]);
    *reinterpret_cast<float4*>(&base[8192 + r * 64 + tx * 4]) =
        make_float4(av[i][0], av[i][1], av[i][2], av[i][3]);
  }
}

// ---------------------------------------------------------------------------
// Reduce partials; emit kp' = rk*Kp + bE, vp' = Vp + bE, and channel-attention
// softmax attn_t[bh][d][c] = softmax_d(S*rq[c]*rk[d]*temp[h]). grid = 64.
// ---------------------------------------------------------------------------
__global__ __launch_bounds__(256) void postproc_kernel(
    const float* __restrict__ part, const float* __restrict__ rq,
    const float* __restrict__ rk, const float* __restrict__ bE,
    const float* __restrict__ temp, float* __restrict__ attn_t,
    float* __restrict__ kp, float* __restrict__ vp)
{
  __shared__ float sums[12288];
  const int bh = blockIdx.x;
  const int tid = threadIdx.x;
  for (int idx = tid; idx < 12288; idx += 256) {
    float s = 0.f;
    for (int ch = 0; ch < 8; ++ch)
      s += part[((size_t)ch * 64 + bh) * 12288 + idx];
    sums[idx] = s;
  }
  __syncthreads();
  for (int idx = tid; idx < 4096; idx += 256) {
    const int c = idx >> 6, p = idx & 63;
    kp[(size_t)bh * 4096 + idx] = sums[4096 + idx] * rk[bh * 64 + c] + bE[p];
    vp[(size_t)bh * 4096 + idx] = sums[8192 + idx] + bE[p];
  }
  const float tv = temp[bh & 3];
  const int lane = tid & 63, wv = tid >> 6;
  for (int ri = 0; ri < 16; ++ri) {
    const int c = wv * 16 + ri;
    const float val = sums[c * 64 + lane] * rq[bh * 64 + c] * rk[bh * 64 + lane] * tv;
    float m = val;
#pragma unroll
    for (int off = 32; off > 0; off >>= 1) m = fmaxf(m, __shfl_xor(m, off));
    const float e = __expf(val - m);
    float ssum = e;
#pragma unroll
    for (int off = 32; off > 0; off >>= 1) ssum += __shfl_xor(ssum, off);
    attn_t[(size_t)bh * 4096 + lane * 64 + c] = e / ssum;   // [d][c]
  }
}

// ---------------------------------------------------------------------------
// x_ca[c][n] = sum_d attn[c][d] * v_ca[d][n], written to [B,N,C] bf16.
// grid = (64 bh, 32 ntiles of 128).
// ---------------------------------------------------------------------------
__global__ __launch_bounds__(256) void xca_kernel(
    const float* __restrict__ attn_t, const unsigned short* __restrict__ vT,
    unsigned short* __restrict__ x_ca)
{
  __shared__ float at[64][68];
  __shared__ float vt[64][132];
  const int tid = threadIdx.x;
  const int bh = blockIdx.x, b = bh >> 2, h = bh & 3;
  const int n0 = blockIdx.y * 128;
  for (int i = tid; i < 1024; i += 256) {
    const float4 f = *reinterpret_cast<const float4*>(&attn_t[(size_t)bh * 4096 + i * 4]);
    *reinterpret_cast<float4*>(&at[i >> 4][(i * 4) & 63]) = f;
  }
  {
    const int d = tid >> 2, seg = tid & 3;
    const size_t rb = (size_t)(bh * 64 + d) * N_ + n0 + seg * 32;
#pragma unroll
    for (int t = 0; t < 4; ++t) {
      const uint4 u = *reinterpret_cast<const uint4*>(&vT[rb + t * 8]);
      float lo, hi;
      const int c0 = seg * 32 + t * 8;
      bfu2x2(u.x, lo, hi); vt[d][c0 + 0] = lo; vt[d][c0 + 1] = hi;
      bfu2x2(u.y, lo, hi); vt[d][c0 + 2] = lo; vt[d][c0 + 3] = hi;
      bfu2x2(u.z, lo, hi); vt[d][c0 + 4] = lo; vt[d][c0 + 5] = hi;
      bfu2x2(u.w, lo, hi); vt[d][c0 + 6] = lo; vt[d][c0 + 7] = hi;
    }
  }
  __syncthreads();
  const int cg = tid & 7, ng = tid >> 3;
  const int c0 = cg * 8, nl0 = ng * 4;
  float acc[4][8] = {};
  for (int d = 0; d < 64; ++d) {
    float a[8];
    *reinterpret_cast<float4*>(&a[0]) = *reinterpret_cast<const float4*>(&at[d][c0]);
    *reinterpret_cast<float4*>(&a[4]) = *reinterpret_cast<const float4*>(&at[d][c0 + 4]);
    const float4 vv = *reinterpret_cast<const float4*>(&vt[d][nl0]);
    const float vn[4] = {vv.x, vv.y, vv.z, vv.w};
#pragma unroll
    for (int n = 0; n < 4; ++n)
#pragma unroll
      for (int c = 0; c < 8; ++c) acc[n][c] += vn[n] * a[c];
  }
#pragma unroll
  for (int n = 0; n < 4; ++n) {
    union { uint4 v; unsigned short u[8]; } pk;
#pragma unroll
    for (int c = 0; c < 8; ++c) pk.u[c] = f2bfu(acc[n][c]);
    const int nn = n0 + nl0 + n;
    *reinterpret_cast<uint4*>(&x_ca[((size_t)b * N_ + nn) * 256 + h * 64 + c0]) = pk.v;
  }
}

// ---------------------------------------------------------------------------
// Spatial attention: per token, scores[p]=sum_c qn[c,n]*kp[c][p]; softmax_p;
// x_sa_t[b][d][h][n] = sum_p attn[p]*vp[d][p].  grid = (64 bh, 16 ntiles).
// ---------------------------------------------------------------------------
__global__ __launch_bounds__(256) void sa_kernel(
    const unsigned short* __restrict__ qT, const float* __restrict__ rq,
    const float* __restrict__ kp, const float* __restrict__ vp,
    const float* __restrict__ temp2, unsigned short* __restrict__ x_sa)
{
  __shared__ float kps[64][68];
  __shared__ float vps[64][68];
  __shared__ float rqs[64];
  const int tid = threadIdx.x;
  const int bh = blockIdx.x, b = bh >> 2, h = bh & 3;
  const int n = blockIdx.y * 256 + tid;
  for (int i = tid; i < 1024; i += 256) {
    const int r = i >> 4, c = (i * 4) & 63;
    *reinterpret_cast<float4*>(&kps[r][c]) =
        *reinterpret_cast<const float4*>(&kp[(size_t)bh * 4096 + i * 4]);
    *reinterpret_cast<float4*>(&vps[r][c]) =
        *reinterpret_cast<const float4*>(&vp[(size_t)bh * 4096 + i * 4]);
  }
  if (tid < 64) rqs[tid] = rq[bh * 64 + tid];
  __syncthreads();
  float sc[64];
#pragma unroll
  for (int p = 0; p < 64; ++p) sc[p] = 0.f;
  const size_t qcol = (size_t)(bh * 64) * N_ + n;
  for (int c = 0; c < 64; ++c) {
    const float qv = bfu2f(qT[qcol + (size_t)c * N_]) * rqs[c];
#pragma unroll
    for (int p4 = 0; p4 < 16; ++p4) {
      const float4 kv = *reinterpret_cast<const float4*>(&kps[c][p4 * 4]);
      sc[p4 * 4 + 0] += qv * kv.x;
      sc[p4 * 4 + 1] += qv * kv.y;
      sc[p4 * 4 + 2] += qv * kv.z;
      sc[p4 * 4 + 3] += qv * kv.w;
    }
  }
  const float t2 = temp2[h];
  float mx = -1e30f;
#pragma unroll
  for (int p = 0; p < 64; ++p) { sc[p] *= t2; mx = fmaxf(mx, sc[p]); }
  float ssum = 0.f;
#pragma unroll
  for (int p = 0; p < 64; ++p) { sc[p] = __expf(sc[p] - mx); ssum += sc[p]; }
  const float inv = 1.f / ssum;
  for (int d = 0; d < 64; ++d) {
    float o = 0.f;
#pragma unroll
    for (int p4 = 0; p4 < 16; ++p4) {
      const float4 vv = *reinterpret_cast<const float4*>(&vps[d][p4 * 4]);
      o += sc[p4 * 4 + 0] * vv.x + sc[p4 * 4 + 1] * vv.y +
           sc[p4 * 4 + 2] * vv.z + sc[p4 * 4 + 3] * vv.w;
    }
    x_sa[((size_t)(b * 64 + d) * 4 + h) * N_ + n] = f2bfu(o * inv);
  }
}

// ---------------------------------------------------------------------------
// Output projections: z=0: out[:, :128] = x_sa_flat @ Wo2^T + bo2
//                     z=1: out[:, 128:] = x_ca      @ Wo1^T + bo1
// grid = (1024, 2, 2).
// ---------------------------------------------------------------------------
__global__ __launch_bounds__(256) void gemm_out(
    const unsigned short* __restrict__ Asa, const unsigned short* __restrict__ Aca,
    const float* __restrict__ Wo2, const float* __restrict__ bo2,
    const float* __restrict__ Wo1, const float* __restrict__ bo1,
    float* __restrict__ out)
{
  __shared__ float As[32][65];
  __shared__ float Bs[32][65];
  const unsigned short* A;
  const float* W; const float* bias; int joff;
  if (blockIdx.z == 0) { A = Asa; W = Wo2; bias = bo2; joff = 0; }
  else                 { A = Aca; W = Wo1; bias = bo1; joff = 128; }
  const int tid = threadIdx.x;
  const int tx = tid & 15, ty = tid >> 4;
  const int m0 = blockIdx.x * 64;
  const int j0 = blockIdx.y * 64;
  float acc[4][4] = {};
  for (int k0 = 0; k0 < 256; k0 += 32) {
    {
      const int r = tid >> 2, seg = tid & 3;
      const uint4 u = *reinterpret_cast<const uint4*>(&A[(size_t)(m0 + r) * 256 + k0 + seg * 8]);
      float lo, hi; const int kb = seg * 8;
      bfu2x2(u.x, lo, hi); As[kb + 0][r] = lo; As[kb + 1][r] = hi;
      bfu2x2(u.y, lo, hi); As[kb + 2][r] = lo; As[kb + 3][r] = hi;
      bfu2x2(u.z, lo, hi); As[kb + 4][r] = lo; As[kb + 5][r] = hi;
      bfu2x2(u.w, lo, hi); As[kb + 6][r] = lo; As[kb + 7][r] = hi;
    }
#pragma unroll
    for (int i = 0; i < 2; ++i) {
      const int idx = tid + i * 256;
      const int r = idx >> 3;
      const int kv = (idx & 7) << 2;
      const float4 wv = *reinterpret_cast<const float4*>(&W[(size_t)(j0 + r) * 256 + k0 + kv]);
      Bs[kv + 0][r] = wv.x; Bs[kv + 1][r] = wv.y; Bs[kv + 2][r] = wv.z; Bs[kv + 3][r] = wv.w;
    }
    __syncthreads();
#pragma unroll
    for (int kk = 0; kk < 32; ++kk) {
      float a[4], bb[4];
#pragma unroll
      for (int i = 0; i < 4; ++i) a[i] = As[kk][ty * 4 + i];
#pragma unroll
      for (int j = 0; j < 4; ++j) bb[j] = Bs[kk][tx * 4 + j];
#pragma unroll
      for (int i = 0; i < 4; ++i)
#pragma unroll
        for (int j = 0; j < 4; ++j) acc[i][j] += a[i] * bb[j];
    }
    __syncthreads();
  }
#pragma unroll
  for (int i = 0; i < 4; ++i) {
    const int m = m0 + ty * 4 + i;
    float4 o;
    o.x = acc[i][0] + bias[j0 + tx * 4 + 0];
    o.y = acc[i][1] + bias[j0 + tx * 4 + 1];
    o.z = acc[i][2] + bias[j0 + tx * 4 + 2];
    o.w = acc[i][3] + bias[j0 + tx * 4 + 3];
    *reinterpret_cast<float4*>(&out[(size_t)m * 256 + joff + j0 + tx * 4]) = o;
  }
}

extern "C" void kernel_launch(void* const* d_in, const int* in_sizes, int n_in,
                              void* d_out, int out_size, void* d_ws, size_t ws_size,
                              hipStream_t stream)
{
  const float* x     = (const float*)d_in[0];
  const float* ref   = (const float*)d_in[1];
  const float* Wq    = (const float*)d_in[2];
  const float* bq    = (const float*)d_in[3];
  const float* Wkvv  = (const float*)d_in[4];
  const float* bkvv  = (const float*)d_in[5];
  const float* WE    = (const float*)d_in[6];
  const float* bE    = (const float*)d_in[7];
  const float* Wo1   = (const float*)d_in[8];
  const float* bo1   = (const float*)d_in[9];
  const float* Wo2   = (const float*)d_in[10];
  const float* bo2   = (const float*)d_in[11];
  const float* temp  = (const float*)d_in[12];
  const float* temp2 = (const float*)d_in[13];
  float* out = (float*)d_out;

  char* ws = (char*)d_ws;
  unsigned short* qT    = (unsigned short*)(ws);               // [4096][4096] bf16 (q, channel-major)
  unsigned short* kvvT  = (unsigned short*)(ws + 33554432);    // [3][4096][4096] bf16 (k, v_ca, v_sa)
  unsigned short* x_ca  = (unsigned short*)(ws + 134217728);   // [B,N,C] bf16
  unsigned short* x_sa  = (unsigned short*)(ws + 167772160);   // [B,hd,H,N] bf16
  float* rq     = (float*)(ws + 201326592);                    // [4096]
  float* rk     = (float*)(ws + 201342976);                    // [4096]
  float* part   = (float*)(ws + 201359360);                    // [8][64][3][64][64] f32
  float* attn_t = (float*)(ws + 226525184);                    // [64][64][64] f32  ([bh][d][c])
  float* kp     = (float*)(ws + 227573760);                    // [64][64][64] f32
  float* vp     = (float*)(ws + 228622336);                    // [64][64][64] f32
  // total ws usage: 229,670,912 bytes

  const dim3 blk(256);
  gemm_proj<<<dim3(1024, 4), blk, 0, stream>>>(x, Wq, bq, qT);
  gemm_proj<<<dim3(1024, 12), blk, 0, stream>>>(ref, Wkvv, bkvv, kvvT);
  norm_kernel<<<dim3(8192), blk, 0, stream>>>(qT, kvvT, rq, rk);
  stats_kernel<<<dim3(64, 8), blk, 0, stream>>>(qT, kvvT, kvvT + 2 * QSZ, WE, part);
  postproc_kernel<<<dim3(64), blk, 0, stream>>>(part, rq, rk, bE, temp, attn_t, kp, vp);
  xca_kernel<<<dim3(64, 32), blk, 0, stream>>>(attn_t, kvvT + QSZ, x_ca);
  sa_kernel<<<dim3(64, 16), blk, 0, stream>>>(qT, rq, kp, vp, temp2, x_sa);
  gemm_out<<<dim3(1024, 2, 2), blk, 0, stream>>>(x_sa, x_ca, Wo2, bo2, Wo1, bo1, out);
}

// Round 2
// 458.721 us; speedup vs baseline: 2.3393x; 2.3393x over previous
//
#include <hip/hip_runtime.h>
#include <hip/hip_bf16.h>

#define DI __device__ __forceinline__

constexpr int B_ = 16, N_ = 4096, C_ = 256, H_ = 4;
constexpr size_t QSZ = (size_t)4096 * 4096;   // elements in one [4096][4096] bf16 plane
constexpr int LDW = 72;    // LDS row stride (ushorts) for 64-wide bf16 tiles (bank-rotating)
constexpr int LDC = 136;   // LDS row stride (ushorts) for 128-wide epilogue tile (16B-aligned)

typedef __attribute__((ext_vector_type(8))) short bh8;
typedef __attribute__((ext_vector_type(4))) float fx4;

DI float bfu2f(unsigned short u) { return __uint_as_float(((unsigned)u) << 16); }
DI void bfu2x2(unsigned u, float& lo, float& hi) {
  lo = __uint_as_float(u << 16);
  hi = __uint_as_float(u & 0xffff0000u);
}
DI unsigned short f2bfu(float f) {   // RNE f32->bf16 (finite inputs)
  unsigned u = __float_as_uint(f);
  unsigned r = 0x7fffu + ((u >> 16) & 1u);
  return (unsigned short)((u + r) >> 16);
}

// ---------------------------------------------------------------------------
// MFMA projection GEMM, transposed output.
// OutT[j][tok] = sum_k W[j][k] * A[tok][k] + bias[j], written bf16 channel-major:
// rowT = ((j>>8)*16 + b)*256 + (j&255), col = n (token within batch).
// grid = (ntile=32, jtile=ncols/128, b=16), block = 256 (4 waves, 2x2).
// ---------------------------------------------------------------------------
__global__ __launch_bounds__(256) void gemm_projT(
    const float* __restrict__ A, const float* __restrict__ W,
    const float* __restrict__ bias, unsigned short* __restrict__ outT)
{
  __shared__ unsigned short smem[2 * 128 * LDW];
  __shared__ float biasS[128];
  unsigned short* Ws = smem;
  unsigned short* Xs = smem + 128 * LDW;
  const int tid = threadIdx.x;
  const int lane = tid & 63, wid = tid >> 6;
  const int wr = wid >> 1, wc = wid & 1;
  const int n0 = blockIdx.x * 128;
  const int j0 = blockIdx.y * 128;
  const int b = blockIdx.z;
  const size_t tok0 = (size_t)b * 4096 + n0;
  if (tid < 128) biasS[tid] = bias[j0 + tid];

  fx4 acc[4][4];
#pragma unroll
  for (int m = 0; m < 4; ++m)
#pragma unroll
    for (int n = 0; n < 4; ++n) acc[m][n] = (fx4){0.f, 0.f, 0.f, 0.f};

  for (int k0 = 0; k0 < 256; k0 += 64) {
#pragma unroll
    for (int c = 0; c < 8; ++c) {
      const int idx = c * 256 + tid;     // 0..2047
      const int r = idx >> 4;            // 0..127
      const int ks = (idx & 15) << 2;    // 0..60
      const float4 wv = *reinterpret_cast<const float4*>(&W[(size_t)(j0 + r) * 256 + k0 + ks]);
      ushort4 pw;
      pw.x = f2bfu(wv.x); pw.y = f2bfu(wv.y); pw.z = f2bfu(wv.z); pw.w = f2bfu(wv.w);
      *reinterpret_cast<ushort4*>(&Ws[r * LDW + ks]) = pw;
      const float4 xv = *reinterpret_cast<const float4*>(&A[(tok0 + r) * 256 + k0 + ks]);
      ushort4 px;
      px.x = f2bfu(xv.x); px.y = f2bfu(xv.y); px.z = f2bfu(xv.z); px.w = f2bfu(xv.w);
      *reinterpret_cast<ushort4*>(&Xs[r * LDW + ks]) = px;
    }
    __syncthreads();
#pragma unroll
    for (int kk = 0; kk < 2; ++kk) {
      const int kb = kk * 32 + (lane >> 4) * 8;
      bh8 af[4], bfr[4];
#pragma unroll
      for (int m = 0; m < 4; ++m)
        af[m] = *reinterpret_cast<const bh8*>(&Ws[(wr * 64 + m * 16 + (lane & 15)) * LDW + kb]);
#pragma unroll
      for (int n = 0; n < 4; ++n)
        bfr[n] = *reinterpret_cast<const bh8*>(&Xs[(wc * 64 + n * 16 + (lane & 15)) * LDW + kb]);
#pragma unroll
      for (int m = 0; m < 4; ++m)
#pragma unroll
        for (int n = 0; n < 4; ++n)
          acc[m][n] = __builtin_amdgcn_mfma_f32_16x16x32_bf16(af[m], bfr[n], acc[m][n], 0, 0, 0);
    }
    __syncthreads();
  }

  // epilogue: acc -> bf16 LDS [128][128] (stride LDC), then coalesced store
  unsigned short* Co = smem;
#pragma unroll
  for (int m = 0; m < 4; ++m) {
    const int jl = wr * 64 + m * 16 + ((lane >> 4) << 2);
#pragma unroll
    for (int n = 0; n < 4; ++n) {
      const int col = wc * 64 + n * 16 + (lane & 15);
#pragma unroll
      for (int r = 0; r < 4; ++r)
        Co[(jl + r) * LDC + col] = f2bfu(acc[m][n][r] + biasS[jl + r]);
    }
  }
  __syncthreads();
#pragma unroll
  for (int c = 0; c < 8; ++c) {
    const int r = tid >> 1;
    const int colseg = (tid & 1) * 64 + c * 8;
    const uint4 v = *reinterpret_cast<const uint4*>(&Co[r * LDC + colseg]);
    const int jj = j0 + r;
    const int rowT = ((jj >> 8) * B_ + b) * 256 + (jj & 255);
    *reinterpret_cast<uint4*>(&outT[(size_t)rowT * N_ + n0 + colseg]) = v;
  }
}

// ---------------------------------------------------------------------------
// MFMA output GEMM: z=0: out[:, :128] = x_sa_flat @ Wo2^T + bo2
//                   z=1: out[:, 128:] = x_ca      @ Wo1^T + bo1
// A operands already bf16 [65536][256]. grid = (512, 1, 2), block = 256.
// ---------------------------------------------------------------------------
__global__ __launch_bounds__(256) void gemm_outm(
    const unsigned short* __restrict__ Asa, const unsigned short* __restrict__ Aca,
    const float* __restrict__ Wo2, const float* __restrict__ bo2,
    const float* __restrict__ Wo1, const float* __restrict__ bo1,
    float* __restrict__ out)
{
  __shared__ unsigned short smem[2 * 128 * LDW];
  __shared__ float biasS[128];
  const unsigned short* A;
  const float* Wsrc; const float* bias; int joff;
  if (blockIdx.z == 0) { A = Asa; Wsrc = Wo2; bias = bo2; joff = 0; }
  else                 { A = Aca; Wsrc = Wo1; bias = bo1; joff = 128; }
  unsigned short* Ws = smem;
  unsigned short* Xs = smem + 128 * LDW;
  const int tid = threadIdx.x;
  const int lane = tid & 63, wid = tid >> 6;
  const int wr = wid >> 1, wc = wid & 1;
  const size_t m0 = (size_t)blockIdx.x * 128;
  if (tid < 128) biasS[tid] = bias[tid];

  fx4 acc[4][4];
#pragma unroll
  for (int m = 0; m < 4; ++m)
#pragma unroll
    for (int n = 0; n < 4; ++n) acc[m][n] = (fx4){0.f, 0.f, 0.f, 0.f};

  for (int k0 = 0; k0 < 256; k0 += 64) {
#pragma unroll
    for (int c = 0; c < 8; ++c) {       // W fp32 -> bf16, 128 rows x 64 k
      const int idx = c * 256 + tid;
      const int r = idx >> 4;
      const int ks = (idx & 15) << 2;
      const float4 wv = *reinterpret_cast<const float4*>(&Wsrc[(size_t)r * 256 + k0 + ks]);
      ushort4 pw;
      pw.x = f2bfu(wv.x); pw.y = f2bfu(wv.y); pw.z = f2bfu(wv.z); pw.w = f2bfu(wv.w);
      *reinterpret_cast<ushort4*>(&Ws[r * LDW + ks]) = pw;
    }
#pragma unroll
    for (int c = 0; c < 4; ++c) {       // A bf16 direct copy, 128 rows x 64 k
      const int idx = c * 256 + tid;    // 0..1023
      const int r = idx >> 3;
      const int ks = (idx & 7) << 3;
      const uint4 v = *reinterpret_cast<const uint4*>(&A[(m0 + r) * 256 + k0 + ks]);
      *reinterpret_cast<uint4*>(&Xs[r * LDW + ks]) = v;
    }
    __syncthreads();
#pragma unroll
    for (int kk = 0; kk < 2; ++kk) {
      const int kb = kk * 32 + (lane >> 4) * 8;
      bh8 af[4], bfr[4];
#pragma unroll
      for (int m = 0; m < 4; ++m)   // A-frag = tokens (D-row side)
        af[m] = *reinterpret_cast<const bh8*>(&Xs[(wr * 64 + m * 16 + (lane & 15)) * LDW + kb]);
#pragma unroll
      for (int n = 0; n < 4; ++n)   // B-frag = W (D-col side)
        bfr[n] = *reinterpret_cast<const bh8*>(&Ws[(wc * 64 + n * 16 + (lane & 15)) * LDW + kb]);
#pragma unroll
      for (int m = 0; m < 4; ++m)
#pragma unroll
        for (int n = 0; n < 4; ++n)
          acc[m][n] = __builtin_amdgcn_mfma_f32_16x16x32_bf16(af[m], bfr[n], acc[m][n], 0, 0, 0);
    }
    __syncthreads();
  }

#pragma unroll
  for (int mi = 0; mi < 4; ++mi) {
    const int mrow = wr * 64 + mi * 16 + ((lane >> 4) << 2);
#pragma unroll
    for (int ni = 0; ni < 4; ++ni) {
      const int j = wc * 64 + ni * 16 + (lane & 15);
      const float bv = biasS[j];
#pragma unroll
      for (int r = 0; r < 4; ++r)
        out[(m0 + mrow + r) * 256 + joff + j] = acc[mi][ni][r] + bv;
    }
  }
}

// ---------------------------------------------------------------------------
// Per-channel 1/max(||row||,eps) over N tokens. blocks 0..4095 -> qT rows,
// 4096..8191 -> kT rows.
// ---------------------------------------------------------------------------
__global__ __launch_bounds__(256) void norm_kernel(
    const unsigned short* __restrict__ qT, const unsigned short* __restrict__ kT,
    float* __restrict__ rq, float* __restrict__ rk)
{
  const int row = blockIdx.x;
  const unsigned short* src = (row < 4096) ? (qT + (size_t)row * N_)
                                           : (kT + (size_t)(row - 4096) * N_);
  float s = 0.f;
  for (int i = threadIdx.x; i < N_ / 8; i += 256) {
    const uint4 u = *reinterpret_cast<const uint4*>(&src[i * 8]);
    float a, b;
    bfu2x2(u.x, a, b); s += a * a + b * b;
    bfu2x2(u.y, a, b); s += a * a + b * b;
    bfu2x2(u.z, a, b); s += a * a + b * b;
    bfu2x2(u.w, a, b); s += a * a + b * b;
  }
#pragma unroll
  for (int off = 32; off > 0; off >>= 1) s += __shfl_xor(s, off);
  __shared__ float ws4[4];
  if ((threadIdx.x & 63) == 0) ws4[threadIdx.x >> 6] = s;
  __syncthreads();
  if (threadIdx.x == 0) {
    const float tot = ws4[0] + ws4[1] + ws4[2] + ws4[3];
    const float r = 1.f / fmaxf(sqrtf(tot), 1e-12f);
    (row < 4096 ? rq : rk)[row & 4095] = r;
  }
}

DI void store16(float (*dst)[68], int seg, int col, uint4 u0, uint4 u1) {
  float lo, hi;
  const int r = seg * 16;
  bfu2x2(u0.x, lo, hi); dst[r + 0][col] = lo;  dst[r + 1][col] = hi;
  bfu2x2(u0.y, lo, hi); dst[r + 2][col] = lo;  dst[r + 3][col] = hi;
  bfu2x2(u0.z, lo, hi); dst[r + 4][col] = lo;  dst[r + 5][col] = hi;
  bfu2x2(u0.w, lo, hi); dst[r + 6][col] = lo;  dst[r + 7][col] = hi;
  bfu2x2(u1.x, lo, hi); dst[r + 8][col] = lo;  dst[r + 9][col] = hi;
  bfu2x2(u1.y, lo, hi); dst[r + 10][col] = lo; dst[r + 11][col] = hi;
  bfu2x2(u1.z, lo, hi); dst[r + 12][col] = lo; dst[r + 13][col] = hi;
  bfu2x2(u1.w, lo, hi); dst[r + 14][col] = lo; dst[r + 15][col] = hi;
}

// ---------------------------------------------------------------------------
// Fused per-(b,h) 64x64 stats over token chunks: S=q·k^T, Kp=k·WE^T, Vp=v·WE^T.
// grid = (64 bh, 8 chunks); partials to part[chunk][bh][3][64][64].
// ---------------------------------------------------------------------------
__global__ __launch_bounds__(256) void stats_kernel(
    const unsigned short* __restrict__ qT, const unsigned short* __restrict__ kT,
    const unsigned short* __restrict__ vT, const float* __restrict__ WE,
    float* __restrict__ part)
{
  __shared__ float qs[64][68], ks[64][68], vs[64][68], ws[64][68];
  const int tid = threadIdx.x;
  const int bh = blockIdx.x, chunk = blockIdx.y;
  const int tx = tid & 15, ty = tid >> 4;
  const int lrow = tid >> 2, seg = tid & 3;
  float as[4][4] = {}, ak[4][4] = {}, av[4][4] = {};
  const size_t rbase = (size_t)(bh * 64 + lrow) * N_;
  for (int sub = 0; sub < 8; ++sub) {
    const int nn = chunk * 512 + sub * 64 + seg * 16;
    {
      uint4 u0 = *reinterpret_cast<const uint4*>(&qT[rbase + nn]);
      uint4 u1 = *reinterpret_cast<const uint4*>(&qT[rbase + nn + 8]);
      store16(qs, seg, lrow, u0, u1);
      u0 = *reinterpret_cast<const uint4*>(&kT[rbase + nn]);
      u1 = *reinterpret_cast<const uint4*>(&kT[rbase + nn + 8]);
      store16(ks, seg, lrow, u0, u1);
      u0 = *reinterpret_cast<const uint4*>(&vT[rbase + nn]);
      u1 = *reinterpret_cast<const uint4*>(&vT[rbase + nn + 8]);
      store16(vs, seg, lrow, u0, u1);
      const float* wrow = &WE[(size_t)lrow * N_ + nn];
#pragma unroll
      for (int t = 0; t < 4; ++t) {
        const float4 f = *reinterpret_cast<const float4*>(&wrow[t * 4]);
        const int r = seg * 16 + t * 4;
        ws[r + 0][lrow] = f.x; ws[r + 1][lrow] = f.y;
        ws[r + 2][lrow] = f.z; ws[r + 3][lrow] = f.w;
      }
    }
    __syncthreads();
#pragma unroll 8
    for (int kk = 0; kk < 64; ++kk) {
      float qr[4], kr[4], vr[4], kc[4], wc[4];
#pragma unroll
      for (int i = 0; i < 4; ++i) {
        qr[i] = qs[kk][ty * 4 + i];
        kr[i] = ks[kk][ty * 4 + i];
        vr[i] = vs[kk][ty * 4 + i];
        kc[i] = ks[kk][tx * 4 + i];
        wc[i] = ws[kk][tx * 4 + i];
      }
#pragma unroll
      for (int i = 0; i < 4; ++i)
#pragma unroll
        for (int j = 0; j < 4; ++j) {
          as[i][j] += qr[i] * kc[j];
          ak[i][j] += kr[i] * wc[j];
          av[i][j] += vr[i] * wc[j];
        }
    }
    __syncthreads();
  }
  float* base = &part[((size_t)chunk * 64 + bh) * 12288];
#pragma unroll
  for (int i = 0; i < 4; ++i) {
    const int r = ty * 4 + i;
    *reinterpret_cast<float4*>(&base[r * 64 + tx * 4]) =
        make_float4(as[i][0], as[i][1], as[i][2], as[i][3]);
    *reinterpret_cast<float4*>(&base[4096 + r * 64 + tx * 4]) =
        make_float4(ak[i][0], ak[i][1], ak[i][2], ak[i][3]);
    *reinterpret_cast<float4*>(&base[8192 + r * 64 + tx * 4]) =
        make_float4(av[i][0], av[i][1], av[i][2], av[i][3]);
  }
}

// ---------------------------------------------------------------------------
// Reduce partials; emit kp' = rk*Kp + bE, vp' = Vp + bE, and channel-attention
// softmax attn_t[bh][d][c] = softmax_d(S*rq[c]*rk[d]*temp[h]). grid = 64.
// ---------------------------------------------------------------------------
__global__ __launch_bounds__(256) void postproc_kernel(
    const float* __restrict__ part, const float* __restrict__ rq,
    const float* __restrict__ rk, const float* __restrict__ bE,
    const float* __restrict__ temp, float* __restrict__ attn_t,
    float* __restrict__ kp, float* __restrict__ vp)
{
  __shared__ float sums[12288];
  const int bh = blockIdx.x;
  const int tid = threadIdx.x;
  for (int idx = tid; idx < 12288; idx += 256) {
    float s = 0.f;
    for (int ch = 0; ch < 8; ++ch)
      s += part[((size_t)ch * 64 + bh) * 12288 + idx];
    sums[idx] = s;
  }
  __syncthreads();
  for (int idx = tid; idx < 4096; idx += 256) {
    const int c = idx >> 6, p = idx & 63;
    kp[(size_t)bh * 4096 + idx] = sums[4096 + idx] * rk[bh * 64 + c] + bE[p];
    vp[(size_t)bh * 4096 + idx] = sums[8192 + idx] + bE[p];
  }
  const float tv = temp[bh & 3];
  const int lane = tid & 63, wv = tid >> 6;
  for (int ri = 0; ri < 16; ++ri) {
    const int c = wv * 16 + ri;
    const float val = sums[c * 64 + lane] * rq[bh * 64 + c] * rk[bh * 64 + lane] * tv;
    float m = val;
#pragma unroll
    for (int off = 32; off > 0; off >>= 1) m = fmaxf(m, __shfl_xor(m, off));
    const float e = __expf(val - m);
    float ssum = e;
#pragma unroll
    for (int off = 32; off > 0; off >>= 1) ssum += __shfl_xor(ssum, off);
    attn_t[(size_t)bh * 4096 + lane * 64 + c] = e / ssum;   // [d][c]
  }
}

// ---------------------------------------------------------------------------
// x_ca[c][n] = sum_d attn[c][d] * v_ca[d][n], written to [B,N,C] bf16.
// grid = (64 bh, 32 ntiles of 128).
// ---------------------------------------------------------------------------
__global__ __launch_bounds__(256) void xca_kernel(
    const float* __restrict__ attn_t, const unsigned short* __restrict__ vT,
    unsigned short* __restrict__ x_ca)
{
  __shared__ float at[64][68];
  __shared__ float vt[64][132];
  const int tid = threadIdx.x;
  const int bh = blockIdx.x, b = bh >> 2, h = bh & 3;
  const int n0 = blockIdx.y * 128;
  for (int i = tid; i < 1024; i += 256) {
    const float4 f = *reinterpret_cast<const float4*>(&attn_t[(size_t)bh * 4096 + i * 4]);
    *reinterpret_cast<float4*>(&at[i >> 4][(i * 4) & 63]) = f;
  }
  {
    const int d = tid >> 2, seg = tid & 3;
    const size_t rb = (size_t)(bh * 64 + d) * N_ + n0 + seg * 32;
#pragma unroll
    for (int t = 0; t < 4; ++t) {
      const uint4 u = *reinterpret_cast<const uint4*>(&vT[rb + t * 8]);
      float lo, hi;
      const int c0 = seg * 32 + t * 8;
      bfu2x2(u.x, lo, hi); vt[d][c0 + 0] = lo; vt[d][c0 + 1] = hi;
      bfu2x2(u.y, lo, hi); vt[d][c0 + 2] = lo; vt[d][c0 + 3] = hi;
      bfu2x2(u.z, lo, hi); vt[d][c0 + 4] = lo; vt[d][c0 + 5] = hi;
      bfu2x2(u.w, lo, hi); vt[d][c0 + 6] = lo; vt[d][c0 + 7] = hi;
    }
  }
  __syncthreads();
  const int cg = tid & 7, ng = tid >> 3;
  const int c0 = cg * 8, nl0 = ng * 4;
  float acc[4][8] = {};
  for (int d = 0; d < 64; ++d) {
    float a[8];
    *reinterpret_cast<float4*>(&a[0]) = *reinterpret_cast<const float4*>(&at[d][c0]);
    *reinterpret_cast<float4*>(&a[4]) = *reinterpret_cast<const float4*>(&at[d][c0 + 4]);
    const float4 vv = *reinterpret_cast<const float4*>(&vt[d][nl0]);
    const float vn[4] = {vv.x, vv.y, vv.z, vv.w};
#pragma unroll
    for (int n = 0; n < 4; ++n)
#pragma unroll
      for (int c = 0; c < 8; ++c) acc[n][c] += vn[n] * a[c];
  }
#pragma unroll
  for (int n = 0; n < 4; ++n) {
    union { uint4 v; unsigned short u[8]; } pk;
#pragma unroll
    for (int c = 0; c < 8; ++c) pk.u[c] = f2bfu(acc[n][c]);
    const int nn = n0 + nl0 + n;
    *reinterpret_cast<uint4*>(&x_ca[((size_t)b * N_ + nn) * 256 + h * 64 + c0]) = pk.v;
  }
}

// ---------------------------------------------------------------------------
// Spatial attention: per token, scores[p]=sum_c qn[c,n]*kp[c][p]; softmax_p;
// x_sa_t[b][d][h][n] = sum_p attn[p]*vp[d][p].  grid = (64 bh, 16 ntiles).
// ---------------------------------------------------------------------------
__global__ __launch_bounds__(256) void sa_kernel(
    const unsigned short* __restrict__ qT, const float* __restrict__ rq,
    const float* __restrict__ kp, const float* __restrict__ vp,
    const float* __restrict__ temp2, unsigned short* __restrict__ x_sa)
{
  __shared__ float kps[64][68];
  __shared__ float vps[64][68];
  __shared__ float rqs[64];
  const int tid = threadIdx.x;
  const int bh = blockIdx.x, b = bh >> 2, h = bh & 3;
  const int n = blockIdx.y * 256 + tid;
  for (int i = tid; i < 1024; i += 256) {
    const int r = i >> 4, c = (i * 4) & 63;
    *reinterpret_cast<float4*>(&kps[r][c]) =
        *reinterpret_cast<const float4*>(&kp[(size_t)bh * 4096 + i * 4]);
    *reinterpret_cast<float4*>(&vps[r][c]) =
        *reinterpret_cast<const float4*>(&vp[(size_t)bh * 4096 + i * 4]);
  }
  if (tid < 64) rqs[tid] = rq[bh * 64 + tid];
  __syncthreads();
  float sc[64];
#pragma unroll
  for (int p = 0; p < 64; ++p) sc[p] = 0.f;
  const size_t qcol = (size_t)(bh * 64) * N_ + n;
  for (int c = 0; c < 64; ++c) {
    const float qv = bfu2f(qT[qcol + (size_t)c * N_]) * rqs[c];
#pragma unroll
    for (int p4 = 0; p4 < 16; ++p4) {
      const float4 kv = *reinterpret_cast<const float4*>(&kps[c][p4 * 4]);
      sc[p4 * 4 + 0] += qv * kv.x;
      sc[p4 * 4 + 1] += qv * kv.y;
      sc[p4 * 4 + 2] += qv * kv.z;
      sc[p4 * 4 + 3] += qv * kv.w;
    }
  }
  const float t2 = temp2[h];
  float mx = -1e30f;
#pragma unroll
  for (int p = 0; p < 64; ++p) { sc[p] *= t2; mx = fmaxf(mx, sc[p]); }
  float ssum = 0.f;
#pragma unroll
  for (int p = 0; p < 64; ++p) { sc[p] = __expf(sc[p] - mx); ssum += sc[p]; }
  const float inv = 1.f / ssum;
  for (int d = 0; d < 64; ++d) {
    float o = 0.f;
#pragma unroll
    for (int p4 = 0; p4 < 16; ++p4) {
      const float4 vv = *reinterpret_cast<const float4*>(&vps[d][p4 * 4]);
      o += sc[p4 * 4 + 0] * vv.x + sc[p4 * 4 + 1] * vv.y +
           sc[p4 * 4 + 2] * vv.z + sc[p4 * 4 + 3] * vv.w;
    }
    x_sa[((size_t)(b * 64 + d) * 4 + h) * N_ + n] = f2bfu(o * inv);
  }
}

extern "C" void kernel_launch(void* const* d_in, const int* in_sizes, int n_in,
                              void* d_out, int out_size, void* d_ws, size_t ws_size,
                              hipStream_t stream)
{
  const float* x     = (const float*)d_in[0];
  const float* ref   = (const float*)d_in[1];
  const float* Wq    = (const float*)d_in[2];
  const float* bq    = (const float*)d_in[3];
  const float* Wkvv  = (const float*)d_in[4];
  const float* bkvv  = (const float*)d_in[5];
  const float* WE    = (const float*)d_in[6];
  const float* bE    = (const float*)d_in[7];
  const float* Wo1   = (const float*)d_in[8];
  const float* bo1   = (const float*)d_in[9];
  const float* Wo2   = (const float*)d_in[10];
  const float* bo2   = (const float*)d_in[11];
  const float* temp  = (const float*)d_in[12];
  const float* temp2 = (const float*)d_in[13];
  float* out = (float*)d_out;

  char* ws = (char*)d_ws;
  unsigned short* qT    = (unsigned short*)(ws);               // [4096][4096] bf16 (q, channel-major)
  unsigned short* kvvT  = (unsigned short*)(ws + 33554432);    // [3][4096][4096] bf16 (k, v_ca, v_sa)
  unsigned short* x_ca  = (unsigned short*)(ws + 134217728);   // [B,N,C] bf16
  unsigned short* x_sa  = (unsigned short*)(ws + 167772160);   // [B,hd,H,N] bf16
  float* rq     = (float*)(ws + 201326592);                    // [4096]
  float* rk     = (float*)(ws + 201342976);                    // [4096]
  float* part   = (float*)(ws + 201359360);                    // [8][64][3][64][64] f32
  float* attn_t = (float*)(ws + 226525184);                    // [64][64][64] f32  ([bh][d][c])
  float* kp     = (float*)(ws + 227573760);                    // [64][64][64] f32
  float* vp     = (float*)(ws + 228622336);                    // [64][64][64] f32
  // total ws usage: 229,670,912 bytes

  const dim3 blk(256);
  gemm_projT<<<dim3(32, 2, 16), blk, 0, stream>>>(x, Wq, bq, qT);
  gemm_projT<<<dim3(32, 6, 16), blk, 0, stream>>>(ref, Wkvv, bkvv, kvvT);
  norm_kernel<<<dim3(8192), blk, 0, stream>>>(qT, kvvT, rq, rk);
  stats_kernel<<<dim3(64, 8), blk, 0, stream>>>(qT, kvvT, kvvT + 2 * QSZ, WE, part);
  postproc_kernel<<<dim3(64), blk, 0, stream>>>(part, rq, rk, bE, temp, attn_t, kp, vp);
  xca_kernel<<<dim3(64, 32), blk, 0, stream>>>(attn_t, kvvT + QSZ, x_ca);
  sa_kernel<<<dim3(64, 16), blk, 0, stream>>>(qT, rq, kp, vp, temp2, x_sa);
  gemm_outm<<<dim3(512, 1, 2), blk, 0, stream>>>(x_sa, x_ca, Wo2, bo2, Wo1, bo1, out);
}

// Round 3
// 370.430 us; speedup vs baseline: 2.8969x; 1.2383x over previous
//
#include <hip/hip_runtime.h>
#include <hip/hip_bf16.h>

#define DI __device__ __forceinline__

constexpr int B_ = 16, N_ = 4096, C_ = 256, H_ = 4;
constexpr size_t QSZ = (size_t)4096 * 4096;   // elements in one [4096][4096] bf16 plane
constexpr int LDW = 72;    // LDS row stride (ushorts) for 64-wide bf16 tiles (bank-rotating)
constexpr int LDC = 136;   // LDS row stride (ushorts) for 128-wide epilogue tile (16B-aligned)

typedef __attribute__((ext_vector_type(8))) short bh8;
typedef __attribute__((ext_vector_type(4))) float fx4;

DI float bfu2f(unsigned short u) { return __uint_as_float(((unsigned)u) << 16); }
DI void bfu2x2(unsigned u, float& lo, float& hi) {
  lo = __uint_as_float(u << 16);
  hi = __uint_as_float(u & 0xffff0000u);
}
DI unsigned short f2bfu(float f) {   // RNE f32->bf16 (finite inputs)
  unsigned u = __float_as_uint(f);
  unsigned r = 0x7fffu + ((u >> 16) & 1u);
  return (unsigned short)((u + r) >> 16);
}

// ---------------------------------------------------------------------------
// MFMA projection GEMM, transposed output.
// OutT[j][tok] = sum_k W[j][k] * A[tok][k] + bias[j], written bf16 channel-major:
// rowT = ((j>>8)*16 + b)*256 + (j&255), col = n (token within batch).
// grid = (ntile=32, jtile=ncols/128, b=16), block = 256 (4 waves, 2x2).
// ---------------------------------------------------------------------------
__global__ __launch_bounds__(256) void gemm_projT(
    const float* __restrict__ A, const float* __restrict__ W,
    const float* __restrict__ bias, unsigned short* __restrict__ outT)
{
  __shared__ unsigned short smem[2 * 128 * LDW];
  __shared__ float biasS[128];
  unsigned short* Ws = smem;
  unsigned short* Xs = smem + 128 * LDW;
  const int tid = threadIdx.x;
  const int lane = tid & 63, wid = tid >> 6;
  const int wr = wid >> 1, wc = wid & 1;
  const int n0 = blockIdx.x * 128;
  const int j0 = blockIdx.y * 128;
  const int b = blockIdx.z;
  const size_t tok0 = (size_t)b * 4096 + n0;
  if (tid < 128) biasS[tid] = bias[j0 + tid];

  fx4 acc[4][4];
#pragma unroll
  for (int m = 0; m < 4; ++m)
#pragma unroll
    for (int n = 0; n < 4; ++n) acc[m][n] = (fx4){0.f, 0.f, 0.f, 0.f};

  for (int k0 = 0; k0 < 256; k0 += 64) {
#pragma unroll
    for (int c = 0; c < 8; ++c) {
      const int idx = c * 256 + tid;     // 0..2047
      const int r = idx >> 4;            // 0..127
      const int ks = (idx & 15) << 2;    // 0..60
      const float4 wv = *reinterpret_cast<const float4*>(&W[(size_t)(j0 + r) * 256 + k0 + ks]);
      ushort4 pw;
      pw.x = f2bfu(wv.x); pw.y = f2bfu(wv.y); pw.z = f2bfu(wv.z); pw.w = f2bfu(wv.w);
      *reinterpret_cast<ushort4*>(&Ws[r * LDW + ks]) = pw;
      const float4 xv = *reinterpret_cast<const float4*>(&A[(tok0 + r) * 256 + k0 + ks]);
      ushort4 px;
      px.x = f2bfu(xv.x); px.y = f2bfu(xv.y); px.z = f2bfu(xv.z); px.w = f2bfu(xv.w);
      *reinterpret_cast<ushort4*>(&Xs[r * LDW + ks]) = px;
    }
    __syncthreads();
#pragma unroll
    for (int kk = 0; kk < 2; ++kk) {
      const int kb = kk * 32 + (lane >> 4) * 8;
      bh8 af[4], bfr[4];
#pragma unroll
      for (int m = 0; m < 4; ++m)
        af[m] = *reinterpret_cast<const bh8*>(&Ws[(wr * 64 + m * 16 + (lane & 15)) * LDW + kb]);
#pragma unroll
      for (int n = 0; n < 4; ++n)
        bfr[n] = *reinterpret_cast<const bh8*>(&Xs[(wc * 64 + n * 16 + (lane & 15)) * LDW + kb]);
#pragma unroll
      for (int m = 0; m < 4; ++m)
#pragma unroll
        for (int n = 0; n < 4; ++n)
          acc[m][n] = __builtin_amdgcn_mfma_f32_16x16x32_bf16(af[m], bfr[n], acc[m][n], 0, 0, 0);
    }
    __syncthreads();
  }

  // epilogue: acc -> bf16 LDS [128][128] (stride LDC), then coalesced store
  unsigned short* Co = smem;
#pragma unroll
  for (int m = 0; m < 4; ++m) {
    const int jl = wr * 64 + m * 16 + ((lane >> 4) << 2);
#pragma unroll
    for (int n = 0; n < 4; ++n) {
      const int col = wc * 64 + n * 16 + (lane & 15);
#pragma unroll
      for (int r = 0; r < 4; ++r)
        Co[(jl + r) * LDC + col] = f2bfu(acc[m][n][r] + biasS[jl + r]);
    }
  }
  __syncthreads();
#pragma unroll
  for (int c = 0; c < 8; ++c) {
    const int r = tid >> 1;
    const int colseg = (tid & 1) * 64 + c * 8;
    const uint4 v = *reinterpret_cast<const uint4*>(&Co[r * LDC + colseg]);
    const int jj = j0 + r;
    const int rowT = ((jj >> 8) * B_ + b) * 256 + (jj & 255);
    *reinterpret_cast<uint4*>(&outT[(size_t)rowT * N_ + n0 + colseg]) = v;
  }
}

// ---------------------------------------------------------------------------
// MFMA output GEMM: z=0: out[:, :128] = x_sa_flat @ Wo2^T + bo2
//                   z=1: out[:, 128:] = x_ca      @ Wo1^T + bo1
// A operands already bf16 [65536][256]. grid = (512, 1, 2), block = 256.
// ---------------------------------------------------------------------------
__global__ __launch_bounds__(256) void gemm_outm(
    const unsigned short* __restrict__ Asa, const unsigned short* __restrict__ Aca,
    const float* __restrict__ Wo2, const float* __restrict__ bo2,
    const float* __restrict__ Wo1, const float* __restrict__ bo1,
    float* __restrict__ out)
{
  __shared__ unsigned short smem[2 * 128 * LDW];
  __shared__ float biasS[128];
  const unsigned short* A;
  const float* Wsrc; const float* bias; int joff;
  if (blockIdx.z == 0) { A = Asa; Wsrc = Wo2; bias = bo2; joff = 0; }
  else                 { A = Aca; Wsrc = Wo1; bias = bo1; joff = 128; }
  unsigned short* Ws = smem;
  unsigned short* Xs = smem + 128 * LDW;
  const int tid = threadIdx.x;
  const int lane = tid & 63, wid = tid >> 6;
  const int wr = wid >> 1, wc = wid & 1;
  const size_t m0 = (size_t)blockIdx.x * 128;
  if (tid < 128) biasS[tid] = bias[tid];

  fx4 acc[4][4];
#pragma unroll
  for (int m = 0; m < 4; ++m)
#pragma unroll
    for (int n = 0; n < 4; ++n) acc[m][n] = (fx4){0.f, 0.f, 0.f, 0.f};

  for (int k0 = 0; k0 < 256; k0 += 64) {
#pragma unroll
    for (int c = 0; c < 8; ++c) {       // W fp32 -> bf16, 128 rows x 64 k
      const int idx = c * 256 + tid;
      const int r = idx >> 4;
      const int ks = (idx & 15) << 2;
      const float4 wv = *reinterpret_cast<const float4*>(&Wsrc[(size_t)r * 256 + k0 + ks]);
      ushort4 pw;
      pw.x = f2bfu(wv.x); pw.y = f2bfu(wv.y); pw.z = f2bfu(wv.z); pw.w = f2bfu(wv.w);
      *reinterpret_cast<ushort4*>(&Ws[r * LDW + ks]) = pw;
    }
#pragma unroll
    for (int c = 0; c < 4; ++c) {       // A bf16 direct copy, 128 rows x 64 k
      const int idx = c * 256 + tid;    // 0..1023
      const int r = idx >> 3;
      const int ks = (idx & 7) << 3;
      const uint4 v = *reinterpret_cast<const uint4*>(&A[(m0 + r) * 256 + k0 + ks]);
      *reinterpret_cast<uint4*>(&Xs[r * LDW + ks]) = v;
    }
    __syncthreads();
#pragma unroll
    for (int kk = 0; kk < 2; ++kk) {
      const int kb = kk * 32 + (lane >> 4) * 8;
      bh8 af[4], bfr[4];
#pragma unroll
      for (int m = 0; m < 4; ++m)   // A-frag = tokens (D-row side)
        af[m] = *reinterpret_cast<const bh8*>(&Xs[(wr * 64 + m * 16 + (lane & 15)) * LDW + kb]);
#pragma unroll
      for (int n = 0; n < 4; ++n)   // B-frag = W (D-col side)
        bfr[n] = *reinterpret_cast<const bh8*>(&Ws[(wc * 64 + n * 16 + (lane & 15)) * LDW + kb]);
#pragma unroll
      for (int m = 0; m < 4; ++m)
#pragma unroll
        for (int n = 0; n < 4; ++n)
          acc[m][n] = __builtin_amdgcn_mfma_f32_16x16x32_bf16(af[m], bfr[n], acc[m][n], 0, 0, 0);
    }
    __syncthreads();
  }

#pragma unroll
  for (int mi = 0; mi < 4; ++mi) {
    const int mrow = wr * 64 + mi * 16 + ((lane >> 4) << 2);
#pragma unroll
    for (int ni = 0; ni < 4; ++ni) {
      const int j = wc * 64 + ni * 16 + (lane & 15);
      const float bv = biasS[j];
#pragma unroll
      for (int r = 0; r < 4; ++r)
        out[(m0 + mrow + r) * 256 + joff + j] = acc[mi][ni][r] + bv;
    }
  }
}

// ---------------------------------------------------------------------------
// WE fp32 -> bf16 plane (64 x 4096). grid = 128, block = 256, 8 elems/thread.
// ---------------------------------------------------------------------------
__global__ __launch_bounds__(256) void cvt_we(
    const float* __restrict__ WE, unsigned short* __restrict__ wEb)
{
  const int idx = blockIdx.x * 256 + threadIdx.x;
  const float4 a = *reinterpret_cast<const float4*>(&WE[(size_t)idx * 8]);
  const float4 b = *reinterpret_cast<const float4*>(&WE[(size_t)idx * 8 + 4]);
  union { uint4 v; unsigned short u[8]; } pk;
  pk.u[0] = f2bfu(a.x); pk.u[1] = f2bfu(a.y); pk.u[2] = f2bfu(a.z); pk.u[3] = f2bfu(a.w);
  pk.u[4] = f2bfu(b.x); pk.u[5] = f2bfu(b.y); pk.u[6] = f2bfu(b.z); pk.u[7] = f2bfu(b.w);
  *reinterpret_cast<uint4*>(&wEb[(size_t)idx * 8]) = pk.v;
}

// ---------------------------------------------------------------------------
// Per-channel 1/max(||row||,eps) over N tokens. blocks 0..4095 -> qT rows,
// 4096..8191 -> kT rows.
// ---------------------------------------------------------------------------
__global__ __launch_bounds__(256) void norm_kernel(
    const unsigned short* __restrict__ qT, const unsigned short* __restrict__ kT,
    float* __restrict__ rq, float* __restrict__ rk)
{
  const int row = blockIdx.x;
  const unsigned short* src = (row < 4096) ? (qT + (size_t)row * N_)
                                           : (kT + (size_t)(row - 4096) * N_);
  float s = 0.f;
  for (int i = threadIdx.x; i < N_ / 8; i += 256) {
    const uint4 u = *reinterpret_cast<const uint4*>(&src[i * 8]);
    float a, b;
    bfu2x2(u.x, a, b); s += a * a + b * b;
    bfu2x2(u.y, a, b); s += a * a + b * b;
    bfu2x2(u.z, a, b); s += a * a + b * b;
    bfu2x2(u.w, a, b); s += a * a + b * b;
  }
#pragma unroll
  for (int off = 32; off > 0; off >>= 1) s += __shfl_xor(s, off);
  __shared__ float ws4[4];
  if ((threadIdx.x & 63) == 0) ws4[threadIdx.x >> 6] = s;
  __syncthreads();
  if (threadIdx.x == 0) {
    const float tot = ws4[0] + ws4[1] + ws4[2] + ws4[3];
    const float r = 1.f / fmaxf(sqrtf(tot), 1e-12f);
    (row < 4096 ? rq : rk)[row & 4095] = r;
  }
}

// ---------------------------------------------------------------------------
// MFMA stats: per (bh, chunk of 512 tokens), three 64x64 partial GEMMs over
// tokens: S=q.k^T (wave0), Kp=k.WE^T (wave1), Vp=v.WE^T (wave2); wave3 stages.
// part[chunk][bh][3][64][64]. grid = (64, 8), block = 256.
// ---------------------------------------------------------------------------
__global__ __launch_bounds__(256) void stats_mfma(
    const unsigned short* __restrict__ qT, const unsigned short* __restrict__ kT,
    const unsigned short* __restrict__ vT, const unsigned short* __restrict__ wEb,
    float* __restrict__ part)
{
  __shared__ unsigned short smem[4 * 64 * LDW];
  unsigned short* sq = smem;
  unsigned short* sk = smem + 64 * LDW;
  unsigned short* sv = smem + 2 * 64 * LDW;
  unsigned short* sw = smem + 3 * 64 * LDW;
  const int tid = threadIdx.x;
  const int lane = tid & 63, wid = tid >> 6;
  const int bh = blockIdx.x, chunk = blockIdx.y;
  const size_t rowbase = (size_t)bh * 64 * N_;

  fx4 acc[4][4];
#pragma unroll
  for (int m = 0; m < 4; ++m)
#pragma unroll
    for (int n = 0; n < 4; ++n) acc[m][n] = (fx4){0.f, 0.f, 0.f, 0.f};

  const unsigned short* Aop = (wid == 1) ? sk : (wid == 2) ? sv : sq;
  const unsigned short* Bop = (wid == 1 || wid == 2) ? sw : sk;

  for (int tile = 0; tile < 8; ++tile) {
    const int n0 = chunk * 512 + tile * 64;
#pragma unroll
    for (int c = 0; c < 2; ++c) {
      const int idx = c * 256 + tid;       // 0..511
      const int r = idx >> 3;              // 0..63
      const int off = (idx & 7) * 8;       // 0..56
      *reinterpret_cast<uint4*>(&sq[r * LDW + off]) =
          *reinterpret_cast<const uint4*>(&qT[rowbase + (size_t)r * N_ + n0 + off]);
      *reinterpret_cast<uint4*>(&sk[r * LDW + off]) =
          *reinterpret_cast<const uint4*>(&kT[rowbase + (size_t)r * N_ + n0 + off]);
      *reinterpret_cast<uint4*>(&sv[r * LDW + off]) =
          *reinterpret_cast<const uint4*>(&vT[rowbase + (size_t)r * N_ + n0 + off]);
      *reinterpret_cast<uint4*>(&sw[r * LDW + off]) =
          *reinterpret_cast<const uint4*>(&wEb[(size_t)r * N_ + n0 + off]);
    }
    __syncthreads();
    if (wid < 3) {
#pragma unroll
      for (int kk = 0; kk < 2; ++kk) {
        const int kb = kk * 32 + (lane >> 4) * 8;
        bh8 af[4], bfr[4];
#pragma unroll
        for (int m = 0; m < 4; ++m)
          af[m] = *reinterpret_cast<const bh8*>(&Aop[(m * 16 + (lane & 15)) * LDW + kb]);
#pragma unroll
        for (int n = 0; n < 4; ++n)
          bfr[n] = *reinterpret_cast<const bh8*>(&Bop[(n * 16 + (lane & 15)) * LDW + kb]);
#pragma unroll
        for (int m = 0; m < 4; ++m)
#pragma unroll
          for (int n = 0; n < 4; ++n)
            acc[m][n] = __builtin_amdgcn_mfma_f32_16x16x32_bf16(af[m], bfr[n], acc[m][n], 0, 0, 0);
      }
    }
    __syncthreads();
  }

  if (wid < 3) {
    float* base = &part[(((size_t)chunk * 64 + bh) * 3 + wid) * 4096];
#pragma unroll
    for (int m = 0; m < 4; ++m) {
      const int row0 = m * 16 + ((lane >> 4) << 2);
#pragma unroll
      for (int n = 0; n < 4; ++n) {
        const int col = n * 16 + (lane & 15);
#pragma unroll
        for (int r = 0; r < 4; ++r)
          base[(row0 + r) * 64 + col] = acc[m][n][r];
      }
    }
  }
}

// ---------------------------------------------------------------------------
// Reduce partials; emit kp' = rk*Kp + bE, vp' = Vp + bE, and channel-attention
// softmax attn_t[bh][d][c] = softmax_d(S*rq[c]*rk[d]*temp[h]). grid = 64.
// ---------------------------------------------------------------------------
__global__ __launch_bounds__(256) void postproc_kernel(
    const float* __restrict__ part, const float* __restrict__ rq,
    const float* __restrict__ rk, const float* __restrict__ bE,
    const float* __restrict__ temp, float* __restrict__ attn_t,
    float* __restrict__ kp, float* __restrict__ vp)
{
  __shared__ float sums[12288];
  const int bh = blockIdx.x;
  const int tid = threadIdx.x;
  for (int idx = tid; idx < 12288; idx += 256) {
    float s = 0.f;
    for (int ch = 0; ch < 8; ++ch)
      s += part[((size_t)ch * 64 + bh) * 12288 + idx];
    sums[idx] = s;
  }
  __syncthreads();
  for (int idx = tid; idx < 4096; idx += 256) {
    const int c = idx >> 6, p = idx & 63;
    kp[(size_t)bh * 4096 + idx] = sums[4096 + idx] * rk[bh * 64 + c] + bE[p];
    vp[(size_t)bh * 4096 + idx] = sums[8192 + idx] + bE[p];
  }
  const float tv = temp[bh & 3];
  const int lane = tid & 63, wv = tid >> 6;
  for (int ri = 0; ri < 16; ++ri) {
    const int c = wv * 16 + ri;
    const float val = sums[c * 64 + lane] * rq[bh * 64 + c] * rk[bh * 64 + lane] * tv;
    float m = val;
#pragma unroll
    for (int off = 32; off > 0; off >>= 1) m = fmaxf(m, __shfl_xor(m, off));
    const float e = __expf(val - m);
    float ssum = e;
#pragma unroll
    for (int off = 32; off > 0; off >>= 1) ssum += __shfl_xor(ssum, off);
    attn_t[(size_t)bh * 4096 + lane * 64 + c] = e / ssum;   // [d][c]
  }
}

// ---------------------------------------------------------------------------
// x_ca[c][n] = sum_d attn[c][d] * v_ca[d][n], written to [B,N,C] bf16.
// grid = (64 bh, 32 ntiles of 128).
// ---------------------------------------------------------------------------
__global__ __launch_bounds__(256) void xca_kernel(
    const float* __restrict__ attn_t, const unsigned short* __restrict__ vT,
    unsigned short* __restrict__ x_ca)
{
  __shared__ float at[64][68];
  __shared__ float vt[64][132];
  const int tid = threadIdx.x;
  const int bh = blockIdx.x, b = bh >> 2, h = bh & 3;
  const int n0 = blockIdx.y * 128;
  for (int i = tid; i < 1024; i += 256) {
    const float4 f = *reinterpret_cast<const float4*>(&attn_t[(size_t)bh * 4096 + i * 4]);
    *reinterpret_cast<float4*>(&at[i >> 4][(i * 4) & 63]) = f;
  }
  {
    const int d = tid >> 2, seg = tid & 3;
    const size_t rb = (size_t)(bh * 64 + d) * N_ + n0 + seg * 32;
#pragma unroll
    for (int t = 0; t < 4; ++t) {
      const uint4 u = *reinterpret_cast<const uint4*>(&vT[rb + t * 8]);
      float lo, hi;
      const int c0 = seg * 32 + t * 8;
      bfu2x2(u.x, lo, hi); vt[d][c0 + 0] = lo; vt[d][c0 + 1] = hi;
      bfu2x2(u.y, lo, hi); vt[d][c0 + 2] = lo; vt[d][c0 + 3] = hi;
      bfu2x2(u.z, lo, hi); vt[d][c0 + 4] = lo; vt[d][c0 + 5] = hi;
      bfu2x2(u.w, lo, hi); vt[d][c0 + 6] = lo; vt[d][c0 + 7] = hi;
    }
  }
  __syncthreads();
  const int cg = tid & 7, ng = tid >> 3;
  const int c0 = cg * 8, nl0 = ng * 4;
  float acc[4][8] = {};
  for (int d = 0; d < 64; ++d) {
    float a[8];
    *reinterpret_cast<float4*>(&a[0]) = *reinterpret_cast<const float4*>(&at[d][c0]);
    *reinterpret_cast<float4*>(&a[4]) = *reinterpret_cast<const float4*>(&at[d][c0 + 4]);
    const float4 vv = *reinterpret_cast<const float4*>(&vt[d][nl0]);
    const float vn[4] = {vv.x, vv.y, vv.z, vv.w};
#pragma unroll
    for (int n = 0; n < 4; ++n)
#pragma unroll
      for (int c = 0; c < 8; ++c) acc[n][c] += vn[n] * a[c];
  }
#pragma unroll
  for (int n = 0; n < 4; ++n) {
    union { uint4 v; unsigned short u[8]; } pk;
#pragma unroll
    for (int c = 0; c < 8; ++c) pk.u[c] = f2bfu(acc[n][c]);
    const int nn = n0 + nl0 + n;
    *reinterpret_cast<uint4*>(&x_ca[((size_t)b * N_ + nn) * 256 + h * 64 + c0]) = pk.v;
  }
}

// ---------------------------------------------------------------------------
// Spatial attention: per token, scores[p]=sum_c qn[c,n]*kp[c][p]; softmax_p;
// x_sa_t[b][d][h][n] = sum_p attn[p]*vp[d][p].  grid = (64 bh, 16 ntiles).
// ---------------------------------------------------------------------------
__global__ __launch_bounds__(256) void sa_kernel(
    const unsigned short* __restrict__ qT, const float* __restrict__ rq,
    const float* __restrict__ kp, const float* __restrict__ vp,
    const float* __restrict__ temp2, unsigned short* __restrict__ x_sa)
{
  __shared__ float kps[64][68];
  __shared__ float vps[64][68];
  __shared__ float rqs[64];
  const int tid = threadIdx.x;
  const int bh = blockIdx.x, b = bh >> 2, h = bh & 3;
  const int n = blockIdx.y * 256 + tid;
  for (int i = tid; i < 1024; i += 256) {
    const int r = i >> 4, c = (i * 4) & 63;
    *reinterpret_cast<float4*>(&kps[r][c]) =
        *reinterpret_cast<const float4*>(&kp[(size_t)bh * 4096 + i * 4]);
    *reinterpret_cast<float4*>(&vps[r][c]) =
        *reinterpret_cast<const float4*>(&vp[(size_t)bh * 4096 + i * 4]);
  }
  if (tid < 64) rqs[tid] = rq[bh * 64 + tid];
  __syncthreads();
  float sc[64];
#pragma unroll
  for (int p = 0; p < 64; ++p) sc[p] = 0.f;
  const size_t qcol = (size_t)(bh * 64) * N_ + n;
  for (int c = 0; c < 64; ++c) {
    const float qv = bfu2f(qT[qcol + (size_t)c * N_]) * rqs[c];
#pragma unroll
    for (int p4 = 0; p4 < 16; ++p4) {
      const float4 kv = *reinterpret_cast<const float4*>(&kps[c][p4 * 4]);
      sc[p4 * 4 + 0] += qv * kv.x;
      sc[p4 * 4 + 1] += qv * kv.y;
      sc[p4 * 4 + 2] += qv * kv.z;
      sc[p4 * 4 + 3] += qv * kv.w;
    }
  }
  const float t2 = temp2[h];
  float mx = -1e30f;
#pragma unroll
  for (int p = 0; p < 64; ++p) { sc[p] *= t2; mx = fmaxf(mx, sc[p]); }
  float ssum = 0.f;
#pragma unroll
  for (int p = 0; p < 64; ++p) { sc[p] = __expf(sc[p] - mx); ssum += sc[p]; }
  const float inv = 1.f / ssum;
  for (int d = 0; d < 64; ++d) {
    float o = 0.f;
#pragma unroll
    for (int p4 = 0; p4 < 16; ++p4) {
      const float4 vv = *reinterpret_cast<const float4*>(&vps[d][p4 * 4]);
      o += sc[p4 * 4 + 0] * vv.x + sc[p4 * 4 + 1] * vv.y +
           sc[p4 * 4 + 2] * vv.z + sc[p4 * 4 + 3] * vv.w;
    }
    x_sa[((size_t)(b * 64 + d) * 4 + h) * N_ + n] = f2bfu(o * inv);
  }
}

extern "C" void kernel_launch(void* const* d_in, const int* in_sizes, int n_in,
                              void* d_out, int out_size, void* d_ws, size_t ws_size,
                              hipStream_t stream)
{
  const float* x     = (const float*)d_in[0];
  const float* ref   = (const float*)d_in[1];
  const float* Wq    = (const float*)d_in[2];
  const float* bq    = (const float*)d_in[3];
  const float* Wkvv  = (const float*)d_in[4];
  const float* bkvv  = (const float*)d_in[5];
  const float* WE    = (const float*)d_in[6];
  const float* bE    = (const float*)d_in[7];
  const float* Wo1   = (const float*)d_in[8];
  const float* bo1   = (const float*)d_in[9];
  const float* Wo2   = (const float*)d_in[10];
  const float* bo2   = (const float*)d_in[11];
  const float* temp  = (const float*)d_in[12];
  const float* temp2 = (const float*)d_in[13];
  float* out = (float*)d_out;

  char* ws = (char*)d_ws;
  unsigned short* qT    = (unsigned short*)(ws);               // [4096][4096] bf16 (q, channel-major)
  unsigned short* kvvT  = (unsigned short*)(ws + 33554432);    // [3][4096][4096] bf16 (k, v_ca, v_sa)
  unsigned short* x_ca  = (unsigned short*)(ws + 134217728);   // [B,N,C] bf16
  unsigned short* x_sa  = (unsigned short*)(ws + 167772160);   // [B,hd,H,N] bf16
  float* rq     = (float*)(ws + 201326592);                    // [4096]
  float* rk     = (float*)(ws + 201342976);                    // [4096]
  float* part   = (float*)(ws + 201359360);                    // [8][64][3][64][64] f32
  float* attn_t = (float*)(ws + 226525184);                    // [64][64][64] f32  ([bh][d][c])
  float* kp     = (float*)(ws + 227573760);                    // [64][64][64] f32
  float* vp     = (float*)(ws + 228622336);                    // [64][64][64] f32
  unsigned short* wEb = (unsigned short*)(ws + 229670912);     // [64][4096] bf16
  // total ws usage: 230,195,200 bytes

  const dim3 blk(256);
  cvt_we<<<dim3(128), blk, 0, stream>>>(WE, wEb);
  gemm_projT<<<dim3(32, 2, 16), blk, 0, stream>>>(x, Wq, bq, qT);
  gemm_projT<<<dim3(32, 6, 16), blk, 0, stream>>>(ref, Wkvv, bkvv, kvvT);
  norm_kernel<<<dim3(8192), blk, 0, stream>>>(qT, kvvT, rq, rk);
  stats_mfma<<<dim3(64, 8), blk, 0, stream>>>(qT, kvvT, kvvT + 2 * QSZ, wEb, part);
  postproc_kernel<<<dim3(64), blk, 0, stream>>>(part, rq, rk, bE, temp, attn_t, kp, vp);
  xca_kernel<<<dim3(64, 32), blk, 0, stream>>>(attn_t, kvvT + QSZ, x_ca);
  sa_kernel<<<dim3(64, 16), blk, 0, stream>>>(qT, rq, kp, vp, temp2, x_sa);
  gemm_outm<<<dim3(512, 1, 2), blk, 0, stream>>>(x_sa, x_ca, Wo2, bo2, Wo1, bo1, out);
}

// Round 4
// 290.813 us; speedup vs baseline: 3.6899x; 1.2738x over previous
//
#include <hip/hip_runtime.h>
#include <hip/hip_bf16.h>

#define DI __device__ __forceinline__

constexpr int B_ = 16, N_ = 4096, C_ = 256, H_ = 4;
constexpr size_t QSZ = (size_t)4096 * 4096;   // elements in one [4096][4096] bf16 plane
constexpr int LDW = 72;    // LDS row stride (ushorts) for 64-wide bf16 tiles (bank-rotating)
constexpr int LDC = 136;   // LDS row stride (ushorts) for 128-wide epilogue tile (16B-aligned)

typedef __attribute__((ext_vector_type(8))) short bh8;
typedef __attribute__((ext_vector_type(4))) float fx4;

DI float bfu2f(unsigned short u) { return __uint_as_float(((unsigned)u) << 16); }
DI void bfu2x2(unsigned u, float& lo, float& hi) {
  lo = __uint_as_float(u << 16);
  hi = __uint_as_float(u & 0xffff0000u);
}
DI unsigned short f2bfu(float f) {   // RNE f32->bf16 (finite inputs)
  unsigned u = __float_as_uint(f);
  unsigned r = 0x7fffu + ((u >> 16) & 1u);
  return (unsigned short)((u + r) >> 16);
}

// ---------------------------------------------------------------------------
// MFMA projection GEMM, transposed output.
// OutT[j][tok] = sum_k W[j][k] * A[tok][k] + bias[j], written bf16 channel-major:
// rowT = ((j>>8)*16 + b)*256 + (j&255), col = n (token within batch).
// If qtok != null, also writes token-major q_tok[((b*4+h)*4096+n)*64 + c].
// grid = (ntile=32, jtile=ncols/128, b=16), block = 256 (4 waves, 2x2).
// ---------------------------------------------------------------------------
__global__ __launch_bounds__(256) void gemm_projT(
    const float* __restrict__ A, const float* __restrict__ W,
    const float* __restrict__ bias, unsigned short* __restrict__ outT,
    unsigned short* __restrict__ qtok)
{
  __shared__ unsigned short smem[2 * 128 * LDW];
  __shared__ float biasS[128];
  unsigned short* Ws = smem;
  unsigned short* Xs = smem + 128 * LDW;
  const int tid = threadIdx.x;
  const int lane = tid & 63, wid = tid >> 6;
  const int wr = wid >> 1, wc = wid & 1;
  const int n0 = blockIdx.x * 128;
  const int j0 = blockIdx.y * 128;
  const int b = blockIdx.z;
  const size_t tok0 = (size_t)b * 4096 + n0;
  if (tid < 128) biasS[tid] = bias[j0 + tid];

  fx4 acc[4][4];
#pragma unroll
  for (int m = 0; m < 4; ++m)
#pragma unroll
    for (int n = 0; n < 4; ++n) acc[m][n] = (fx4){0.f, 0.f, 0.f, 0.f};

  for (int k0 = 0; k0 < 256; k0 += 64) {
#pragma unroll
    for (int c = 0; c < 8; ++c) {
      const int idx = c * 256 + tid;     // 0..2047
      const int r = idx >> 4;            // 0..127
      const int ks = (idx & 15) << 2;    // 0..60
      const float4 wv = *reinterpret_cast<const float4*>(&W[(size_t)(j0 + r) * 256 + k0 + ks]);
      ushort4 pw;
      pw.x = f2bfu(wv.x); pw.y = f2bfu(wv.y); pw.z = f2bfu(wv.z); pw.w = f2bfu(wv.w);
      *reinterpret_cast<ushort4*>(&Ws[r * LDW + ks]) = pw;
      const float4 xv = *reinterpret_cast<const float4*>(&A[(tok0 + r) * 256 + k0 + ks]);
      ushort4 px;
      px.x = f2bfu(xv.x); px.y = f2bfu(xv.y); px.z = f2bfu(xv.z); px.w = f2bfu(xv.w);
      *reinterpret_cast<ushort4*>(&Xs[r * LDW + ks]) = px;
    }
    __syncthreads();
#pragma unroll
    for (int kk = 0; kk < 2; ++kk) {
      const int kb = kk * 32 + (lane >> 4) * 8;
      bh8 af[4], bfr[4];
#pragma unroll
      for (int m = 0; m < 4; ++m)
        af[m] = *reinterpret_cast<const bh8*>(&Ws[(wr * 64 + m * 16 + (lane & 15)) * LDW + kb]);
#pragma unroll
      for (int n = 0; n < 4; ++n)
        bfr[n] = *reinterpret_cast<const bh8*>(&Xs[(wc * 64 + n * 16 + (lane & 15)) * LDW + kb]);
#pragma unroll
      for (int m = 0; m < 4; ++m)
#pragma unroll
        for (int n = 0; n < 4; ++n)
          acc[m][n] = __builtin_amdgcn_mfma_f32_16x16x32_bf16(af[m], bfr[n], acc[m][n], 0, 0, 0);
    }
    __syncthreads();
  }

  // epilogue: acc -> bf16 LDS [128][128] (stride LDC), then coalesced store
  unsigned short* Co = smem;
#pragma unroll
  for (int m = 0; m < 4; ++m) {
    const int jl = wr * 64 + m * 16 + ((lane >> 4) << 2);
#pragma unroll
    for (int n = 0; n < 4; ++n) {
      const int col = wc * 64 + n * 16 + (lane & 15);
#pragma unroll
      for (int r = 0; r < 4; ++r)
        Co[(jl + r) * LDC + col] = f2bfu(acc[m][n][r] + biasS[jl + r]);
    }
  }
  __syncthreads();
#pragma unroll
  for (int c = 0; c < 8; ++c) {
    const int r = tid >> 1;
    const int colseg = (tid & 1) * 64 + c * 8;
    const uint4 v = *reinterpret_cast<const uint4*>(&Co[r * LDC + colseg]);
    const int jj = j0 + r;
    const int rowT = ((jj >> 8) * B_ + b) * 256 + (jj & 255);
    *reinterpret_cast<uint4*>(&outT[(size_t)rowT * N_ + n0 + colseg]) = v;
  }
  // optional token-major copy (for q): q_tok[((b*4+h)*4096 + n)*64 + c]
  if (qtok) {
#pragma unroll
    for (int i = 0; i < 8; ++i) {
      const int idx = i * 256 + tid;        // 0..2047
      const int col = idx & 127;            // token within tile
      const int cb = (idx >> 7) * 8;        // channel octet 0..120
      union { uint4 v; unsigned short u[8]; } pk;
#pragma unroll
      for (int t = 0; t < 8; ++t) pk.u[t] = Co[(cb + t) * LDC + col];
      const int jj = j0 + cb;
      const int hh = jj >> 6, cc = jj & 63;
      *reinterpret_cast<uint4*>(
          &qtok[(((size_t)b * 4 + hh) * 4096 + n0 + col) * 64 + cc]) = pk.v;
    }
  }
}

// ---------------------------------------------------------------------------
// MFMA output GEMM: z=0: out[:, :128] = x_sa_flat @ Wo2^T + bo2
//                   z=1: out[:, 128:] = x_ca      @ Wo1^T + bo1
// A operands already bf16 [65536][256]. grid = (512, 1, 2), block = 256.
// ---------------------------------------------------------------------------
__global__ __launch_bounds__(256) void gemm_outm(
    const unsigned short* __restrict__ Asa, const unsigned short* __restrict__ Aca,
    const float* __restrict__ Wo2, const float* __restrict__ bo2,
    const float* __restrict__ Wo1, const float* __restrict__ bo1,
    float* __restrict__ out)
{
  __shared__ unsigned short smem[2 * 128 * LDW];
  __shared__ float biasS[128];
  const unsigned short* A;
  const float* Wsrc; const float* bias; int joff;
  if (blockIdx.z == 0) { A = Asa; Wsrc = Wo2; bias = bo2; joff = 0; }
  else                 { A = Aca; Wsrc = Wo1; bias = bo1; joff = 128; }
  unsigned short* Ws = smem;
  unsigned short* Xs = smem + 128 * LDW;
  const int tid = threadIdx.x;
  const int lane = tid & 63, wid = tid >> 6;
  const int wr = wid >> 1, wc = wid & 1;
  const size_t m0 = (size_t)blockIdx.x * 128;
  if (tid < 128) biasS[tid] = bias[tid];

  fx4 acc[4][4];
#pragma unroll
  for (int m = 0; m < 4; ++m)
#pragma unroll
    for (int n = 0; n < 4; ++n) acc[m][n] = (fx4){0.f, 0.f, 0.f, 0.f};

  for (int k0 = 0; k0 < 256; k0 += 64) {
#pragma unroll
    for (int c = 0; c < 8; ++c) {       // W fp32 -> bf16, 128 rows x 64 k
      const int idx = c * 256 + tid;
      const int r = idx >> 4;
      const int ks = (idx & 15) << 2;
      const float4 wv = *reinterpret_cast<const float4*>(&Wsrc[(size_t)r * 256 + k0 + ks]);
      ushort4 pw;
      pw.x = f2bfu(wv.x); pw.y = f2bfu(wv.y); pw.z = f2bfu(wv.z); pw.w = f2bfu(wv.w);
      *reinterpret_cast<ushort4*>(&Ws[r * LDW + ks]) = pw;
    }
#pragma unroll
    for (int c = 0; c < 4; ++c) {       // A bf16 direct copy, 128 rows x 64 k
      const int idx = c * 256 + tid;    // 0..1023
      const int r = idx >> 3;
      const int ks = (idx & 7) << 3;
      const uint4 v = *reinterpret_cast<const uint4*>(&A[(m0 + r) * 256 + k0 + ks]);
      *reinterpret_cast<uint4*>(&Xs[r * LDW + ks]) = v;
    }
    __syncthreads();
#pragma unroll
    for (int kk = 0; kk < 2; ++kk) {
      const int kb = kk * 32 + (lane >> 4) * 8;
      bh8 af[4], bfr[4];
#pragma unroll
      for (int m = 0; m < 4; ++m)   // A-frag = tokens (D-row side)
        af[m] = *reinterpret_cast<const bh8*>(&Xs[(wr * 64 + m * 16 + (lane & 15)) * LDW + kb]);
#pragma unroll
      for (int n = 0; n < 4; ++n)   // B-frag = W (D-col side)
        bfr[n] = *reinterpret_cast<const bh8*>(&Ws[(wc * 64 + n * 16 + (lane & 15)) * LDW + kb]);
#pragma unroll
      for (int m = 0; m < 4; ++m)
#pragma unroll
        for (int n = 0; n < 4; ++n)
          acc[m][n] = __builtin_amdgcn_mfma_f32_16x16x32_bf16(af[m], bfr[n], acc[m][n], 0, 0, 0);
    }
    __syncthreads();
  }

#pragma unroll
  for (int mi = 0; mi < 4; ++mi) {
    const int mrow = wr * 64 + mi * 16 + ((lane >> 4) << 2);
#pragma unroll
    for (int ni = 0; ni < 4; ++ni) {
      const int j = wc * 64 + ni * 16 + (lane & 15);
      const float bv = biasS[j];
#pragma unroll
      for (int r = 0; r < 4; ++r)
        out[(m0 + mrow + r) * 256 + joff + j] = acc[mi][ni][r] + bv;
    }
  }
}

// ---------------------------------------------------------------------------
// WE fp32 -> bf16 plane (64 x 4096). grid = 128, block = 256, 8 elems/thread.
// ---------------------------------------------------------------------------
__global__ __launch_bounds__(256) void cvt_we(
    const float* __restrict__ WE, unsigned short* __restrict__ wEb)
{
  const int idx = blockIdx.x * 256 + threadIdx.x;
  const float4 a = *reinterpret_cast<const float4*>(&WE[(size_t)idx * 8]);
  const float4 b = *reinterpret_cast<const float4*>(&WE[(size_t)idx * 8 + 4]);
  union { uint4 v; unsigned short u[8]; } pk;
  pk.u[0] = f2bfu(a.x); pk.u[1] = f2bfu(a.y); pk.u[2] = f2bfu(a.z); pk.u[3] = f2bfu(a.w);
  pk.u[4] = f2bfu(b.x); pk.u[5] = f2bfu(b.y); pk.u[6] = f2bfu(b.z); pk.u[7] = f2bfu(b.w);
  *reinterpret_cast<uint4*>(&wEb[(size_t)idx * 8]) = pk.v;
}

// ---------------------------------------------------------------------------
// Per-channel 1/max(||row||,eps) over N tokens. blocks 0..4095 -> qT rows,
// 4096..8191 -> kT rows.
// ---------------------------------------------------------------------------
__global__ __launch_bounds__(256) void norm_kernel(
    const unsigned short* __restrict__ qT, const unsigned short* __restrict__ kT,
    float* __restrict__ rq, float* __restrict__ rk)
{
  const int row = blockIdx.x;
  const unsigned short* src = (row < 4096) ? (qT + (size_t)row * N_)
                                           : (kT + (size_t)(row - 4096) * N_);
  float s = 0.f;
  for (int i = threadIdx.x; i < N_ / 8; i += 256) {
    const uint4 u = *reinterpret_cast<const uint4*>(&src[i * 8]);
    float a, b;
    bfu2x2(u.x, a, b); s += a * a + b * b;
    bfu2x2(u.y, a, b); s += a * a + b * b;
    bfu2x2(u.z, a, b); s += a * a + b * b;
    bfu2x2(u.w, a, b); s += a * a + b * b;
  }
#pragma unroll
  for (int off = 32; off > 0; off >>= 1) s += __shfl_xor(s, off);
  __shared__ float ws4[4];
  if ((threadIdx.x & 63) == 0) ws4[threadIdx.x >> 6] = s;
  __syncthreads();
  if (threadIdx.x == 0) {
    const float tot = ws4[0] + ws4[1] + ws4[2] + ws4[3];
    const float r = 1.f / fmaxf(sqrtf(tot), 1e-12f);
    (row < 4096 ? rq : rk)[row & 4095] = r;
  }
}

// ---------------------------------------------------------------------------
// MFMA stats: per (bh, chunk of 512 tokens), three 64x64 partial GEMMs over
// tokens: wave0: S=q.k^T; wave1: KpT=WE.k^T; wave2: Vp=v.WE^T; wave3 stages.
// part[chunk][bh][3][64][64]. grid = (64, 8), block = 256.
// ---------------------------------------------------------------------------
__global__ __launch_bounds__(256) void stats_mfma(
    const unsigned short* __restrict__ qT, const unsigned short* __restrict__ kT,
    const unsigned short* __restrict__ vT, const unsigned short* __restrict__ wEb,
    float* __restrict__ part)
{
  __shared__ unsigned short smem[4 * 64 * LDW];
  unsigned short* sq = smem;
  unsigned short* sk = smem + 64 * LDW;
  unsigned short* sv = smem + 2 * 64 * LDW;
  unsigned short* sw = smem + 3 * 64 * LDW;
  const int tid = threadIdx.x;
  const int lane = tid & 63, wid = tid >> 6;
  const int bh = blockIdx.x, chunk = blockIdx.y;
  const size_t rowbase = (size_t)bh * 64 * N_;

  fx4 acc[4][4];
#pragma unroll
  for (int m = 0; m < 4; ++m)
#pragma unroll
    for (int n = 0; n < 4; ++n) acc[m][n] = (fx4){0.f, 0.f, 0.f, 0.f};

  const unsigned short* Aop = (wid == 1) ? sw : (wid == 2) ? sv : sq;
  const unsigned short* Bop = (wid == 1) ? sk : (wid == 2) ? sw : sk;

  for (int tile = 0; tile < 8; ++tile) {
    const int n0 = chunk * 512 + tile * 64;
#pragma unroll
    for (int c = 0; c < 2; ++c) {
      const int idx = c * 256 + tid;       // 0..511
      const int r = idx >> 3;              // 0..63
      const int off = (idx & 7) * 8;       // 0..56
      *reinterpret_cast<uint4*>(&sq[r * LDW + off]) =
          *reinterpret_cast<const uint4*>(&qT[rowbase + (size_t)r * N_ + n0 + off]);
      *reinterpret_cast<uint4*>(&sk[r * LDW + off]) =
          *reinterpret_cast<const uint4*>(&kT[rowbase + (size_t)r * N_ + n0 + off]);
      *reinterpret_cast<uint4*>(&sv[r * LDW + off]) =
          *reinterpret_cast<const uint4*>(&vT[rowbase + (size_t)r * N_ + n0 + off]);
      *reinterpret_cast<uint4*>(&sw[r * LDW + off]) =
          *reinterpret_cast<const uint4*>(&wEb[(size_t)r * N_ + n0 + off]);
    }
    __syncthreads();
    if (wid < 3) {
#pragma unroll
      for (int kk = 0; kk < 2; ++kk) {
        const int kb = kk * 32 + (lane >> 4) * 8;
        bh8 af[4], bfr[4];
#pragma unroll
        for (int m = 0; m < 4; ++m)
          af[m] = *reinterpret_cast<const bh8*>(&Aop[(m * 16 + (lane & 15)) * LDW + kb]);
#pragma unroll
        for (int n = 0; n < 4; ++n)
          bfr[n] = *reinterpret_cast<const bh8*>(&Bop[(n * 16 + (lane & 15)) * LDW + kb]);
#pragma unroll
        for (int m = 0; m < 4; ++m)
#pragma unroll
          for (int n = 0; n < 4; ++n)
            acc[m][n] = __builtin_amdgcn_mfma_f32_16x16x32_bf16(af[m], bfr[n], acc[m][n], 0, 0, 0);
      }
    }
    __syncthreads();
  }

  if (wid < 3) {
    float* base = &part[(((size_t)chunk * 64 + bh) * 3 + wid) * 4096];
#pragma unroll
    for (int m = 0; m < 4; ++m) {
      const int row0 = m * 16 + ((lane >> 4) << 2);
#pragma unroll
      for (int n = 0; n < 4; ++n) {
        const int col = n * 16 + (lane & 15);
#pragma unroll
        for (int r = 0; r < 4; ++r)
          base[(row0 + r) * 64 + col] = acc[m][n][r];
      }
    }
  }
}

// ---------------------------------------------------------------------------
// Reduce partials; emit bf16 kp2t[p][c] = (KpT*rk[c] + bE[p])*rq[c]*temp2[h],
// bf16 vpb[d][p] = Vp + bE[p], and channel-attention softmax
// attn_t[bh][d][c] = softmax_d(S*rq[c]*rk[d]*temp[h]). grid = 64.
// ---------------------------------------------------------------------------
__global__ __launch_bounds__(256) void postproc_kernel(
    const float* __restrict__ part, const float* __restrict__ rq,
    const float* __restrict__ rk, const float* __restrict__ bE,
    const float* __restrict__ temp, const float* __restrict__ temp2,
    float* __restrict__ attn_t,
    unsigned short* __restrict__ kp2t, unsigned short* __restrict__ vpb)
{
  __shared__ float sums[12288];
  const int bh = blockIdx.x;
  const int tid = threadIdx.x;
  for (int idx = tid; idx < 12288; idx += 256) {
    float s = 0.f;
    for (int ch = 0; ch < 8; ++ch)
      s += part[((size_t)ch * 64 + bh) * 12288 + idx];
    sums[idx] = s;
  }
  __syncthreads();
  const float t2 = temp2[bh & 3];
  for (int idx = tid; idx < 4096; idx += 256) {
    const int p = idx >> 6, c = idx & 63;
    kp2t[(size_t)bh * 4096 + idx] =
        f2bfu((sums[4096 + idx] * rk[bh * 64 + c] + bE[p]) * rq[bh * 64 + c] * t2);
    vpb[(size_t)bh * 4096 + idx] = f2bfu(sums[8192 + idx] + bE[idx & 63]);
  }
  const float tv = temp[bh & 3];
  const int lane = tid & 63, wv = tid >> 6;
  for (int ri = 0; ri < 16; ++ri) {
    const int c = wv * 16 + ri;
    const float val = sums[c * 64 + lane] * rq[bh * 64 + c] * rk[bh * 64 + lane] * tv;
    float m = val;
#pragma unroll
    for (int off = 32; off > 0; off >>= 1) m = fmaxf(m, __shfl_xor(m, off));
    const float e = __expf(val - m);
    float ssum = e;
#pragma unroll
    for (int off = 32; off > 0; off >>= 1) ssum += __shfl_xor(ssum, off);
    attn_t[(size_t)bh * 4096 + lane * 64 + c] = e / ssum;   // [d][c]
  }
}

// ---------------------------------------------------------------------------
// MFMA spatial attention. Per wave: 64 tokens. GEMM1 S=q_tok·kp2t^T (K=c),
// in-register softmax over p, P(bf16)->LDS, GEMM2 out=P·vpb^T (K=p),
// transpose-store via stride-65 LDS to x_sa[b][d][h][n].
// grid = (64 bh, 16), block = 256 (4 waves).
// ---------------------------------------------------------------------------
__global__ __launch_bounds__(256) void sa_mfma(
    const unsigned short* __restrict__ qtok, const unsigned short* __restrict__ kp2t,
    const unsigned short* __restrict__ vpb, unsigned short* __restrict__ x_sa)
{
  __shared__ unsigned short skp[64 * LDW];
  __shared__ unsigned short svp[64 * LDW];
  __shared__ unsigned short pt[4][64 * LDW];
  const int tid = threadIdx.x;
  const int lane = tid & 63, wid = tid >> 6;
  const int l15 = lane & 15, l4 = lane >> 4;
  const int bh = blockIdx.x, b = bh >> 2, h = bh & 3;
  const int n0 = blockIdx.y * 256 + wid * 64;
  unsigned short* myp = &pt[wid][0];

#pragma unroll
  for (int i = 0; i < 2; ++i) {
    const int idx = i * 256 + tid;       // 0..511
    const int r = idx >> 3, off = (idx & 7) * 8;
    *reinterpret_cast<uint4*>(&skp[r * LDW + off]) =
        *reinterpret_cast<const uint4*>(&kp2t[(size_t)bh * 4096 + r * 64 + off]);
    *reinterpret_cast<uint4*>(&svp[r * LDW + off]) =
        *reinterpret_cast<const uint4*>(&vpb[(size_t)bh * 4096 + r * 64 + off]);
  }
  __syncthreads();

  // GEMM1: S[n][p]
  fx4 acc[4][4];
#pragma unroll
  for (int m = 0; m < 4; ++m)
#pragma unroll
    for (int j = 0; j < 4; ++j) acc[m][j] = (fx4){0.f, 0.f, 0.f, 0.f};
  const size_t qbase = ((size_t)bh * 4096 + n0) * 64;
#pragma unroll
  for (int kk = 0; kk < 2; ++kk) {
    const int kb = kk * 32 + l4 * 8;
    bh8 af[4], bf[4];
#pragma unroll
    for (int m = 0; m < 4; ++m)
      af[m] = *reinterpret_cast<const bh8*>(&qtok[qbase + (size_t)(m * 16 + l15) * 64 + kb]);
#pragma unroll
    for (int j = 0; j < 4; ++j)
      bf[j] = *reinterpret_cast<const bh8*>(&skp[(j * 16 + l15) * LDW + kb]);
#pragma unroll
    for (int m = 0; m < 4; ++m)
#pragma unroll
      for (int j = 0; j < 4; ++j)
        acc[m][j] = __builtin_amdgcn_mfma_f32_16x16x32_bf16(af[m], bf[j], acc[m][j], 0, 0, 0);
  }

  // softmax over p per row (row n = m*16 + l4*4 + r; col p = j*16 + l15)
  fx4 inv[4];
#pragma unroll
  for (int m = 0; m < 4; ++m) {
    fx4 vm = acc[m][0];
#pragma unroll
    for (int j = 1; j < 4; ++j)
#pragma unroll
      for (int r = 0; r < 4; ++r) vm[r] = fmaxf(vm[r], acc[m][j][r]);
#pragma unroll
    for (int msk = 1; msk < 16; msk <<= 1)
#pragma unroll
      for (int r = 0; r < 4; ++r) vm[r] = fmaxf(vm[r], __shfl_xor(vm[r], msk));
    fx4 s = (fx4){0.f, 0.f, 0.f, 0.f};
#pragma unroll
    for (int j = 0; j < 4; ++j)
#pragma unroll
      for (int r = 0; r < 4; ++r) {
        acc[m][j][r] = __expf(acc[m][j][r] - vm[r]);
        s[r] += acc[m][j][r];
      }
#pragma unroll
    for (int msk = 1; msk < 16; msk <<= 1)
#pragma unroll
      for (int r = 0; r < 4; ++r) s[r] += __shfl_xor(s[r], msk);
#pragma unroll
    for (int r = 0; r < 4; ++r) inv[m][r] = 1.f / s[r];
#pragma unroll
    for (int j = 0; j < 4; ++j)
#pragma unroll
      for (int r = 0; r < 4; ++r)
        myp[(m * 16 + l4 * 4 + r) * LDW + j * 16 + l15] = f2bfu(acc[m][j][r]);
  }

  // GEMM2: O[n][d] = P·vpb^T (per-wave private LDS; in-order DS, no barrier)
  fx4 acc2[4][4];
#pragma unroll
  for (int m = 0; m < 4; ++m)
#pragma unroll
    for (int j = 0; j < 4; ++j) acc2[m][j] = (fx4){0.f, 0.f, 0.f, 0.f};
#pragma unroll
  for (int kk = 0; kk < 2; ++kk) {
    const int kb = kk * 32 + l4 * 8;
    bh8 af[4], bf[4];
#pragma unroll
    for (int m = 0; m < 4; ++m)
      af[m] = *reinterpret_cast<const bh8*>(&myp[(m * 16 + l15) * LDW + kb]);
#pragma unroll
    for (int j = 0; j < 4; ++j)
      bf[j] = *reinterpret_cast<const bh8*>(&svp[(j * 16 + l15) * LDW + kb]);
#pragma unroll
    for (int m = 0; m < 4; ++m)
#pragma unroll
      for (int j = 0; j < 4; ++j)
        acc2[m][j] = __builtin_amdgcn_mfma_f32_16x16x32_bf16(af[m], bf[j], acc2[m][j], 0, 0, 0);
  }

  // epilogue: apply 1/sum per row, bf16 -> LDS [n][d] stride 65, store d-major
#pragma unroll
  for (int m = 0; m < 4; ++m)
#pragma unroll
    for (int j = 0; j < 4; ++j)
#pragma unroll
      for (int r = 0; r < 4; ++r)
        myp[(m * 16 + l4 * 4 + r) * 65 + j * 16 + l15] = f2bfu(acc2[m][j][r] * inv[m][r]);
#pragma unroll
  for (int dstep = 0; dstep < 8; ++dstep) {
    const int d = dstep * 8 + (lane >> 3);
    const int nseg = (lane & 7) * 8;
    union { uint4 v; unsigned short u[8]; } pk;
#pragma unroll
    for (int t = 0; t < 8; ++t) pk.u[t] = myp[(nseg + t) * 65 + d];
    *reinterpret_cast<uint4*>(
        &x_sa[((size_t)(b * 64 + d) * 4 + h) * (size_t)N_ + n0 + nseg]) = pk.v;
  }
}

// ---------------------------------------------------------------------------
// x_ca[c][n] = sum_d attn[c][d] * v_ca[d][n], written to [B,N,C] bf16.
// grid = (64 bh, 32 ntiles of 128).
// ---------------------------------------------------------------------------
__global__ __launch_bounds__(256) void xca_kernel(
    const float* __restrict__ attn_t, const unsigned short* __restrict__ vT,
    unsigned short* __restrict__ x_ca)
{
  __shared__ float at[64][68];
  __shared__ float vt[64][132];
  const int tid = threadIdx.x;
  const int bh = blockIdx.x, b = bh >> 2, h = bh & 3;
  const int n0 = blockIdx.y * 128;
  for (int i = tid; i < 1024; i += 256) {
    const float4 f = *reinterpret_cast<const float4*>(&attn_t[(size_t)bh * 4096 + i * 4]);
    *reinterpret_cast<float4*>(&at[i >> 4][(i * 4) & 63]) = f;
  }
  {
    const int d = tid >> 2, seg = tid & 3;
    const size_t rb = (size_t)(bh * 64 + d) * N_ + n0 + seg * 32;
#pragma unroll
    for (int t = 0; t < 4; ++t) {
      const uint4 u = *reinterpret_cast<const uint4*>(&vT[rb + t * 8]);
      float lo, hi;
      const int c0 = seg * 32 + t * 8;
      bfu2x2(u.x, lo, hi); vt[d][c0 + 0] = lo; vt[d][c0 + 1] = hi;
      bfu2x2(u.y, lo, hi); vt[d][c0 + 2] = lo; vt[d][c0 + 3] = hi;
      bfu2x2(u.z, lo, hi); vt[d][c0 + 4] = lo; vt[d][c0 + 5] = hi;
      bfu2x2(u.w, lo, hi); vt[d][c0 + 6] = lo; vt[d][c0 + 7] = hi;
    }
  }
  __syncthreads();
  const int cg = tid & 7, ng = tid >> 3;
  const int c0 = cg * 8, nl0 = ng * 4;
  float acc[4][8] = {};
  for (int d = 0; d < 64; ++d) {
    float a[8];
    *reinterpret_cast<float4*>(&a[0]) = *reinterpret_cast<const float4*>(&at[d][c0]);
    *reinterpret_cast<float4*>(&a[4]) = *reinterpret_cast<const float4*>(&at[d][c0 + 4]);
    const float4 vv = *reinterpret_cast<const float4*>(&vt[d][nl0]);
    const float vn[4] = {vv.x, vv.y, vv.z, vv.w};
#pragma unroll
    for (int n = 0; n < 4; ++n)
#pragma unroll
      for (int c = 0; c < 8; ++c) acc[n][c] += vn[n] * a[c];
  }
#pragma unroll
  for (int n = 0; n < 4; ++n) {
    union { uint4 v; unsigned short u[8]; } pk;
#pragma unroll
    for (int c = 0; c < 8; ++c) pk.u[c] = f2bfu(acc[n][c]);
    const int nn = n0 + nl0 + n;
    *reinterpret_cast<uint4*>(&x_ca[((size_t)b * N_ + nn) * 256 + h * 64 + c0]) = pk.v;
  }
}

extern "C" void kernel_launch(void* const* d_in, const int* in_sizes, int n_in,
                              void* d_out, int out_size, void* d_ws, size_t ws_size,
                              hipStream_t stream)
{
  const float* x     = (const float*)d_in[0];
  const float* ref   = (const float*)d_in[1];
  const float* Wq    = (const float*)d_in[2];
  const float* bq    = (const float*)d_in[3];
  const float* Wkvv  = (const float*)d_in[4];
  const float* bkvv  = (const float*)d_in[5];
  const float* WE    = (const float*)d_in[6];
  const float* bE    = (const float*)d_in[7];
  const float* Wo1   = (const float*)d_in[8];
  const float* bo1   = (const float*)d_in[9];
  const float* Wo2   = (const float*)d_in[10];
  const float* bo2   = (const float*)d_in[11];
  const float* temp  = (const float*)d_in[12];
  const float* temp2 = (const float*)d_in[13];
  float* out = (float*)d_out;

  char* ws = (char*)d_ws;
  unsigned short* qT    = (unsigned short*)(ws);               // [4096][4096] bf16 (q, channel-major)
  unsigned short* kvvT  = (unsigned short*)(ws + 33554432);    // [3][4096][4096] bf16 (k, v_ca, v_sa)
  unsigned short* qtok  = (unsigned short*)(ws + 134217728);   // [64bh][4096][64] bf16; later x_ca
  unsigned short* x_ca  = (unsigned short*)(ws + 134217728);   // [B,N,C] bf16 (aliases qtok; sa runs first)
  unsigned short* x_sa  = (unsigned short*)(ws + 167772160);   // [B,hd,H,N] bf16
  float* rq     = (float*)(ws + 201326592);                    // [4096]
  float* rk     = (float*)(ws + 201342976);                    // [4096]
  float* part   = (float*)(ws + 201359360);                    // [8][64][3][64][64] f32
  float* attn_t = (float*)(ws + 226525184);                    // [64][64][64] f32  ([bh][d][c])
  unsigned short* kp2t = (unsigned short*)(ws + 227573760);    // [64bh][64p][64c] bf16
  unsigned short* vpb  = (unsigned short*)(ws + 228622336);    // [64bh][64d][64p] bf16
  unsigned short* wEb  = (unsigned short*)(ws + 229670912);    // [64][4096] bf16
  // total ws usage: 230,195,200 bytes

  const dim3 blk(256);
  cvt_we<<<dim3(128), blk, 0, stream>>>(WE, wEb);
  gemm_projT<<<dim3(32, 2, 16), blk, 0, stream>>>(x, Wq, bq, qT, qtok);
  gemm_projT<<<dim3(32, 6, 16), blk, 0, stream>>>(ref, Wkvv, bkvv, kvvT, nullptr);
  norm_kernel<<<dim3(8192), blk, 0, stream>>>(qT, kvvT, rq, rk);
  stats_mfma<<<dim3(64, 8), blk, 0, stream>>>(qT, kvvT, kvvT + 2 * QSZ, wEb, part);
  postproc_kernel<<<dim3(64), blk, 0, stream>>>(part, rq, rk, bE, temp, temp2, attn_t, kp2t, vpb);
  sa_mfma<<<dim3(64, 16), blk, 0, stream>>>(qtok, kp2t, vpb, x_sa);
  xca_kernel<<<dim3(64, 32), blk, 0, stream>>>(attn_t, kvvT + QSZ, x_ca);
  gemm_outm<<<dim3(512, 1, 2), blk, 0, stream>>>(x_sa, x_ca, Wo2, bo2, Wo1, bo1, out);
}

// Round 5
// 275.619 us; speedup vs baseline: 3.8934x; 1.0551x over previous
//
#include <hip/hip_runtime.h>
#include <hip/hip_bf16.h>

#define DI __device__ __forceinline__

constexpr int B_ = 16, N_ = 4096, C_ = 256, H_ = 4;
constexpr size_t QSZ = (size_t)4096 * 4096;   // elements in one [4096][4096] bf16 plane
constexpr int LDW = 72;    // LDS row stride (ushorts) for 64-wide bf16 tiles (bank-rotating)
constexpr int LDC = 136;   // LDS row stride (ushorts) for 128-wide epilogue tile (16B-aligned)

typedef __attribute__((ext_vector_type(8))) short bh8;
typedef __attribute__((ext_vector_type(4))) float fx4;
typedef __attribute__((address_space(1))) unsigned int gu32;
typedef __attribute__((address_space(3))) unsigned int lu32;

DI float bfu2f(unsigned short u) { return __uint_as_float(((unsigned)u) << 16); }
DI void bfu2x2(unsigned u, float& lo, float& hi) {
  lo = __uint_as_float(u << 16);
  hi = __uint_as_float(u & 0xffff0000u);
}
DI unsigned short f2bfu(float f) {   // RNE f32->bf16 (finite inputs)
  unsigned u = __float_as_uint(f);
  unsigned r = 0x7fffu + ((u >> 16) & 1u);
  return (unsigned short)((u + r) >> 16);
}
DI void gl_lds16(const unsigned short* g, unsigned short* l) {
  // async 16B/lane global->LDS; LDS dest = wave-uniform base + lane*16
  __builtin_amdgcn_global_load_lds((gu32*)g, (lu32*)l, 16, 0, 0);
}

// ---------------------------------------------------------------------------
// fp32 -> bf16 casts. cast_xref: grid 16384 (x first 8192 blocks, ref next).
// ---------------------------------------------------------------------------
__global__ __launch_bounds__(256) void cast_xref(
    const float* __restrict__ x, const float* __restrict__ ref,
    unsigned short* __restrict__ xb, unsigned short* __restrict__ refb)
{
  const int bid = blockIdx.x;
  const float* src = (bid < 8192) ? x : ref;
  unsigned short* dst = (bid < 8192) ? xb : refb;
  const size_t base = ((size_t)(bid & 8191) * 256 + threadIdx.x) * 8;
  const float4 a = *reinterpret_cast<const float4*>(&src[base]);
  const float4 b = *reinterpret_cast<const float4*>(&src[base + 4]);
  union { uint4 v; unsigned short u[8]; } pk;
  pk.u[0] = f2bfu(a.x); pk.u[1] = f2bfu(a.y); pk.u[2] = f2bfu(a.z); pk.u[3] = f2bfu(a.w);
  pk.u[4] = f2bfu(b.x); pk.u[5] = f2bfu(b.y); pk.u[6] = f2bfu(b.z); pk.u[7] = f2bfu(b.w);
  *reinterpret_cast<uint4*>(&dst[base]) = pk.v;
}

// Wb layout (ushorts): Wq@0 (65536), Wkvv@65536 (196608), Wo2@262144 (32768),
// Wo1@294912 (32768). WE -> wEb [64][4096]. grid = 288.
__global__ __launch_bounds__(256) void cast_w(
    const float* __restrict__ Wq, const float* __restrict__ Wkvv,
    const float* __restrict__ Wo2, const float* __restrict__ Wo1,
    const float* __restrict__ WE, unsigned short* __restrict__ Wb,
    unsigned short* __restrict__ wEb)
{
  const int b = blockIdx.x;
  const float* src; unsigned short* dst; int lb;
  if (b < 32)       { src = Wq;   dst = Wb;          lb = b; }
  else if (b < 128) { src = Wkvv; dst = Wb + 65536;  lb = b - 32; }
  else if (b < 144) { src = Wo2;  dst = Wb + 262144; lb = b - 128; }
  else if (b < 160) { src = Wo1;  dst = Wb + 294912; lb = b - 144; }
  else              { src = WE;   dst = wEb;         lb = b - 160; }
  const size_t base = ((size_t)lb * 256 + threadIdx.x) * 8;
  const float4 a = *reinterpret_cast<const float4*>(&src[base]);
  const float4 bb = *reinterpret_cast<const float4*>(&src[base + 4]);
  union { uint4 v; unsigned short u[8]; } pk;
  pk.u[0] = f2bfu(a.x);  pk.u[1] = f2bfu(a.y);  pk.u[2] = f2bfu(a.z);  pk.u[3] = f2bfu(a.w);
  pk.u[4] = f2bfu(bb.x); pk.u[5] = f2bfu(bb.y); pk.u[6] = f2bfu(bb.z); pk.u[7] = f2bfu(bb.w);
  *reinterpret_cast<uint4*>(&dst[base]) = pk.v;
}

// ---------------------------------------------------------------------------
// All-bf16 MFMA projection GEMM (global_load_lds + XOR-swizzled staging).
// OutT[j][tok] = sum_k W[j][k]*A[tok][k] + bias[j], bf16 channel-major:
// rowT = ((j>>8)*16 + b)*256 + (j&255), col = n. Optional token-major qtok.
// grid = (32 ntiles, ncols/128, 16 b), block = 256 (4 waves, 2x2).
// LDS tiles packed [128][64]; element colblock cb stored at cb^(row&7).
// ---------------------------------------------------------------------------
__global__ __launch_bounds__(256) void gemm_projT2(
    const unsigned short* __restrict__ Ab, const unsigned short* __restrict__ Wb,
    const float* __restrict__ bias, unsigned short* __restrict__ outT,
    unsigned short* __restrict__ qtok)
{
  __shared__ unsigned short smem[128 * LDC];   // 34816 B; staging uses first 32KB
  __shared__ float biasS[128];
  unsigned short* Ws = smem;
  unsigned short* Xs = smem + 128 * 64;
  const int tid = threadIdx.x;
  const int lane = tid & 63, wid = tid >> 6;
  const int l15 = lane & 15, l4 = lane >> 4;
  const int wr = wid >> 1, wc = wid & 1;
  const int n0 = blockIdx.x * 128;
  const int j0 = blockIdx.y * 128;
  const int b = blockIdx.z;
  const size_t tok0 = (size_t)b * 4096 + n0;
  const int lrow = lane >> 3, lcb = lane & 7;
  if (tid < 128) biasS[tid] = bias[j0 + tid];

  fx4 acc[4][4];
#pragma unroll
  for (int m = 0; m < 4; ++m)
#pragma unroll
    for (int n = 0; n < 4; ++n) acc[m][n] = (fx4){0.f, 0.f, 0.f, 0.f};

  for (int k0 = 0; k0 < 256; k0 += 64) {
#pragma unroll
    for (int i = 0; i < 4; ++i) {
      const int ci = i * 4 + wid;            // chunk 0..15 (8 rows each)
      const int row = ci * 8 + lrow;         // 0..127
      const int scb = lcb ^ (row & 7);       // pre-swizzled source col-block
      gl_lds16(&Wb[(size_t)(j0 + row) * 256 + k0 + scb * 8], &Ws[ci * 512]);
      gl_lds16(&Ab[(tok0 + row) * 256 + k0 + scb * 8], &Xs[ci * 512]);
    }
    __syncthreads();
#pragma unroll
    for (int kk = 0; kk < 2; ++kk) {
      const int cbi = kk * 4 + l4;           // col-block index 0..7
      bh8 af[4], bfr[4];
#pragma unroll
      for (int m = 0; m < 4; ++m) {
        const int r = wr * 64 + m * 16 + l15;
        af[m] = *reinterpret_cast<const bh8*>(&Ws[r * 64 + ((cbi ^ (r & 7)) << 3)]);
      }
#pragma unroll
      for (int n = 0; n < 4; ++n) {
        const int r = wc * 64 + n * 16 + l15;
        bfr[n] = *reinterpret_cast<const bh8*>(&Xs[r * 64 + ((cbi ^ (r & 7)) << 3)]);
      }
#pragma unroll
      for (int m = 0; m < 4; ++m)
#pragma unroll
        for (int n = 0; n < 4; ++n)
          acc[m][n] = __builtin_amdgcn_mfma_f32_16x16x32_bf16(af[m], bfr[n], acc[m][n], 0, 0, 0);
    }
    __syncthreads();
  }

  // epilogue: acc -> bf16 LDS [128][128] (stride LDC), then coalesced store
  unsigned short* Co = smem;
#pragma unroll
  for (int m = 0; m < 4; ++m) {
    const int jl = wr * 64 + m * 16 + (l4 << 2);
#pragma unroll
    for (int n = 0; n < 4; ++n) {
      const int col = wc * 64 + n * 16 + l15;
#pragma unroll
      for (int r = 0; r < 4; ++r)
        Co[(jl + r) * LDC + col] = f2bfu(acc[m][n][r] + biasS[jl + r]);
    }
  }
  __syncthreads();
#pragma unroll
  for (int c = 0; c < 8; ++c) {
    const int r = tid >> 1;
    const int colseg = (tid & 1) * 64 + c * 8;
    const uint4 v = *reinterpret_cast<const uint4*>(&Co[r * LDC + colseg]);
    const int jj = j0 + r;
    const int rowT = ((jj >> 8) * B_ + b) * 256 + (jj & 255);
    *reinterpret_cast<uint4*>(&outT[(size_t)rowT * N_ + n0 + colseg]) = v;
  }
  // optional token-major copy (for q): q_tok[((b*4+h)*4096 + n)*64 + c]
  if (qtok) {
#pragma unroll
    for (int i = 0; i < 8; ++i) {
      const int idx = i * 256 + tid;        // 0..2047
      const int col = idx & 127;            // token within tile
      const int cb = (idx >> 7) * 8;        // channel octet 0..120
      union { uint4 v; unsigned short u[8]; } pk;
#pragma unroll
      for (int t = 0; t < 8; ++t) pk.u[t] = Co[(cb + t) * LDC + col];
      const int jj = j0 + cb;
      const int hh = jj >> 6, cc = jj & 63;
      *reinterpret_cast<uint4*>(
          &qtok[(((size_t)b * 4 + hh) * 4096 + n0 + col) * 64 + cc]) = pk.v;
    }
  }
}

// ---------------------------------------------------------------------------
// All-bf16 MFMA output GEMM: z=0: out[:, :128] = Asa @ Wo2^T + bo2
//                            z=1: out[:, 128:] = Aca @ Wo1^T + bo1
// Wob = bf16 [Wo2(128 rows); Wo1(128 rows)]. grid = (512, 1, 2), block = 256.
// ---------------------------------------------------------------------------
__global__ __launch_bounds__(256) void gemm_outm2(
    const unsigned short* __restrict__ Asa, const unsigned short* __restrict__ Aca,
    const unsigned short* __restrict__ Wob,
    const float* __restrict__ bo2, const float* __restrict__ bo1,
    float* __restrict__ out)
{
  __shared__ unsigned short smem[2 * 128 * 64];
  __shared__ float biasS[128];
  const unsigned short* A = (blockIdx.z == 0) ? Asa : Aca;
  const unsigned short* Wsrc = Wob + (size_t)blockIdx.z * 32768;
  const float* bias = (blockIdx.z == 0) ? bo2 : bo1;
  const int joff = blockIdx.z * 128;
  unsigned short* Ws = smem;
  unsigned short* Xs = smem + 128 * 64;
  const int tid = threadIdx.x;
  const int lane = tid & 63, wid = tid >> 6;
  const int l15 = lane & 15, l4 = lane >> 4;
  const int wr = wid >> 1, wc = wid & 1;
  const size_t m0 = (size_t)blockIdx.x * 128;
  const int lrow = lane >> 3, lcb = lane & 7;
  if (tid < 128) biasS[tid] = bias[tid];

  fx4 acc[4][4];
#pragma unroll
  for (int m = 0; m < 4; ++m)
#pragma unroll
    for (int n = 0; n < 4; ++n) acc[m][n] = (fx4){0.f, 0.f, 0.f, 0.f};

  for (int k0 = 0; k0 < 256; k0 += 64) {
#pragma unroll
    for (int i = 0; i < 4; ++i) {
      const int ci = i * 4 + wid;
      const int row = ci * 8 + lrow;
      const int scb = lcb ^ (row & 7);
      gl_lds16(&Wsrc[(size_t)row * 256 + k0 + scb * 8], &Ws[ci * 512]);
      gl_lds16(&A[(m0 + row) * 256 + k0 + scb * 8], &Xs[ci * 512]);
    }
    __syncthreads();
#pragma unroll
    for (int kk = 0; kk < 2; ++kk) {
      const int cbi = kk * 4 + l4;
      bh8 af[4], bfr[4];
#pragma unroll
      for (int m = 0; m < 4; ++m) {   // A-frag = tokens (D-row side)
        const int r = wr * 64 + m * 16 + l15;
        af[m] = *reinterpret_cast<const bh8*>(&Xs[r * 64 + ((cbi ^ (r & 7)) << 3)]);
      }
#pragma unroll
      for (int n = 0; n < 4; ++n) {   // B-frag = W (D-col side)
        const int r = wc * 64 + n * 16 + l15;
        bfr[n] = *reinterpret_cast<const bh8*>(&Ws[r * 64 + ((cbi ^ (r & 7)) << 3)]);
      }
#pragma unroll
      for (int m = 0; m < 4; ++m)
#pragma unroll
        for (int n = 0; n < 4; ++n)
          acc[m][n] = __builtin_amdgcn_mfma_f32_16x16x32_bf16(af[m], bfr[n], acc[m][n], 0, 0, 0);
    }
    __syncthreads();
  }

#pragma unroll
  for (int mi = 0; mi < 4; ++mi) {
    const int mrow = wr * 64 + mi * 16 + (l4 << 2);
#pragma unroll
    for (int ni = 0; ni < 4; ++ni) {
      const int j = wc * 64 + ni * 16 + l15;
      const float bv = biasS[j];
#pragma unroll
      for (int r = 0; r < 4; ++r)
        out[(m0 + mrow + r) * 256 + joff + j] = acc[mi][ni][r] + bv;
    }
  }
}

// ---------------------------------------------------------------------------
// Per-channel 1/max(||row||,eps) over N tokens. blocks 0..4095 -> qT rows,
// 4096..8191 -> kT rows.
// ---------------------------------------------------------------------------
__global__ __launch_bounds__(256) void norm_kernel(
    const unsigned short* __restrict__ qT, const unsigned short* __restrict__ kT,
    float* __restrict__ rq, float* __restrict__ rk)
{
  const int row = blockIdx.x;
  const unsigned short* src = (row < 4096) ? (qT + (size_t)row * N_)
                                           : (kT + (size_t)(row - 4096) * N_);
  float s = 0.f;
  for (int i = threadIdx.x; i < N_ / 8; i += 256) {
    const uint4 u = *reinterpret_cast<const uint4*>(&src[i * 8]);
    float a, b;
    bfu2x2(u.x, a, b); s += a * a + b * b;
    bfu2x2(u.y, a, b); s += a * a + b * b;
    bfu2x2(u.z, a, b); s += a * a + b * b;
    bfu2x2(u.w, a, b); s += a * a + b * b;
  }
#pragma unroll
  for (int off = 32; off > 0; off >>= 1) s += __shfl_xor(s, off);
  __shared__ float ws4[4];
  if ((threadIdx.x & 63) == 0) ws4[threadIdx.x >> 6] = s;
  __syncthreads();
  if (threadIdx.x == 0) {
    const float tot = ws4[0] + ws4[1] + ws4[2] + ws4[3];
    const float r = 1.f / fmaxf(sqrtf(tot), 1e-12f);
    (row < 4096 ? rq : rk)[row & 4095] = r;
  }
}

// ---------------------------------------------------------------------------
// MFMA stats: per (bh, chunk of 512 tokens), three 64x64 partial GEMMs over
// tokens: wave0: S=q.k^T; wave1: KpT=WE.k^T; wave2: Vp=v.WE^T; wave3 stages.
// part[chunk][bh][3][64][64]. grid = (64, 8), block = 256.
// ---------------------------------------------------------------------------
__global__ __launch_bounds__(256) void stats_mfma(
    const unsigned short* __restrict__ qT, const unsigned short* __restrict__ kT,
    const unsigned short* __restrict__ vT, const unsigned short* __restrict__ wEb,
    float* __restrict__ part)
{
  __shared__ unsigned short smem[4 * 64 * LDW];
  unsigned short* sq = smem;
  unsigned short* sk = smem + 64 * LDW;
  unsigned short* sv = smem + 2 * 64 * LDW;
  unsigned short* sw = smem + 3 * 64 * LDW;
  const int tid = threadIdx.x;
  const int lane = tid & 63, wid = tid >> 6;
  const int bh = blockIdx.x, chunk = blockIdx.y;
  const size_t rowbase = (size_t)bh * 64 * N_;

  fx4 acc[4][4];
#pragma unroll
  for (int m = 0; m < 4; ++m)
#pragma unroll
    for (int n = 0; n < 4; ++n) acc[m][n] = (fx4){0.f, 0.f, 0.f, 0.f};

  const unsigned short* Aop = (wid == 1) ? sw : (wid == 2) ? sv : sq;
  const unsigned short* Bop = (wid == 1) ? sk : (wid == 2) ? sw : sk;

  for (int tile = 0; tile < 8; ++tile) {
    const int n0 = chunk * 512 + tile * 64;
#pragma unroll
    for (int c = 0; c < 2; ++c) {
      const int idx = c * 256 + tid;       // 0..511
      const int r = idx >> 3;              // 0..63
      const int off = (idx & 7) * 8;       // 0..56
      *reinterpret_cast<uint4*>(&sq[r * LDW + off]) =
          *reinterpret_cast<const uint4*>(&qT[rowbase + (size_t)r * N_ + n0 + off]);
      *reinterpret_cast<uint4*>(&sk[r * LDW + off]) =
          *reinterpret_cast<const uint4*>(&kT[rowbase + (size_t)r * N_ + n0 + off]);
      *reinterpret_cast<uint4*>(&sv[r * LDW + off]) =
          *reinterpret_cast<const uint4*>(&vT[rowbase + (size_t)r * N_ + n0 + off]);
      *reinterpret_cast<uint4*>(&sw[r * LDW + off]) =
          *reinterpret_cast<const uint4*>(&wEb[(size_t)r * N_ + n0 + off]);
    }
    __syncthreads();
    if (wid < 3) {
#pragma unroll
      for (int kk = 0; kk < 2; ++kk) {
        const int kb = kk * 32 + (lane >> 4) * 8;
        bh8 af[4], bfr[4];
#pragma unroll
        for (int m = 0; m < 4; ++m)
          af[m] = *reinterpret_cast<const bh8*>(&Aop[(m * 16 + (lane & 15)) * LDW + kb]);
#pragma unroll
        for (int n = 0; n < 4; ++n)
          bfr[n] = *reinterpret_cast<const bh8*>(&Bop[(n * 16 + (lane & 15)) * LDW + kb]);
#pragma unroll
        for (int m = 0; m < 4; ++m)
#pragma unroll
          for (int n = 0; n < 4; ++n)
            acc[m][n] = __builtin_amdgcn_mfma_f32_16x16x32_bf16(af[m], bfr[n], acc[m][n], 0, 0, 0);
      }
    }
    __syncthreads();
  }

  if (wid < 3) {
    float* base = &part[(((size_t)chunk * 64 + bh) * 3 + wid) * 4096];
#pragma unroll
    for (int m = 0; m < 4; ++m) {
      const int row0 = m * 16 + ((lane >> 4) << 2);
#pragma unroll
      for (int n = 0; n < 4; ++n) {
        const int col = n * 16 + (lane & 15);
#pragma unroll
        for (int r = 0; r < 4; ++r)
          base[(row0 + r) * 64 + col] = acc[m][n][r];
      }
    }
  }
}

// ---------------------------------------------------------------------------
// Reduce partials; emit bf16 kp2t[p][c] = (KpT*rk[c] + bE[p])*rq[c]*temp2[h],
// bf16 vpb[d][p] = Vp + bE[p], and channel-attention softmax
// attn_t[bh][d][c] = softmax_d(S*rq[c]*rk[d]*temp[h]). grid = 64.
// ---------------------------------------------------------------------------
__global__ __launch_bounds__(256) void postproc_kernel(
    const float* __restrict__ part, const float* __restrict__ rq,
    const float* __restrict__ rk, const float* __restrict__ bE,
    const float* __restrict__ temp, const float* __restrict__ temp2,
    float* __restrict__ attn_t,
    unsigned short* __restrict__ kp2t, unsigned short* __restrict__ vpb)
{
  __shared__ float sums[12288];
  const int bh = blockIdx.x;
  const int tid = threadIdx.x;
  for (int idx = tid; idx < 12288; idx += 256) {
    float s = 0.f;
    for (int ch = 0; ch < 8; ++ch)
      s += part[((size_t)ch * 64 + bh) * 12288 + idx];
    sums[idx] = s;
  }
  __syncthreads();
  const float t2 = temp2[bh & 3];
  for (int idx = tid; idx < 4096; idx += 256) {
    const int p = idx >> 6, c = idx & 63;
    kp2t[(size_t)bh * 4096 + idx] =
        f2bfu((sums[4096 + idx] * rk[bh * 64 + c] + bE[p]) * rq[bh * 64 + c] * t2);
    vpb[(size_t)bh * 4096 + idx] = f2bfu(sums[8192 + idx] + bE[idx & 63]);
  }
  const float tv = temp[bh & 3];
  const int lane = tid & 63, wv = tid >> 6;
  for (int ri = 0; ri < 16; ++ri) {
    const int c = wv * 16 + ri;
    const float val = sums[c * 64 + lane] * rq[bh * 64 + c] * rk[bh * 64 + lane] * tv;
    float m = val;
#pragma unroll
    for (int off = 32; off > 0; off >>= 1) m = fmaxf(m, __shfl_xor(m, off));
    const float e = __expf(val - m);
    float ssum = e;
#pragma unroll
    for (int off = 32; off > 0; off >>= 1) ssum += __shfl_xor(ssum, off);
    attn_t[(size_t)bh * 4096 + lane * 64 + c] = e / ssum;   // [d][c]
  }
}

// ---------------------------------------------------------------------------
// MFMA spatial attention. Per wave: 64 tokens. GEMM1 S=q_tok·kp2t^T (K=c),
// in-register softmax over p, P(bf16)->LDS, GEMM2 out=P·vpb^T (K=p),
// transpose-store via stride-65 LDS to x_sa[b][d][h][n].
// grid = (64 bh, 16), block = 256 (4 waves).
// ---------------------------------------------------------------------------
__global__ __launch_bounds__(256) void sa_mfma(
    const unsigned short* __restrict__ qtok, const unsigned short* __restrict__ kp2t,
    const unsigned short* __restrict__ vpb, unsigned short* __restrict__ x_sa)
{
  __shared__ unsigned short skp[64 * LDW];
  __shared__ unsigned short svp[64 * LDW];
  __shared__ unsigned short pt[4][64 * LDW];
  const int tid = threadIdx.x;
  const int lane = tid & 63, wid = tid >> 6;
  const int l15 = lane & 15, l4 = lane >> 4;
  const int bh = blockIdx.x, b = bh >> 2, h = bh & 3;
  const int n0 = blockIdx.y * 256 + wid * 64;
  unsigned short* myp = &pt[wid][0];

#pragma unroll
  for (int i = 0; i < 2; ++i) {
    const int idx = i * 256 + tid;       // 0..511
    const int r = idx >> 3, off = (idx & 7) * 8;
    *reinterpret_cast<uint4*>(&skp[r * LDW + off]) =
        *reinterpret_cast<const uint4*>(&kp2t[(size_t)bh * 4096 + r * 64 + off]);
    *reinterpret_cast<uint4*>(&svp[r * LDW + off]) =
        *reinterpret_cast<const uint4*>(&vpb[(size_t)bh * 4096 + r * 64 + off]);
  }
  __syncthreads();

  // GEMM1: S[n][p]
  fx4 acc[4][4];
#pragma unroll
  for (int m = 0; m < 4; ++m)
#pragma unroll
    for (int j = 0; j < 4; ++j) acc[m][j] = (fx4){0.f, 0.f, 0.f, 0.f};
  const size_t qbase = ((size_t)bh * 4096 + n0) * 64;
#pragma unroll
  for (int kk = 0; kk < 2; ++kk) {
    const int kb = kk * 32 + l4 * 8;
    bh8 af[4], bf[4];
#pragma unroll
    for (int m = 0; m < 4; ++m)
      af[m] = *reinterpret_cast<const bh8*>(&qtok[qbase + (size_t)(m * 16 + l15) * 64 + kb]);
#pragma unroll
    for (int j = 0; j < 4; ++j)
      bf[j] = *reinterpret_cast<const bh8*>(&skp[(j * 16 + l15) * LDW + kb]);
#pragma unroll
    for (int m = 0; m < 4; ++m)
#pragma unroll
      for (int j = 0; j < 4; ++j)
        acc[m][j] = __builtin_amdgcn_mfma_f32_16x16x32_bf16(af[m], bf[j], acc[m][j], 0, 0, 0);
  }

  // softmax over p per row (row n = m*16 + l4*4 + r; col p = j*16 + l15)
  fx4 inv[4];
#pragma unroll
  for (int m = 0; m < 4; ++m) {
    fx4 vm = acc[m][0];
#pragma unroll
    for (int j = 1; j < 4; ++j)
#pragma unroll
      for (int r = 0; r < 4; ++r) vm[r] = fmaxf(vm[r], acc[m][j][r]);
#pragma unroll
    for (int msk = 1; msk < 16; msk <<= 1)
#pragma unroll
      for (int r = 0; r < 4; ++r) vm[r] = fmaxf(vm[r], __shfl_xor(vm[r], msk));
    fx4 s = (fx4){0.f, 0.f, 0.f, 0.f};
#pragma unroll
    for (int j = 0; j < 4; ++j)
#pragma unroll
      for (int r = 0; r < 4; ++r) {
        acc[m][j][r] = __expf(acc[m][j][r] - vm[r]);
        s[r] += acc[m][j][r];
      }
#pragma unroll
    for (int msk = 1; msk < 16; msk <<= 1)
#pragma unroll
      for (int r = 0; r < 4; ++r) s[r] += __shfl_xor(s[r], msk);
#pragma unroll
    for (int r = 0; r < 4; ++r) inv[m][r] = 1.f / s[r];
#pragma unroll
    for (int j = 0; j < 4; ++j)
#pragma unroll
      for (int r = 0; r < 4; ++r)
        myp[(m * 16 + l4 * 4 + r) * LDW + j * 16 + l15] = f2bfu(acc[m][j][r]);
  }

  // GEMM2: O[n][d] = P·vpb^T (per-wave private LDS; in-order DS, no barrier)
  fx4 acc2[4][4];
#pragma unroll
  for (int m = 0; m < 4; ++m)
#pragma unroll
    for (int j = 0; j < 4; ++j) acc2[m][j] = (fx4){0.f, 0.f, 0.f, 0.f};
#pragma unroll
  for (int kk = 0; kk < 2; ++kk) {
    const int kb = kk * 32 + l4 * 8;
    bh8 af[4], bf[4];
#pragma unroll
    for (int m = 0; m < 4; ++m)
      af[m] = *reinterpret_cast<const bh8*>(&myp[(m * 16 + l15) * LDW + kb]);
#pragma unroll
    for (int j = 0; j < 4; ++j)
      bf[j] = *reinterpret_cast<const bh8*>(&svp[(j * 16 + l15) * LDW + kb]);
#pragma unroll
    for (int m = 0; m < 4; ++m)
#pragma unroll
      for (int j = 0; j < 4; ++j)
        acc2[m][j] = __builtin_amdgcn_mfma_f32_16x16x32_bf16(af[m], bf[j], acc2[m][j], 0, 0, 0);
  }

  // epilogue: apply 1/sum per row, bf16 -> LDS [n][d] stride 65, store d-major
#pragma unroll
  for (int m = 0; m < 4; ++m)
#pragma unroll
    for (int j = 0; j < 4; ++j)
#pragma unroll
      for (int r = 0; r < 4; ++r)
        myp[(m * 16 + l4 * 4 + r) * 65 + j * 16 + l15] = f2bfu(acc2[m][j][r] * inv[m][r]);
#pragma unroll
  for (int dstep = 0; dstep < 8; ++dstep) {
    const int d = dstep * 8 + (lane >> 3);
    const int nseg = (lane & 7) * 8;
    union { uint4 v; unsigned short u[8]; } pk;
#pragma unroll
    for (int t = 0; t < 8; ++t) pk.u[t] = myp[(nseg + t) * 65 + d];
    *reinterpret_cast<uint4*>(
        &x_sa[((size_t)(b * 64 + d) * 4 + h) * (size_t)N_ + n0 + nseg]) = pk.v;
  }
}

// ---------------------------------------------------------------------------
// x_ca[c][n] = sum_d attn[c][d] * v_ca[d][n], written to [B,N,C] bf16.
// grid = (64 bh, 32 ntiles of 128).
// ---------------------------------------------------------------------------
__global__ __launch_bounds__(256) void xca_kernel(
    const float* __restrict__ attn_t, const unsigned short* __restrict__ vT,
    unsigned short* __restrict__ x_ca)
{
  __shared__ float at[64][68];
  __shared__ float vt[64][132];
  const int tid = threadIdx.x;
  const int bh = blockIdx.x, b = bh >> 2, h = bh & 3;
  const int n0 = blockIdx.y * 128;
  for (int i = tid; i < 1024; i += 256) {
    const float4 f = *reinterpret_cast<const float4*>(&attn_t[(size_t)bh * 4096 + i * 4]);
    *reinterpret_cast<float4*>(&at[i >> 4][(i * 4) & 63]) = f;
  }
  {
    const int d = tid >> 2, seg = tid & 3;
    const size_t rb = (size_t)(bh * 64 + d) * N_ + n0 + seg * 32;
#pragma unroll
    for (int t = 0; t < 4; ++t) {
      const uint4 u = *reinterpret_cast<const uint4*>(&vT[rb + t * 8]);
      float lo, hi;
      const int c0 = seg * 32 + t * 8;
      bfu2x2(u.x, lo, hi); vt[d][c0 + 0] = lo; vt[d][c0 + 1] = hi;
      bfu2x2(u.y, lo, hi); vt[d][c0 + 2] = lo; vt[d][c0 + 3] = hi;
      bfu2x2(u.z, lo, hi); vt[d][c0 + 4] = lo; vt[d][c0 + 5] = hi;
      bfu2x2(u.w, lo, hi); vt[d][c0 + 6] = lo; vt[d][c0 + 7] = hi;
    }
  }
  __syncthreads();
  const int cg = tid & 7, ng = tid >> 3;
  const int c0 = cg * 8, nl0 = ng * 4;
  float acc[4][8] = {};
  for (int d = 0; d < 64; ++d) {
    float a[8];
    *reinterpret_cast<float4*>(&a[0]) = *reinterpret_cast<const float4*>(&at[d][c0]);
    *reinterpret_cast<float4*>(&a[4]) = *reinterpret_cast<const float4*>(&at[d][c0 + 4]);
    const float4 vv = *reinterpret_cast<const float4*>(&vt[d][nl0]);
    const float vn[4] = {vv.x, vv.y, vv.z, vv.w};
#pragma unroll
    for (int n = 0; n < 4; ++n)
#pragma unroll
      for (int c = 0; c < 8; ++c) acc[n][c] += vn[n] * a[c];
  }
#pragma unroll
  for (int n = 0; n < 4; ++n) {
    union { uint4 v; unsigned short u[8]; } pk;
#pragma unroll
    for (int c = 0; c < 8; ++c) pk.u[c] = f2bfu(acc[n][c]);
    const int nn = n0 + nl0 + n;
    *reinterpret_cast<uint4*>(&x_ca[((size_t)b * N_ + nn) * 256 + h * 64 + c0]) = pk.v;
  }
}

extern "C" void kernel_launch(void* const* d_in, const int* in_sizes, int n_in,
                              void* d_out, int out_size, void* d_ws, size_t ws_size,
                              hipStream_t stream)
{
  const float* x     = (const float*)d_in[0];
  const float* ref   = (const float*)d_in[1];
  const float* Wq    = (const float*)d_in[2];
  const float* bq    = (const float*)d_in[3];
  const float* Wkvv  = (const float*)d_in[4];
  const float* bkvv  = (const float*)d_in[5];
  const float* WE    = (const float*)d_in[6];
  const float* bE    = (const float*)d_in[7];
  const float* Wo1   = (const float*)d_in[8];
  const float* bo1   = (const float*)d_in[9];
  const float* Wo2   = (const float*)d_in[10];
  const float* bo2   = (const float*)d_in[11];
  const float* temp  = (const float*)d_in[12];
  const float* temp2 = (const float*)d_in[13];
  float* out = (float*)d_out;

  char* ws = (char*)d_ws;
  unsigned short* qT    = (unsigned short*)(ws);               // [4096][4096] bf16 (q, channel-major)
  unsigned short* kvvT  = (unsigned short*)(ws + 33554432);    // [3][4096][4096] bf16 (k, v_ca, v_sa)
  unsigned short* qtok  = (unsigned short*)(ws + 134217728);   // [64bh][4096][64] bf16; later x_ca
  unsigned short* x_ca  = (unsigned short*)(ws + 134217728);   // [B,N,C] bf16 (aliases qtok; sa runs first)
  unsigned short* x_sa  = (unsigned short*)(ws + 167772160);   // [B,hd,H,N] bf16 (aliases refb!)
  unsigned short* refb  = (unsigned short*)(ws + 167772160);   // [65536][256] bf16 ref (dead before sa_mfma)
  float* rq     = (float*)(ws + 201326592);                    // [4096]
  float* rk     = (float*)(ws + 201342976);                    // [4096]
  float* part   = (float*)(ws + 201359360);                    // [8][64][3][64][64] f32
  float* attn_t = (float*)(ws + 226525184);                    // [64][64][64] f32  ([bh][d][c])
  unsigned short* kp2t = (unsigned short*)(ws + 227573760);    // [64bh][64p][64c] bf16
  unsigned short* vpb  = (unsigned short*)(ws + 228622336);    // [64bh][64d][64p] bf16
  unsigned short* wEb  = (unsigned short*)(ws + 229670912);    // [64][4096] bf16
  unsigned short* xb   = (unsigned short*)(ws + 230195200);    // [65536][256] bf16 x
  unsigned short* Wb   = (unsigned short*)(ws + 263749632);    // weights bf16 (655360 B)
  // total ws usage: 264,404,992 bytes

  const dim3 blk(256);
  cast_xref<<<dim3(16384), blk, 0, stream>>>(x, ref, xb, refb);
  cast_w<<<dim3(288), blk, 0, stream>>>(Wq, Wkvv, Wo2, Wo1, WE, Wb, wEb);
  gemm_projT2<<<dim3(32, 2, 16), blk, 0, stream>>>(xb, Wb, bq, qT, qtok);
  gemm_projT2<<<dim3(32, 6, 16), blk, 0, stream>>>(refb, Wb + 65536, bkvv, kvvT, nullptr);
  norm_kernel<<<dim3(8192), blk, 0, stream>>>(qT, kvvT, rq, rk);
  stats_mfma<<<dim3(64, 8), blk, 0, stream>>>(qT, kvvT, kvvT + 2 * QSZ, wEb, part);
  postproc_kernel<<<dim3(64), blk, 0, stream>>>(part, rq, rk, bE, temp, temp2, attn_t, kp2t, vpb);
  sa_mfma<<<dim3(64, 16), blk, 0, stream>>>(qtok, kp2t, vpb, x_sa);
  xca_kernel<<<dim3(64, 32), blk, 0, stream>>>(attn_t, kvvT + QSZ, x_ca);
  gemm_outm2<<<dim3(512, 1, 2), blk, 0, stream>>>(x_sa, x_ca, Wb + 262144, bo2, bo1, out);
}

// Round 7
// 242.933 us; speedup vs baseline: 4.4172x; 1.1345x over previous
//
#include <hip/hip_runtime.h>
#include <hip/hip_bf16.h>

#define DI __device__ __forceinline__

constexpr int B_ = 16, N_ = 4096, C_ = 256, H_ = 4;
constexpr size_t QSZ = (size_t)4096 * 4096;   // elements in one [4096][4096] bf16 plane
constexpr int LDW = 72;    // LDS row stride (ushorts) for 64-wide bf16 tiles (bank-rotating)
constexpr int LDC = 136;   // LDS row stride (ushorts) for 128-wide epilogue tile (16B-aligned)

typedef __attribute__((ext_vector_type(8))) short bh8;
typedef __attribute__((ext_vector_type(4))) float fx4;
typedef __attribute__((address_space(1))) unsigned int gu32;
typedef __attribute__((address_space(3))) unsigned int lu32;

DI float bfu2f(unsigned short u) { return __uint_as_float(((unsigned)u) << 16); }
DI void bfu2x2(unsigned u, float& lo, float& hi) {
  lo = __uint_as_float(u << 16);
  hi = __uint_as_float(u & 0xffff0000u);
}
DI unsigned short f2bfu(float f) {   // RNE f32->bf16 (finite inputs)
  unsigned u = __float_as_uint(f);
  unsigned r = 0x7fffu + ((u >> 16) & 1u);
  return (unsigned short)((u + r) >> 16);
}
DI void gl_lds16(const unsigned short* g, unsigned short* l) {
  // async 16B/lane global->LDS; LDS dest = wave-uniform base + lane*16
  __builtin_amdgcn_global_load_lds((gu32*)g, (lu32*)l, 16, 0, 0);
}

// ---------------------------------------------------------------------------
// fp32 -> bf16 casts. cast_xref: grid 16384 (x first 8192 blocks, ref next).
// ---------------------------------------------------------------------------
__global__ __launch_bounds__(256) void cast_xref(
    const float* __restrict__ x, const float* __restrict__ ref,
    unsigned short* __restrict__ xb, unsigned short* __restrict__ refb)
{
  const int bid = blockIdx.x;
  const float* src = (bid < 8192) ? x : ref;
  unsigned short* dst = (bid < 8192) ? xb : refb;
  const size_t base = ((size_t)(bid & 8191) * 256 + threadIdx.x) * 8;
  const float4 a = *reinterpret_cast<const float4*>(&src[base]);
  const float4 b = *reinterpret_cast<const float4*>(&src[base + 4]);
  union { uint4 v; unsigned short u[8]; } pk;
  pk.u[0] = f2bfu(a.x); pk.u[1] = f2bfu(a.y); pk.u[2] = f2bfu(a.z); pk.u[3] = f2bfu(a.w);
  pk.u[4] = f2bfu(b.x); pk.u[5] = f2bfu(b.y); pk.u[6] = f2bfu(b.z); pk.u[7] = f2bfu(b.w);
  *reinterpret_cast<uint4*>(&dst[base]) = pk.v;
}

// Wb layout (ushorts): Wq@0 (65536), Wkvv@65536 (196608), Wo2@262144 (32768),
// Wo1@294912 (32768). WE -> wEb [64][4096]. grid = 288.
__global__ __launch_bounds__(256) void cast_w(
    const float* __restrict__ Wq, const float* __restrict__ Wkvv,
    const float* __restrict__ Wo2, const float* __restrict__ Wo1,
    const float* __restrict__ WE, unsigned short* __restrict__ Wb,
    unsigned short* __restrict__ wEb)
{
  const int b = blockIdx.x;
  const float* src; unsigned short* dst; int lb;
  if (b < 32)       { src = Wq;   dst = Wb;          lb = b; }
  else if (b < 128) { src = Wkvv; dst = Wb + 65536;  lb = b - 32; }
  else if (b < 144) { src = Wo2;  dst = Wb + 262144; lb = b - 128; }
  else if (b < 160) { src = Wo1;  dst = Wb + 294912; lb = b - 144; }
  else              { src = WE;   dst = wEb;         lb = b - 160; }
  const size_t base = ((size_t)lb * 256 + threadIdx.x) * 8;
  const float4 a = *reinterpret_cast<const float4*>(&src[base]);
  const float4 bb = *reinterpret_cast<const float4*>(&src[base + 4]);
  union { uint4 v; unsigned short u[8]; } pk;
  pk.u[0] = f2bfu(a.x);  pk.u[1] = f2bfu(a.y);  pk.u[2] = f2bfu(a.z);  pk.u[3] = f2bfu(a.w);
  pk.u[4] = f2bfu(bb.x); pk.u[5] = f2bfu(bb.y); pk.u[6] = f2bfu(bb.z); pk.u[7] = f2bfu(bb.w);
  *reinterpret_cast<uint4*>(&dst[base]) = pk.v;
}

// ---------------------------------------------------------------------------
// Fused bf16 MFMA projection GEMM (q + kvv in one launch), double-buffered
// global_load_lds pipeline (2-phase), XOR-swizzled staging.
// blockIdx.y 0..1 -> q (writes qT + token-major qtok); 2..7 -> kvv:
//   plane 0 (k) -> kvv2T plane 0; plane 1 (v_ca) -> token-major vtok ONLY;
//   plane 2 (v_sa) -> kvv2T plane 1.
// OutT row = (plT*16 + b)*256 + (j&255), col = n.
// grid = (32 ntiles, 8, 16 b), block = 256 (4 waves, 2x2).
// ---------------------------------------------------------------------------
__global__ __launch_bounds__(256) void proj_fused(
    const unsigned short* __restrict__ xb, const unsigned short* __restrict__ refb,
    const unsigned short* __restrict__ Wball,
    const float* __restrict__ bq, const float* __restrict__ bkvv,
    unsigned short* __restrict__ qT, unsigned short* __restrict__ kvv2T,
    unsigned short* __restrict__ qtok, unsigned short* __restrict__ vtok)
{
  __shared__ unsigned short smem[32768];      // 2 bufs x (W 8192 + X 8192) = 64KB
  __shared__ float biasS[128];
  const int tid = threadIdx.x;
  const int lane = tid & 63, wid = tid >> 6;
  const int l15 = lane & 15, l4 = lane >> 4;
  const int wr = wid >> 1, wc = wid & 1;
  const int yt = blockIdx.y;
  const bool isq = (yt < 2);
  const unsigned short* Ab = isq ? xb : refb;
  const unsigned short* Wsrc = isq ? Wball : (Wball + 65536);
  const float* bias = isq ? bq : bkvv;
  unsigned short* outT = isq ? qT : kvv2T;
  const int j0 = (isq ? yt : (yt - 2)) * 128;
  const int pl = j0 >> 8;                       // kvv source plane 0..2 (q: 0)
  const bool writeT = isq || (pl != 1);         // skip channel-major for v_ca
  const int plT = (!isq && pl == 2) ? 1 : 0;    // compacted plane index
  unsigned short* tok = isq ? qtok : ((pl == 1) ? vtok : nullptr);
  const int n0 = blockIdx.x * 128;
  const int b = blockIdx.z;
  const size_t tok0 = (size_t)b * 4096 + n0;
  const int lrow = lane >> 3, lcb = lane & 7;
  if (tid < 128) biasS[tid] = bias[j0 + tid];

  fx4 acc[4][4];
#pragma unroll
  for (int m = 0; m < 4; ++m)
#pragma unroll
    for (int n = 0; n < 4; ++n) acc[m][n] = (fx4){0.f, 0.f, 0.f, 0.f};

  auto STAGE = [&](int buf, int k0) {
    unsigned short* Wd = smem + buf * 16384;
    unsigned short* Xd = Wd + 8192;
#pragma unroll
    for (int i = 0; i < 4; ++i) {
      const int ci = i * 4 + wid;            // chunk 0..15 (8 rows each)
      const int row = ci * 8 + lrow;         // 0..127
      const int scb = lcb ^ (row & 7);       // pre-swizzled source col-block
      gl_lds16(&Wsrc[(size_t)(j0 + row) * 256 + k0 + scb * 8], &Wd[ci * 512]);
      gl_lds16(&Ab[(tok0 + row) * 256 + k0 + scb * 8], &Xd[ci * 512]);
    }
  };
  auto COMPUTE = [&](int buf) {
    const unsigned short* Ws = smem + buf * 16384;
    const unsigned short* Xs = Ws + 8192;
#pragma unroll
    for (int kk = 0; kk < 2; ++kk) {
      const int cbi = kk * 4 + l4;           // col-block index 0..7
      bh8 af[4], bfr[4];
#pragma unroll
      for (int m = 0; m < 4; ++m) {
        const int r = wr * 64 + m * 16 + l15;
        af[m] = *reinterpret_cast<const bh8*>(&Ws[r * 64 + ((cbi ^ (r & 7)) << 3)]);
      }
#pragma unroll
      for (int n = 0; n < 4; ++n) {
        const int r = wc * 64 + n * 16 + l15;
        bfr[n] = *reinterpret_cast<const bh8*>(&Xs[r * 64 + ((cbi ^ (r & 7)) << 3)]);
      }
#pragma unroll
      for (int m = 0; m < 4; ++m)
#pragma unroll
        for (int n = 0; n < 4; ++n)
          acc[m][n] = __builtin_amdgcn_mfma_f32_16x16x32_bf16(af[m], bfr[n], acc[m][n], 0, 0, 0);
    }
  };

  STAGE(0, 0);
  __syncthreads();
  for (int t = 0; t < 4; ++t) {
    if (t < 3) STAGE((t + 1) & 1, (t + 1) * 64);   // issue before compute: overlap
    COMPUTE(t & 1);
    __syncthreads();
  }

  // epilogue: acc -> bf16 LDS [128][128] (stride LDC), then coalesced stores
  unsigned short* Co = smem;
#pragma unroll
  for (int m = 0; m < 4; ++m) {
    const int jl = wr * 64 + m * 16 + (l4 << 2);
#pragma unroll
    for (int n = 0; n < 4; ++n) {
      const int col = wc * 64 + n * 16 + l15;
#pragma unroll
      for (int r = 0; r < 4; ++r)
        Co[(jl + r) * LDC + col] = f2bfu(acc[m][n][r] + biasS[jl + r]);
    }
  }
  __syncthreads();
  if (writeT) {
#pragma unroll
    for (int c = 0; c < 8; ++c) {
      const int r = tid >> 1;
      const int colseg = (tid & 1) * 64 + c * 8;
      const uint4 v = *reinterpret_cast<const uint4*>(&Co[r * LDC + colseg]);
      const int jj = j0 + r;
      const int rowT = (plT * B_ + b) * 256 + (jj & 255);
      *reinterpret_cast<uint4*>(&outT[(size_t)rowT * N_ + n0 + colseg]) = v;
    }
  }
  // optional token-major copy: tok[((b*4+h)*4096 + n)*64 + c]
  if (tok) {
#pragma unroll
    for (int i = 0; i < 8; ++i) {
      const int idx = i * 256 + tid;        // 0..2047
      const int col = idx & 127;            // token within tile
      const int cb = (idx >> 7) * 8;        // channel octet 0..120
      union { uint4 v; unsigned short u[8]; } pk;
#pragma unroll
      for (int t = 0; t < 8; ++t) pk.u[t] = Co[(cb + t) * LDC + col];
      const int jj = j0 + cb;
      const int hh = (jj >> 6) & 3, cc = jj & 63;
      *reinterpret_cast<uint4*>(
          &tok[(((size_t)b * 4 + hh) * 4096 + n0 + col) * 64 + cc]) = pk.v;
    }
  }
}

// ---------------------------------------------------------------------------
// All-bf16 MFMA output GEMM, 2-phase pipelined.
// z=0: out[:, :128] = Asa @ Wo2^T + bo2 ; z=1: out[:, 128:] = Aca @ Wo1^T + bo1
// grid = (512, 1, 2), block = 256.
// ---------------------------------------------------------------------------
__global__ __launch_bounds__(256) void gemm_outm2(
    const unsigned short* __restrict__ Asa, const unsigned short* __restrict__ Aca,
    const unsigned short* __restrict__ Wob,
    const float* __restrict__ bo2, const float* __restrict__ bo1,
    float* __restrict__ out)
{
  __shared__ unsigned short smem[32768];
  __shared__ float biasS[128];
  const unsigned short* A = (blockIdx.z == 0) ? Asa : Aca;
  const unsigned short* Wsrc = Wob + (size_t)blockIdx.z * 32768;
  const float* bias = (blockIdx.z == 0) ? bo2 : bo1;
  const int joff = blockIdx.z * 128;
  const int tid = threadIdx.x;
  const int lane = tid & 63, wid = tid >> 6;
  const int l15 = lane & 15, l4 = lane >> 4;
  const int wr = wid >> 1, wc = wid & 1;
  const size_t m0 = (size_t)blockIdx.x * 128;
  const int lrow = lane >> 3, lcb = lane & 7;
  if (tid < 128) biasS[tid] = bias[tid];

  fx4 acc[4][4];
#pragma unroll
  for (int m = 0; m < 4; ++m)
#pragma unroll
    for (int n = 0; n < 4; ++n) acc[m][n] = (fx4){0.f, 0.f, 0.f, 0.f};

  auto STAGE = [&](int buf, int k0) {
    unsigned short* Wd = smem + buf * 16384;
    unsigned short* Xd = Wd + 8192;
#pragma unroll
    for (int i = 0; i < 4; ++i) {
      const int ci = i * 4 + wid;
      const int row = ci * 8 + lrow;
      const int scb = lcb ^ (row & 7);
      gl_lds16(&Wsrc[(size_t)row * 256 + k0 + scb * 8], &Wd[ci * 512]);
      gl_lds16(&A[(m0 + row) * 256 + k0 + scb * 8], &Xd[ci * 512]);
    }
  };
  auto COMPUTE = [&](int buf) {
    const unsigned short* Ws = smem + buf * 16384;
    const unsigned short* Xs = Ws + 8192;
#pragma unroll
    for (int kk = 0; kk < 2; ++kk) {
      const int cbi = kk * 4 + l4;
      bh8 af[4], bfr[4];
#pragma unroll
      for (int m = 0; m < 4; ++m) {   // A-frag = tokens (D-row side)
        const int r = wr * 64 + m * 16 + l15;
        af[m] = *reinterpret_cast<const bh8*>(&Xs[r * 64 + ((cbi ^ (r & 7)) << 3)]);
      }
#pragma unroll
      for (int n = 0; n < 4; ++n) {   // B-frag = W (D-col side)
        const int r = wc * 64 + n * 16 + l15;
        bfr[n] = *reinterpret_cast<const bh8*>(&Ws[r * 64 + ((cbi ^ (r & 7)) << 3)]);
      }
#pragma unroll
      for (int m = 0; m < 4; ++m)
#pragma unroll
        for (int n = 0; n < 4; ++n)
          acc[m][n] = __builtin_amdgcn_mfma_f32_16x16x32_bf16(af[m], bfr[n], acc[m][n], 0, 0, 0);
    }
  };

  STAGE(0, 0);
  __syncthreads();
  for (int t = 0; t < 4; ++t) {
    if (t < 3) STAGE((t + 1) & 1, (t + 1) * 64);
    COMPUTE(t & 1);
    __syncthreads();
  }

#pragma unroll
  for (int mi = 0; mi < 4; ++mi) {
    const int mrow = wr * 64 + mi * 16 + (l4 << 2);
#pragma unroll
    for (int ni = 0; ni < 4; ++ni) {
      const int j = wc * 64 + ni * 16 + l15;
      const float bv = biasS[j];
#pragma unroll
      for (int r = 0; r < 4; ++r)
        out[(m0 + mrow + r) * 256 + joff + j] = acc[mi][ni][r] + bv;
    }
  }
}

// ---------------------------------------------------------------------------
// Per-channel 1/max(||row||,eps) over N tokens. blocks 0..4095 -> qT rows,
// 4096..8191 -> kT rows.
// ---------------------------------------------------------------------------
__global__ __launch_bounds__(256) void norm_kernel(
    const unsigned short* __restrict__ qT, const unsigned short* __restrict__ kT,
    float* __restrict__ rq, float* __restrict__ rk)
{
  const int row = blockIdx.x;
  const unsigned short* src = (row < 4096) ? (qT + (size_t)row * N_)
                                           : (kT + (size_t)(row - 4096) * N_);
  float s = 0.f;
  for (int i = threadIdx.x; i < N_ / 8; i += 256) {
    const uint4 u = *reinterpret_cast<const uint4*>(&src[i * 8]);
    float a, b;
    bfu2x2(u.x, a, b); s += a * a + b * b;
    bfu2x2(u.y, a, b); s += a * a + b * b;
    bfu2x2(u.z, a, b); s += a * a + b * b;
    bfu2x2(u.w, a, b); s += a * a + b * b;
  }
#pragma unroll
  for (int off = 32; off > 0; off >>= 1) s += __shfl_xor(s, off);
  __shared__ float ws4[4];
  if ((threadIdx.x & 63) == 0) ws4[threadIdx.x >> 6] = s;
  __syncthreads();
  if (threadIdx.x == 0) {
    const float tot = ws4[0] + ws4[1] + ws4[2] + ws4[3];
    const float r = 1.f / fmaxf(sqrtf(tot), 1e-12f);
    (row < 4096 ? rq : rk)[row & 4095] = r;
  }
}

// ---------------------------------------------------------------------------
// MFMA stats: per (bh, chunk of 512 tokens), three 64x64 partial GEMMs over
// tokens: wave0: S=q.k^T; wave1: KpT=WE.k^T; wave2: Vp=v.WE^T; wave3 stages.
// part[chunk][bh][3][64][64]. grid = (64, 8), block = 256.
// ---------------------------------------------------------------------------
__global__ __launch_bounds__(256) void stats_mfma(
    const unsigned short* __restrict__ qT, const unsigned short* __restrict__ kT,
    const unsigned short* __restrict__ vT, const unsigned short* __restrict__ wEb,
    float* __restrict__ part)
{
  __shared__ unsigned short smem[4 * 64 * LDW];
  unsigned short* sq = smem;
  unsigned short* sk = smem + 64 * LDW;
  unsigned short* sv = smem + 2 * 64 * LDW;
  unsigned short* sw = smem + 3 * 64 * LDW;
  const int tid = threadIdx.x;
  const int lane = tid & 63, wid = tid >> 6;
  const int bh = blockIdx.x, chunk = blockIdx.y;
  const size_t rowbase = (size_t)bh * 64 * N_;

  fx4 acc[4][4];
#pragma unroll
  for (int m = 0; m < 4; ++m)
#pragma unroll
    for (int n = 0; n < 4; ++n) acc[m][n] = (fx4){0.f, 0.f, 0.f, 0.f};

  const unsigned short* Aop = (wid == 1) ? sw : (wid == 2) ? sv : sq;
  const unsigned short* Bop = (wid == 1) ? sk : (wid == 2) ? sw : sk;

  for (int tile = 0; tile < 8; ++tile) {
    const int n0 = chunk * 512 + tile * 64;
#pragma unroll
    for (int c = 0; c < 2; ++c) {
      const int idx = c * 256 + tid;       // 0..511
      const int r = idx >> 3;              // 0..63
      const int off = (idx & 7) * 8;       // 0..56
      *reinterpret_cast<uint4*>(&sq[r * LDW + off]) =
          *reinterpret_cast<const uint4*>(&qT[rowbase + (size_t)r * N_ + n0 + off]);
      *reinterpret_cast<uint4*>(&sk[r * LDW + off]) =
          *reinterpret_cast<const uint4*>(&kT[rowbase + (size_t)r * N_ + n0 + off]);
      *reinterpret_cast<uint4*>(&sv[r * LDW + off]) =
          *reinterpret_cast<const uint4*>(&vT[rowbase + (size_t)r * N_ + n0 + off]);
      *reinterpret_cast<uint4*>(&sw[r * LDW + off]) =
          *reinterpret_cast<const uint4*>(&wEb[(size_t)r * N_ + n0 + off]);
    }
    __syncthreads();
    if (wid < 3) {
#pragma unroll
      for (int kk = 0; kk < 2; ++kk) {
        const int kb = kk * 32 + (lane >> 4) * 8;
        bh8 af[4], bfr[4];
#pragma unroll
        for (int m = 0; m < 4; ++m)
          af[m] = *reinterpret_cast<const bh8*>(&Aop[(m * 16 + (lane & 15)) * LDW + kb]);
#pragma unroll
        for (int n = 0; n < 4; ++n)
          bfr[n] = *reinterpret_cast<const bh8*>(&Bop[(n * 16 + (lane & 15)) * LDW + kb]);
#pragma unroll
        for (int m = 0; m < 4; ++m)
#pragma unroll
          for (int n = 0; n < 4; ++n)
            acc[m][n] = __builtin_amdgcn_mfma_f32_16x16x32_bf16(af[m], bfr[n], acc[m][n], 0, 0, 0);
      }
    }
    __syncthreads();
  }

  if (wid < 3) {
    float* base = &part[(((size_t)chunk * 64 + bh) * 3 + wid) * 4096];
#pragma unroll
    for (int m = 0; m < 4; ++m) {
      const int row0 = m * 16 + ((lane >> 4) << 2);
#pragma unroll
      for (int n = 0; n < 4; ++n) {
        const int col = n * 16 + (lane & 15);
#pragma unroll
        for (int r = 0; r < 4; ++r)
          base[(row0 + r) * 64 + col] = acc[m][n][r];
      }
    }
  }
}

// ---------------------------------------------------------------------------
// Reduce partials; emit bf16 kp2t[p][c] = (KpT*rk[c] + bE[p])*rq[c]*temp2[h],
// bf16 vpb[d][p] = Vp + bE[p], and channel-attention softmax as bf16
// attn_b[bh][c][d] = softmax_d(S*rq[c]*rk[d]*temp[h]). grid = 64.
// ---------------------------------------------------------------------------
__global__ __launch_bounds__(256) void postproc_kernel(
    const float* __restrict__ part, const float* __restrict__ rq,
    const float* __restrict__ rk, const float* __restrict__ bE,
    const float* __restrict__ temp, const float* __restrict__ temp2,
    unsigned short* __restrict__ attn_b,
    unsigned short* __restrict__ kp2t, unsigned short* __restrict__ vpb)
{
  __shared__ float sums[12288];
  const int bh = blockIdx.x;
  const int tid = threadIdx.x;
  for (int idx = tid; idx < 12288; idx += 256) {
    float s = 0.f;
    for (int ch = 0; ch < 8; ++ch)
      s += part[((size_t)ch * 64 + bh) * 12288 + idx];
    sums[idx] = s;
  }
  __syncthreads();
  const float t2 = temp2[bh & 3];
  for (int idx = tid; idx < 4096; idx += 256) {
    const int p = idx >> 6, c = idx & 63;
    kp2t[(size_t)bh * 4096 + idx] =
        f2bfu((sums[4096 + idx] * rk[bh * 64 + c] + bE[p]) * rq[bh * 64 + c] * t2);
    vpb[(size_t)bh * 4096 + idx] = f2bfu(sums[8192 + idx] + bE[idx & 63]);
  }
  const float tv = temp[bh & 3];
  const int lane = tid & 63, wv = tid >> 6;
  for (int ri = 0; ri < 16; ++ri) {
    const int c = wv * 16 + ri;
    const float val = sums[c * 64 + lane] * rq[bh * 64 + c] * rk[bh * 64 + lane] * tv;
    float m = val;
#pragma unroll
    for (int off = 32; off > 0; off >>= 1) m = fmaxf(m, __shfl_xor(m, off));
    const float e = __expf(val - m);
    float ssum = e;
#pragma unroll
    for (int off = 32; off > 0; off >>= 1) ssum += __shfl_xor(ssum, off);
    attn_b[(size_t)bh * 4096 + c * 64 + lane] = f2bfu(e / ssum);   // [c][d]
  }
}

// ---------------------------------------------------------------------------
// MFMA spatial attention. Per wave: 64 tokens. GEMM1 S=q_tok·kp2t^T (K=c),
// in-register softmax over p, P(bf16)->LDS, GEMM2 out=P·vpb^T (K=p),
// transpose-store via stride-65 LDS to x_sa[b][d][h][n].
// grid = (64 bh, 16), block = 256 (4 waves).
// ---------------------------------------------------------------------------
__global__ __launch_bounds__(256) void sa_mfma(
    const unsigned short* __restrict__ qtok, const unsigned short* __restrict__ kp2t,
    const unsigned short* __restrict__ vpb, unsigned short* __restrict__ x_sa)
{
  __shared__ unsigned short skp[64 * LDW];
  __shared__ unsigned short svp[64 * LDW];
  __shared__ unsigned short pt[4][64 * LDW];
  const int tid = threadIdx.x;
  const int lane = tid & 63, wid = tid >> 6;
  const int l15 = lane & 15, l4 = lane >> 4;
  const int bh = blockIdx.x, b = bh >> 2, h = bh & 3;
  const int n0 = blockIdx.y * 256 + wid * 64;
  unsigned short* myp = &pt[wid][0];

#pragma unroll
  for (int i = 0; i < 2; ++i) {
    const int idx = i * 256 + tid;       // 0..511
    const int r = idx >> 3, off = (idx & 7) * 8;
    *reinterpret_cast<uint4*>(&skp[r * LDW + off]) =
        *reinterpret_cast<const uint4*>(&kp2t[(size_t)bh * 4096 + r * 64 + off]);
    *reinterpret_cast<uint4*>(&svp[r * LDW + off]) =
        *reinterpret_cast<const uint4*>(&vpb[(size_t)bh * 4096 + r * 64 + off]);
  }
  __syncthreads();

  // GEMM1: S[n][p]
  fx4 acc[4][4];
#pragma unroll
  for (int m = 0; m < 4; ++m)
#pragma unroll
    for (int j = 0; j < 4; ++j) acc[m][j] = (fx4){0.f, 0.f, 0.f, 0.f};
  const size_t qbase = ((size_t)bh * 4096 + n0) * 64;
#pragma unroll
  for (int kk = 0; kk < 2; ++kk) {
    const int kb = kk * 32 + l4 * 8;
    bh8 af[4], bf[4];
#pragma unroll
    for (int m = 0; m < 4; ++m)
      af[m] = *reinterpret_cast<const bh8*>(&qtok[qbase + (size_t)(m * 16 + l15) * 64 + kb]);
#pragma unroll
    for (int j = 0; j < 4; ++j)
      bf[j] = *reinterpret_cast<const bh8*>(&skp[(j * 16 + l15) * LDW + kb]);
#pragma unroll
    for (int m = 0; m < 4; ++m)
#pragma unroll
      for (int j = 0; j < 4; ++j)
        acc[m][j] = __builtin_amdgcn_mfma_f32_16x16x32_bf16(af[m], bf[j], acc[m][j], 0, 0, 0);
  }

  // softmax over p per row (row n = m*16 + l4*4 + r; col p = j*16 + l15)
  fx4 inv[4];
#pragma unroll
  for (int m = 0; m < 4; ++m) {
    fx4 vm = acc[m][0];
#pragma unroll
    for (int j = 1; j < 4; ++j)
#pragma unroll
      for (int r = 0; r < 4; ++r) vm[r] = fmaxf(vm[r], acc[m][j][r]);
#pragma unroll
    for (int msk = 1; msk < 16; msk <<= 1)
#pragma unroll
      for (int r = 0; r < 4; ++r) vm[r] = fmaxf(vm[r], __shfl_xor(vm[r], msk));
    fx4 s = (fx4){0.f, 0.f, 0.f, 0.f};
#pragma unroll
    for (int j = 0; j < 4; ++j)
#pragma unroll
      for (int r = 0; r < 4; ++r) {
        acc[m][j][r] = __expf(acc[m][j][r] - vm[r]);
        s[r] += acc[m][j][r];
      }
#pragma unroll
    for (int msk = 1; msk < 16; msk <<= 1)
#pragma unroll
      for (int r = 0; r < 4; ++r) s[r] += __shfl_xor(s[r], msk);
#pragma unroll
    for (int r = 0; r < 4; ++r) inv[m][r] = 1.f / s[r];
#pragma unroll
    for (int j = 0; j < 4; ++j)
#pragma unroll
      for (int r = 0; r < 4; ++r)
        myp[(m * 16 + l4 * 4 + r) * LDW + j * 16 + l15] = f2bfu(acc[m][j][r]);
  }

  // GEMM2: O[n][d] = P·vpb^T (per-wave private LDS; in-order DS, no barrier)
  fx4 acc2[4][4];
#pragma unroll
  for (int m = 0; m < 4; ++m)
#pragma unroll
    for (int j = 0; j < 4; ++j) acc2[m][j] = (fx4){0.f, 0.f, 0.f, 0.f};
#pragma unroll
  for (int kk = 0; kk < 2; ++kk) {
    const int kb = kk * 32 + l4 * 8;
    bh8 af[4], bf[4];
#pragma unroll
    for (int m = 0; m < 4; ++m)
      af[m] = *reinterpret_cast<const bh8*>(&myp[(m * 16 + l15) * LDW + kb]);
#pragma unroll
    for (int j = 0; j < 4; ++j)
      bf[j] = *reinterpret_cast<const bh8*>(&svp[(j * 16 + l15) * LDW + kb]);
#pragma unroll
    for (int m = 0; m < 4; ++m)
#pragma unroll
      for (int j = 0; j < 4; ++j)
        acc2[m][j] = __builtin_amdgcn_mfma_f32_16x16x32_bf16(af[m], bf[j], acc2[m][j], 0, 0, 0);
  }

  // epilogue: apply 1/sum per row, bf16 -> LDS [n][d] stride 65, store d-major
#pragma unroll
  for (int m = 0; m < 4; ++m)
#pragma unroll
    for (int j = 0; j < 4; ++j)
#pragma unroll
      for (int r = 0; r < 4; ++r)
        myp[(m * 16 + l4 * 4 + r) * 65 + j * 16 + l15] = f2bfu(acc2[m][j][r] * inv[m][r]);
#pragma unroll
  for (int dstep = 0; dstep < 8; ++dstep) {
    const int d = dstep * 8 + (lane >> 3);
    const int nseg = (lane & 7) * 8;
    union { uint4 v; unsigned short u[8]; } pk;
#pragma unroll
    for (int t = 0; t < 8; ++t) pk.u[t] = myp[(nseg + t) * 65 + d];
    *reinterpret_cast<uint4*>(
        &x_sa[((size_t)(b * 64 + d) * 4 + h) * (size_t)N_ + n0 + nseg]) = pk.v;
  }
}

// ---------------------------------------------------------------------------
// MFMA channel-attention apply: x_ca[n][c] = sum_d attn_b[c][d]*vtok[n][d].
// A-frags from global attn_b (L2-resident), B-frags from global vtok
// (token-major v_ca). Per-wave 64c x 64n. grid = (64 bh, 16), block = 256.
// ---------------------------------------------------------------------------
__global__ __launch_bounds__(256) void xca_mfma(
    const unsigned short* __restrict__ attn_b, const unsigned short* __restrict__ vtok,
    unsigned short* __restrict__ x_ca)
{
  __shared__ unsigned short co[4][64 * LDW];
  const int tid = threadIdx.x;
  const int lane = tid & 63, wid = tid >> 6;
  const int l15 = lane & 15, l4 = lane >> 4;
  const int bh = blockIdx.x, b = bh >> 2, h = bh & 3;
  const int n0 = blockIdx.y * 256 + wid * 64;
  unsigned short* myco = &co[wid][0];

  fx4 acc[4][4];
#pragma unroll
  for (int m = 0; m < 4; ++m)
#pragma unroll
    for (int j = 0; j < 4; ++j) acc[m][j] = (fx4){0.f, 0.f, 0.f, 0.f};
  const size_t abase = (size_t)bh * 4096;
  const size_t vbase = ((size_t)bh * 4096 + n0) * 64;
#pragma unroll
  for (int kk = 0; kk < 2; ++kk) {
    const int kb = kk * 32 + l4 * 8;
    bh8 af[4], bf[4];
#pragma unroll
    for (int m = 0; m < 4; ++m)   // A rows = c
      af[m] = *reinterpret_cast<const bh8*>(&attn_b[abase + (size_t)(m * 16 + l15) * 64 + kb]);
#pragma unroll
    for (int j = 0; j < 4; ++j)   // B rows = n
      bf[j] = *reinterpret_cast<const bh8*>(&vtok[vbase + (size_t)(j * 16 + l15) * 64 + kb]);
#pragma unroll
    for (int m = 0; m < 4; ++m)
#pragma unroll
      for (int j = 0; j < 4; ++j)
        acc[m][j] = __builtin_amdgcn_mfma_f32_16x16x32_bf16(af[m], bf[j], acc[m][j], 0, 0, 0);
  }

  // transpose via per-wave LDS: co[n][c], then coalesced store to x_ca[B,N,C]
#pragma unroll
  for (int m = 0; m < 4; ++m)
#pragma unroll
    for (int j = 0; j < 4; ++j)
#pragma unroll
      for (int r = 0; r < 4; ++r)
        myco[(j * 16 + l15) * LDW + m * 16 + l4 * 4 + r] = f2bfu(acc[m][j][r]);
#pragma unroll
  for (int p = 0; p < 8; ++p) {
    const int nloc = p * 8 + (lane >> 3);
    const int cseg = (lane & 7) * 8;
    const uint4 v = *reinterpret_cast<const uint4*>(&myco[nloc * LDW + cseg]);
    *reinterpret_cast<uint4*>(
        &x_ca[((size_t)b * N_ + n0 + nloc) * 256 + h * 64 + cseg]) = v;
  }
}

extern "C" void kernel_launch(void* const* d_in, const int* in_sizes, int n_in,
                              void* d_out, int out_size, void* d_ws, size_t ws_size,
                              hipStream_t stream)
{
  const float* x     = (const float*)d_in[0];
  const float* ref   = (const float*)d_in[1];
  const float* Wq    = (const float*)d_in[2];
  const float* bq    = (const float*)d_in[3];
  const float* Wkvv  = (const float*)d_in[4];
  const float* bkvv  = (const float*)d_in[5];
  const float* WE    = (const float*)d_in[6];
  const float* bE    = (const float*)d_in[7];
  const float* Wo1   = (const float*)d_in[8];
  const float* bo1   = (const float*)d_in[9];
  const float* Wo2   = (const float*)d_in[10];
  const float* bo2   = (const float*)d_in[11];
  const float* temp  = (const float*)d_in[12];
  const float* temp2 = (const float*)d_in[13];
  float* out = (float*)d_out;

  // ---- workspace plan (total 237,666,304 B; R5-proven budget 264 MB) ----
  char* ws = (char*)d_ws;
  unsigned short* qT      = (unsigned short*)(ws);             // [4096][4096] bf16
  unsigned short* kvv2T   = (unsigned short*)(ws + 33554432);  // [2][4096][4096] bf16 (k, v_sa)
  unsigned short* qtok    = (unsigned short*)(ws + 100663296); // [64bh][4096][64] bf16
  unsigned short* refb    = (unsigned short*)(ws + 134217728); // ref bf16 (dead after proj)
  unsigned short* x_sa    = (unsigned short*)(ws + 134217728); //  -> [B,hd,H,N] bf16
  unsigned short* vca_tok = (unsigned short*)(ws + 167772160); // [64bh][4096][64] bf16
  unsigned short* xb      = (unsigned short*)(ws + 201326592); // x bf16 (dead after proj)
  float*          part    = (float*)(ws + 201326592);          //  -> [8][64][3][64][64] f32 (24 MB)
  unsigned short* x_ca    = (unsigned short*)(ws + 201326592); //  -> [B,N,C] bf16
  unsigned short* Wb      = (unsigned short*)(ws + 234881024); // weights bf16 (655,360 B)
  unsigned short* wEb     = (unsigned short*)(ws + 235536384); // [64][4096] bf16
  float* rq     = (float*)(ws + 236060672);                    // [4096]
  float* rk     = (float*)(ws + 236077056);                    // [4096]
  unsigned short* attn_b  = (unsigned short*)(ws + 236093440); // [64bh][64c][64d] bf16
  unsigned short* kp2t    = (unsigned short*)(ws + 236617728); // [64bh][64p][64c] bf16
  unsigned short* vpb     = (unsigned short*)(ws + 237142016); // [64bh][64d][64p] bf16

  const dim3 blk(256);
  cast_xref<<<dim3(16384), blk, 0, stream>>>(x, ref, xb, refb);
  cast_w<<<dim3(288), blk, 0, stream>>>(Wq, Wkvv, Wo2, Wo1, WE, Wb, wEb);
  proj_fused<<<dim3(32, 8, 16), blk, 0, stream>>>(xb, refb, Wb, bq, bkvv,
                                                  qT, kvv2T, qtok, vca_tok);
  norm_kernel<<<dim3(8192), blk, 0, stream>>>(qT, kvv2T, rq, rk);
  stats_mfma<<<dim3(64, 8), blk, 0, stream>>>(qT, kvv2T, kvv2T + QSZ, wEb, part);
  postproc_kernel<<<dim3(64), blk, 0, stream>>>(part, rq, rk, bE, temp, temp2,
                                                attn_b, kp2t, vpb);
  sa_mfma<<<dim3(64, 16), blk, 0, stream>>>(qtok, kp2t, vpb, x_sa);
  xca_mfma<<<dim3(64, 16), blk, 0, stream>>>(attn_b, vca_tok, x_ca);
  gemm_outm2<<<dim3(512, 1, 2), blk, 0, stream>>>(x_sa, x_ca, Wb + 262144, bo2, bo1, out);
}

// Round 8
// 213.427 us; speedup vs baseline: 5.0279x; 1.1382x over previous
//
#include <hip/hip_runtime.h>
#include <hip/hip_bf16.h>

#define DI __device__ __forceinline__

constexpr int B_ = 16, N_ = 4096, C_ = 256, H_ = 4;
constexpr size_t QSZ = (size_t)4096 * 4096;   // elements in one [4096][4096] bf16 plane
constexpr int LDW = 72;    // LDS row stride (ushorts) for 64-wide bf16 tiles (bank-rotating)
constexpr int LDC = 136;   // LDS row stride (ushorts) for 128-wide epilogue tile (16B-aligned)

typedef __attribute__((ext_vector_type(8))) short bh8;
typedef __attribute__((ext_vector_type(4))) float fx4;
typedef __attribute__((address_space(1))) unsigned int gu32;
typedef __attribute__((address_space(3))) unsigned int lu32;

DI float bfu2f(unsigned short u) { return __uint_as_float(((unsigned)u) << 16); }
DI void bfu2x2(unsigned u, float& lo, float& hi) {
  lo = __uint_as_float(u << 16);
  hi = __uint_as_float(u & 0xffff0000u);
}
DI unsigned short f2bfu(float f) {   // RNE f32->bf16 (finite inputs)
  unsigned u = __float_as_uint(f);
  unsigned r = 0x7fffu + ((u >> 16) & 1u);
  return (unsigned short)((u + r) >> 16);
}
DI void gl_lds16(const unsigned short* g, unsigned short* l) {
  // async 16B/lane global->LDS; LDS dest = wave-uniform base + lane*16
  __builtin_amdgcn_global_load_lds((gu32*)g, (lu32*)l, 16, 0, 0);
}

// ---------------------------------------------------------------------------
// fp32 -> bf16 casts. cast_xref: grid 16384 (x first 8192 blocks, ref next).
// ---------------------------------------------------------------------------
__global__ __launch_bounds__(256) void cast_xref(
    const float* __restrict__ x, const float* __restrict__ ref,
    unsigned short* __restrict__ xb, unsigned short* __restrict__ refb)
{
  const int bid = blockIdx.x;
  const float* src = (bid < 8192) ? x : ref;
  unsigned short* dst = (bid < 8192) ? xb : refb;
  const size_t base = ((size_t)(bid & 8191) * 256 + threadIdx.x) * 8;
  const float4 a = *reinterpret_cast<const float4*>(&src[base]);
  const float4 b = *reinterpret_cast<const float4*>(&src[base + 4]);
  union { uint4 v; unsigned short u[8]; } pk;
  pk.u[0] = f2bfu(a.x); pk.u[1] = f2bfu(a.y); pk.u[2] = f2bfu(a.z); pk.u[3] = f2bfu(a.w);
  pk.u[4] = f2bfu(b.x); pk.u[5] = f2bfu(b.y); pk.u[6] = f2bfu(b.z); pk.u[7] = f2bfu(b.w);
  *reinterpret_cast<uint4*>(&dst[base]) = pk.v;
}

// Wb layout (ushorts): Wq@0 (65536), Wkvv@65536 (196608), Wo2@262144 (32768),
// Wo1@294912 (32768). WE -> wEb [64][4096]. grid = 288.
__global__ __launch_bounds__(256) void cast_w(
    const float* __restrict__ Wq, const float* __restrict__ Wkvv,
    const float* __restrict__ Wo2, const float* __restrict__ Wo1,
    const float* __restrict__ WE, unsigned short* __restrict__ Wb,
    unsigned short* __restrict__ wEb)
{
  const int b = blockIdx.x;
  const float* src; unsigned short* dst; int lb;
  if (b < 32)       { src = Wq;   dst = Wb;          lb = b; }
  else if (b < 128) { src = Wkvv; dst = Wb + 65536;  lb = b - 32; }
  else if (b < 144) { src = Wo2;  dst = Wb + 262144; lb = b - 128; }
  else if (b < 160) { src = Wo1;  dst = Wb + 294912; lb = b - 144; }
  else              { src = WE;   dst = wEb;         lb = b - 160; }
  const size_t base = ((size_t)lb * 256 + threadIdx.x) * 8;
  const float4 a = *reinterpret_cast<const float4*>(&src[base]);
  const float4 bb = *reinterpret_cast<const float4*>(&src[base + 4]);
  union { uint4 v; unsigned short u[8]; } pk;
  pk.u[0] = f2bfu(a.x);  pk.u[1] = f2bfu(a.y);  pk.u[2] = f2bfu(a.z);  pk.u[3] = f2bfu(a.w);
  pk.u[4] = f2bfu(bb.x); pk.u[5] = f2bfu(bb.y); pk.u[6] = f2bfu(bb.z); pk.u[7] = f2bfu(bb.w);
  *reinterpret_cast<uint4*>(&dst[base]) = pk.v;
}

// ---------------------------------------------------------------------------
// Fused bf16 MFMA projection GEMM (q + kvv in one launch), double-buffered
// global_load_lds pipeline (2-phase), XOR-swizzled staging, fully-coalesced
// epilogue stores (full cache lines per instruction).
// blockIdx.y 0..1 -> q (writes qT + token-major qtok); 2..7 -> kvv:
//   plane 0 (k) -> kvv2T plane 0; plane 1 (v_ca) -> token-major vtok ONLY;
//   plane 2 (v_sa) -> kvv2T plane 1.
// grid = (32 ntiles, 8, 16 b), block = 256 (4 waves, 2x2).
// ---------------------------------------------------------------------------
__global__ __launch_bounds__(256) void proj_fused(
    const unsigned short* __restrict__ xb, const unsigned short* __restrict__ refb,
    const unsigned short* __restrict__ Wball,
    const float* __restrict__ bq, const float* __restrict__ bkvv,
    unsigned short* __restrict__ qT, unsigned short* __restrict__ kvv2T,
    unsigned short* __restrict__ qtok, unsigned short* __restrict__ vtok)
{
  __shared__ unsigned short smem[32768];      // 2 bufs x (W 8192 + X 8192) = 64KB
  __shared__ float biasS[128];
  const int tid = threadIdx.x;
  const int lane = tid & 63, wid = tid >> 6;
  const int l15 = lane & 15, l4 = lane >> 4;
  const int wr = wid >> 1, wc = wid & 1;
  const int yt = blockIdx.y;
  const bool isq = (yt < 2);
  const unsigned short* Ab = isq ? xb : refb;
  const unsigned short* Wsrc = isq ? Wball : (Wball + 65536);
  const float* bias = isq ? bq : bkvv;
  unsigned short* outT = isq ? qT : kvv2T;
  const int j0 = (isq ? yt : (yt - 2)) * 128;
  const int pl = j0 >> 8;                       // kvv source plane 0..2 (q: 0)
  const bool writeT = isq || (pl != 1);         // skip channel-major for v_ca
  const int plT = (!isq && pl == 2) ? 1 : 0;    // compacted plane index
  unsigned short* tok = isq ? qtok : ((pl == 1) ? vtok : nullptr);
  const int n0 = blockIdx.x * 128;
  const int b = blockIdx.z;
  const size_t tok0 = (size_t)b * 4096 + n0;
  const int lrow = lane >> 3, lcb = lane & 7;
  if (tid < 128) biasS[tid] = bias[j0 + tid];

  fx4 acc[4][4];
#pragma unroll
  for (int m = 0; m < 4; ++m)
#pragma unroll
    for (int n = 0; n < 4; ++n) acc[m][n] = (fx4){0.f, 0.f, 0.f, 0.f};

  auto STAGE = [&](int buf, int k0) {
    unsigned short* Wd = smem + buf * 16384;
    unsigned short* Xd = Wd + 8192;
#pragma unroll
    for (int i = 0; i < 4; ++i) {
      const int ci = i * 4 + wid;            // chunk 0..15 (8 rows each)
      const int row = ci * 8 + lrow;         // 0..127
      const int scb = lcb ^ (row & 7);       // pre-swizzled source col-block
      gl_lds16(&Wsrc[(size_t)(j0 + row) * 256 + k0 + scb * 8], &Wd[ci * 512]);
      gl_lds16(&Ab[(tok0 + row) * 256 + k0 + scb * 8], &Xd[ci * 512]);
    }
  };
  auto COMPUTE = [&](int buf) {
    const unsigned short* Ws = smem + buf * 16384;
    const unsigned short* Xs = Ws + 8192;
#pragma unroll
    for (int kk = 0; kk < 2; ++kk) {
      const int cbi = kk * 4 + l4;           // col-block index 0..7
      bh8 af[4], bfr[4];
#pragma unroll
      for (int m = 0; m < 4; ++m) {
        const int r = wr * 64 + m * 16 + l15;
        af[m] = *reinterpret_cast<const bh8*>(&Ws[r * 64 + ((cbi ^ (r & 7)) << 3)]);
      }
#pragma unroll
      for (int n = 0; n < 4; ++n) {
        const int r = wc * 64 + n * 16 + l15;
        bfr[n] = *reinterpret_cast<const bh8*>(&Xs[r * 64 + ((cbi ^ (r & 7)) << 3)]);
      }
#pragma unroll
      for (int m = 0; m < 4; ++m)
#pragma unroll
        for (int n = 0; n < 4; ++n)
          acc[m][n] = __builtin_amdgcn_mfma_f32_16x16x32_bf16(af[m], bfr[n], acc[m][n], 0, 0, 0);
    }
  };

  STAGE(0, 0);
  __syncthreads();
  for (int t = 0; t < 4; ++t) {
    if (t < 3) STAGE((t + 1) & 1, (t + 1) * 64);   // issue before compute: overlap
    COMPUTE(t & 1);
    __syncthreads();
  }

  // epilogue: acc -> bf16 LDS [128][128] (stride LDC)
  unsigned short* Co = smem;
#pragma unroll
  for (int m = 0; m < 4; ++m) {
    const int jl = wr * 64 + m * 16 + (l4 << 2);
#pragma unroll
    for (int n = 0; n < 4; ++n) {
      const int col = wc * 64 + n * 16 + l15;
#pragma unroll
      for (int r = 0; r < 4; ++r)
        Co[(jl + r) * LDC + col] = f2bfu(acc[m][n][r] + biasS[jl + r]);
    }
  }
  __syncthreads();
  // channel-major store: 16 lanes x 16B = 256B contiguous per row, 16 rows/instr
  if (writeT) {
#pragma unroll
    for (int c = 0; c < 8; ++c) {
      const int r = c * 16 + (tid >> 4);
      const int colseg = (tid & 15) * 8;
      const uint4 v = *reinterpret_cast<const uint4*>(&Co[r * LDC + colseg]);
      const int jj = j0 + r;
      const int rowT = (plT * B_ + b) * 256 + (jj & 255);
      *reinterpret_cast<uint4*>(&outT[(size_t)rowT * N_ + n0 + colseg]) = v;
    }
  }
  // token-major store: 8 lanes fill one 128B token row; 32 rows = 4KB contig/instr
  if (tok) {
#pragma unroll
    for (int i = 0; i < 8; ++i) {
      const int half = i >> 2;                 // channel half (64 ch each)
      const int cb = half * 64 + (tid & 7) * 8;
      const int nloc = (i & 3) * 32 + (tid >> 3);
      union { uint4 v; unsigned short u[8]; } pk;
#pragma unroll
      for (int t = 0; t < 8; ++t) pk.u[t] = Co[(cb + t) * LDC + nloc];
      const int jj = j0 + cb;
      const int hh = (jj >> 6) & 3, cc = jj & 63;
      *reinterpret_cast<uint4*>(
          &tok[(((size_t)b * 4 + hh) * 4096 + n0 + nloc) * 64 + cc]) = pk.v;
    }
  }
}

// ---------------------------------------------------------------------------
// All-bf16 MFMA output GEMM, 2-phase pipelined.
// z=0: out[:, :128] = Asa @ Wo2^T + bo2 ; z=1: out[:, 128:] = Aca @ Wo1^T + bo1
// grid = (512, 1, 2), block = 256.
// ---------------------------------------------------------------------------
__global__ __launch_bounds__(256) void gemm_outm2(
    const unsigned short* __restrict__ Asa, const unsigned short* __restrict__ Aca,
    const unsigned short* __restrict__ Wob,
    const float* __restrict__ bo2, const float* __restrict__ bo1,
    float* __restrict__ out)
{
  __shared__ unsigned short smem[32768];
  __shared__ float biasS[128];
  const unsigned short* A = (blockIdx.z == 0) ? Asa : Aca;
  const unsigned short* Wsrc = Wob + (size_t)blockIdx.z * 32768;
  const float* bias = (blockIdx.z == 0) ? bo2 : bo1;
  const int joff = blockIdx.z * 128;
  const int tid = threadIdx.x;
  const int lane = tid & 63, wid = tid >> 6;
  const int l15 = lane & 15, l4 = lane >> 4;
  const int wr = wid >> 1, wc = wid & 1;
  const size_t m0 = (size_t)blockIdx.x * 128;
  const int lrow = lane >> 3, lcb = lane & 7;
  if (tid < 128) biasS[tid] = bias[tid];

  fx4 acc[4][4];
#pragma unroll
  for (int m = 0; m < 4; ++m)
#pragma unroll
    for (int n = 0; n < 4; ++n) acc[m][n] = (fx4){0.f, 0.f, 0.f, 0.f};

  auto STAGE = [&](int buf, int k0) {
    unsigned short* Wd = smem + buf * 16384;
    unsigned short* Xd = Wd + 8192;
#pragma unroll
    for (int i = 0; i < 4; ++i) {
      const int ci = i * 4 + wid;
      const int row = ci * 8 + lrow;
      const int scb = lcb ^ (row & 7);
      gl_lds16(&Wsrc[(size_t)row * 256 + k0 + scb * 8], &Wd[ci * 512]);
      gl_lds16(&A[(m0 + row) * 256 + k0 + scb * 8], &Xd[ci * 512]);
    }
  };
  auto COMPUTE = [&](int buf) {
    const unsigned short* Ws = smem + buf * 16384;
    const unsigned short* Xs = Ws + 8192;
#pragma unroll
    for (int kk = 0; kk < 2; ++kk) {
      const int cbi = kk * 4 + l4;
      bh8 af[4], bfr[4];
#pragma unroll
      for (int m = 0; m < 4; ++m) {   // A-frag = tokens (D-row side)
        const int r = wr * 64 + m * 16 + l15;
        af[m] = *reinterpret_cast<const bh8*>(&Xs[r * 64 + ((cbi ^ (r & 7)) << 3)]);
      }
#pragma unroll
      for (int n = 0; n < 4; ++n) {   // B-frag = W (D-col side)
        const int r = wc * 64 + n * 16 + l15;
        bfr[n] = *reinterpret_cast<const bh8*>(&Ws[r * 64 + ((cbi ^ (r & 7)) << 3)]);
      }
#pragma unroll
      for (int m = 0; m < 4; ++m)
#pragma unroll
        for (int n = 0; n < 4; ++n)
          acc[m][n] = __builtin_amdgcn_mfma_f32_16x16x32_bf16(af[m], bfr[n], acc[m][n], 0, 0, 0);
    }
  };

  STAGE(0, 0);
  __syncthreads();
  for (int t = 0; t < 4; ++t) {
    if (t < 3) STAGE((t + 1) & 1, (t + 1) * 64);
    COMPUTE(t & 1);
    __syncthreads();
  }

#pragma unroll
  for (int mi = 0; mi < 4; ++mi) {
    const int mrow = wr * 64 + mi * 16 + (l4 << 2);
#pragma unroll
    for (int ni = 0; ni < 4; ++ni) {
      const int j = wc * 64 + ni * 16 + l15;
      const float bv = biasS[j];
#pragma unroll
      for (int r = 0; r < 4; ++r)
        out[(m0 + mrow + r) * 256 + joff + j] = acc[mi][ni][r] + bv;
    }
  }
}

// ---------------------------------------------------------------------------
// MFMA stats + fused norms. Per (bh, chunk of 512 tokens):
// wave0: S=q.k^T; wave1: KpT=WE.k^T; wave2: Vp=v.WE^T; wave3: stages + per-
// channel sum-of-squares of q,k over the chunk -> partN.
// part[chunk][bh][3][64][64]; partN[chunk][bh][2][64]. grid = (64,8), blk 256.
// ---------------------------------------------------------------------------
__global__ __launch_bounds__(256) void stats_mfma(
    const unsigned short* __restrict__ qT, const unsigned short* __restrict__ kT,
    const unsigned short* __restrict__ vT, const unsigned short* __restrict__ wEb,
    float* __restrict__ part, float* __restrict__ partN)
{
  __shared__ unsigned short smem[4 * 64 * LDW];
  unsigned short* sq = smem;
  unsigned short* sk = smem + 64 * LDW;
  unsigned short* sv = smem + 2 * 64 * LDW;
  unsigned short* sw = smem + 3 * 64 * LDW;
  const int tid = threadIdx.x;
  const int lane = tid & 63, wid = tid >> 6;
  const int bh = blockIdx.x, chunk = blockIdx.y;
  const size_t rowbase = (size_t)bh * 64 * N_;

  fx4 acc[4][4];
#pragma unroll
  for (int m = 0; m < 4; ++m)
#pragma unroll
    for (int n = 0; n < 4; ++n) acc[m][n] = (fx4){0.f, 0.f, 0.f, 0.f};
  float q2 = 0.f, k2 = 0.f;

  const unsigned short* Aop = (wid == 1) ? sw : (wid == 2) ? sv : sq;
  const unsigned short* Bop = (wid == 1) ? sk : (wid == 2) ? sw : sk;

  for (int tile = 0; tile < 8; ++tile) {
    const int n0 = chunk * 512 + tile * 64;
#pragma unroll
    for (int c = 0; c < 2; ++c) {
      const int idx = c * 256 + tid;       // 0..511
      const int r = idx >> 3;              // 0..63
      const int off = (idx & 7) * 8;       // 0..56
      *reinterpret_cast<uint4*>(&sq[r * LDW + off]) =
          *reinterpret_cast<const uint4*>(&qT[rowbase + (size_t)r * N_ + n0 + off]);
      *reinterpret_cast<uint4*>(&sk[r * LDW + off]) =
          *reinterpret_cast<const uint4*>(&kT[rowbase + (size_t)r * N_ + n0 + off]);
      *reinterpret_cast<uint4*>(&sv[r * LDW + off]) =
          *reinterpret_cast<const uint4*>(&vT[rowbase + (size_t)r * N_ + n0 + off]);
      *reinterpret_cast<uint4*>(&sw[r * LDW + off]) =
          *reinterpret_cast<const uint4*>(&wEb[(size_t)r * N_ + n0 + off]);
    }
    __syncthreads();
    if (wid < 3) {
#pragma unroll
      for (int kk = 0; kk < 2; ++kk) {
        const int kb = kk * 32 + (lane >> 4) * 8;
        bh8 af[4], bfr[4];
#pragma unroll
        for (int m = 0; m < 4; ++m)
          af[m] = *reinterpret_cast<const bh8*>(&Aop[(m * 16 + (lane & 15)) * LDW + kb]);
#pragma unroll
        for (int n = 0; n < 4; ++n)
          bfr[n] = *reinterpret_cast<const bh8*>(&Bop[(n * 16 + (lane & 15)) * LDW + kb]);
#pragma unroll
        for (int m = 0; m < 4; ++m)
#pragma unroll
          for (int n = 0; n < 4; ++n)
            acc[m][n] = __builtin_amdgcn_mfma_f32_16x16x32_bf16(af[m], bfr[n], acc[m][n], 0, 0, 0);
      }
    } else {
      // wave3: per-channel sum of squares for q and k (row = lane)
      const unsigned short* qrow = &sq[lane * LDW];
      const unsigned short* krow = &sk[lane * LDW];
#pragma unroll
      for (int t = 0; t < 8; ++t) {
        const uint4 uq = *reinterpret_cast<const uint4*>(&qrow[t * 8]);
        const uint4 uk = *reinterpret_cast<const uint4*>(&krow[t * 8]);
        float a, b;
        bfu2x2(uq.x, a, b); q2 += a * a + b * b;
        bfu2x2(uq.y, a, b); q2 += a * a + b * b;
        bfu2x2(uq.z, a, b); q2 += a * a + b * b;
        bfu2x2(uq.w, a, b); q2 += a * a + b * b;
        bfu2x2(uk.x, a, b); k2 += a * a + b * b;
        bfu2x2(uk.y, a, b); k2 += a * a + b * b;
        bfu2x2(uk.z, a, b); k2 += a * a + b * b;
        bfu2x2(uk.w, a, b); k2 += a * a + b * b;
      }
    }
    __syncthreads();
  }

  if (wid < 3) {
    float* base = &part[(((size_t)chunk * 64 + bh) * 3 + wid) * 4096];
#pragma unroll
    for (int m = 0; m < 4; ++m) {
      const int row0 = m * 16 + ((lane >> 4) << 2);
#pragma unroll
      for (int n = 0; n < 4; ++n) {
        const int col = n * 16 + (lane & 15);
#pragma unroll
        for (int r = 0; r < 4; ++r)
          base[(row0 + r) * 64 + col] = acc[m][n][r];
      }
    }
  } else {
    float* nb = &partN[((size_t)chunk * 64 + bh) * 128];
    nb[lane] = q2;
    nb[64 + lane] = k2;
  }
}

// ---------------------------------------------------------------------------
// Reduce partials (incl. norms); emit bf16 kp2t[p][c], vpb[d][p], and
// channel-attention softmax attn_b[bh][c][d]. grid = 64.
// ---------------------------------------------------------------------------
__global__ __launch_bounds__(256) void postproc_kernel(
    const float* __restrict__ part, const float* __restrict__ partN,
    const float* __restrict__ bE,
    const float* __restrict__ temp, const float* __restrict__ temp2,
    unsigned short* __restrict__ attn_b,
    unsigned short* __restrict__ kp2t, unsigned short* __restrict__ vpb)
{
  __shared__ float sums[12288];
  __shared__ float rqS[64], rkS[64];
  const int bh = blockIdx.x;
  const int tid = threadIdx.x;
  for (int idx = tid; idx < 12288; idx += 256) {
    float s = 0.f;
    for (int ch = 0; ch < 8; ++ch)
      s += part[((size_t)ch * 64 + bh) * 12288 + idx];
    sums[idx] = s;
  }
  if (tid < 128) {
    float s = 0.f;
    for (int ch = 0; ch < 8; ++ch)
      s += partN[((size_t)ch * 64 + bh) * 128 + tid];
    const float r = 1.f / fmaxf(sqrtf(s), 1e-12f);
    if (tid < 64) rqS[tid] = r; else rkS[tid - 64] = r;
  }
  __syncthreads();
  const float t2 = temp2[bh & 3];
  for (int idx = tid; idx < 4096; idx += 256) {
    const int p = idx >> 6, c = idx & 63;
    kp2t[(size_t)bh * 4096 + idx] =
        f2bfu((sums[4096 + idx] * rkS[c] + bE[p]) * rqS[c] * t2);
    vpb[(size_t)bh * 4096 + idx] = f2bfu(sums[8192 + idx] + bE[idx & 63]);
  }
  const float tv = temp[bh & 3];
  const int lane = tid & 63, wv = tid >> 6;
  for (int ri = 0; ri < 16; ++ri) {
    const int c = wv * 16 + ri;
    const float val = sums[c * 64 + lane] * rqS[c] * rkS[lane] * tv;
    float m = val;
#pragma unroll
    for (int off = 32; off > 0; off >>= 1) m = fmaxf(m, __shfl_xor(m, off));
    const float e = __expf(val - m);
    float ssum = e;
#pragma unroll
    for (int off = 32; off > 0; off >>= 1) ssum += __shfl_xor(ssum, off);
    attn_b[(size_t)bh * 4096 + c * 64 + lane] = f2bfu(e / ssum);   // [c][d]
  }
}

// ---------------------------------------------------------------------------
// MFMA spatial attention. Per wave: 64 tokens. GEMM1 S=q_tok·kp2t^T (K=c),
// in-register softmax over p, P(bf16)->LDS, GEMM2 out=P·vpb^T (K=p),
// transpose-store via stride-65 LDS to x_sa[b][d][h][n].
// grid = (64 bh, 16), block = 256 (4 waves).
// ---------------------------------------------------------------------------
__global__ __launch_bounds__(256) void sa_mfma(
    const unsigned short* __restrict__ qtok, const unsigned short* __restrict__ kp2t,
    const unsigned short* __restrict__ vpb, unsigned short* __restrict__ x_sa)
{
  __shared__ unsigned short skp[64 * LDW];
  __shared__ unsigned short svp[64 * LDW];
  __shared__ unsigned short pt[4][64 * LDW];
  const int tid = threadIdx.x;
  const int lane = tid & 63, wid = tid >> 6;
  const int l15 = lane & 15, l4 = lane >> 4;
  const int bh = blockIdx.x, b = bh >> 2, h = bh & 3;
  const int n0 = blockIdx.y * 256 + wid * 64;
  unsigned short* myp = &pt[wid][0];

#pragma unroll
  for (int i = 0; i < 2; ++i) {
    const int idx = i * 256 + tid;       // 0..511
    const int r = idx >> 3, off = (idx & 7) * 8;
    *reinterpret_cast<uint4*>(&skp[r * LDW + off]) =
        *reinterpret_cast<const uint4*>(&kp2t[(size_t)bh * 4096 + r * 64 + off]);
    *reinterpret_cast<uint4*>(&svp[r * LDW + off]) =
        *reinterpret_cast<const uint4*>(&vpb[(size_t)bh * 4096 + r * 64 + off]);
  }
  __syncthreads();

  // GEMM1: S[n][p]
  fx4 acc[4][4];
#pragma unroll
  for (int m = 0; m < 4; ++m)
#pragma unroll
    for (int j = 0; j < 4; ++j) acc[m][j] = (fx4){0.f, 0.f, 0.f, 0.f};
  const size_t qbase = ((size_t)bh * 4096 + n0) * 64;
#pragma unroll
  for (int kk = 0; kk < 2; ++kk) {
    const int kb = kk * 32 + l4 * 8;
    bh8 af[4], bf[4];
#pragma unroll
    for (int m = 0; m < 4; ++m)
      af[m] = *reinterpret_cast<const bh8*>(&qtok[qbase + (size_t)(m * 16 + l15) * 64 + kb]);
#pragma unroll
    for (int j = 0; j < 4; ++j)
      bf[j] = *reinterpret_cast<const bh8*>(&skp[(j * 16 + l15) * LDW + kb]);
#pragma unroll
    for (int m = 0; m < 4; ++m)
#pragma unroll
      for (int j = 0; j < 4; ++j)
        acc[m][j] = __builtin_amdgcn_mfma_f32_16x16x32_bf16(af[m], bf[j], acc[m][j], 0, 0, 0);
  }

  // softmax over p per row (row n = m*16 + l4*4 + r; col p = j*16 + l15)
  fx4 inv[4];
#pragma unroll
  for (int m = 0; m < 4; ++m) {
    fx4 vm = acc[m][0];
#pragma unroll
    for (int j = 1; j < 4; ++j)
#pragma unroll
      for (int r = 0; r < 4; ++r) vm[r] = fmaxf(vm[r], acc[m][j][r]);
#pragma unroll
    for (int msk = 1; msk < 16; msk <<= 1)
#pragma unroll
      for (int r = 0; r < 4; ++r) vm[r] = fmaxf(vm[r], __shfl_xor(vm[r], msk));
    fx4 s = (fx4){0.f, 0.f, 0.f, 0.f};
#pragma unroll
    for (int j = 0; j < 4; ++j)
#pragma unroll
      for (int r = 0; r < 4; ++r) {
        acc[m][j][r] = __expf(acc[m][j][r] - vm[r]);
        s[r] += acc[m][j][r];
      }
#pragma unroll
    for (int msk = 1; msk < 16; msk <<= 1)
#pragma unroll
      for (int r = 0; r < 4; ++r) s[r] += __shfl_xor(s[r], msk);
#pragma unroll
    for (int r = 0; r < 4; ++r) inv[m][r] = 1.f / s[r];
#pragma unroll
    for (int j = 0; j < 4; ++j)
#pragma unroll
      for (int r = 0; r < 4; ++r)
        myp[(m * 16 + l4 * 4 + r) * LDW + j * 16 + l15] = f2bfu(acc[m][j][r]);
  }

  // GEMM2: O[n][d] = P·vpb^T (per-wave private LDS; in-order DS, no barrier)
  fx4 acc2[4][4];
#pragma unroll
  for (int m = 0; m < 4; ++m)
#pragma unroll
    for (int j = 0; j < 4; ++j) acc2[m][j] = (fx4){0.f, 0.f, 0.f, 0.f};
#pragma unroll
  for (int kk = 0; kk < 2; ++kk) {
    const int kb = kk * 32 + l4 * 8;
    bh8 af[4], bf[4];
#pragma unroll
    for (int m = 0; m < 4; ++m)
      af[m] = *reinterpret_cast<const bh8*>(&myp[(m * 16 + l15) * LDW + kb]);
#pragma unroll
    for (int j = 0; j < 4; ++j)
      bf[j] = *reinterpret_cast<const bh8*>(&svp[(j * 16 + l15) * LDW + kb]);
#pragma unroll
    for (int m = 0; m < 4; ++m)
#pragma unroll
      for (int j = 0; j < 4; ++j)
        acc2[m][j] = __builtin_amdgcn_mfma_f32_16x16x32_bf16(af[m], bf[j], acc2[m][j], 0, 0, 0);
  }

  // epilogue: apply 1/sum per row, bf16 -> LDS [n][d] stride 65, store d-major
#pragma unroll
  for (int m = 0; m < 4; ++m)
#pragma unroll
    for (int j = 0; j < 4; ++j)
#pragma unroll
      for (int r = 0; r < 4; ++r)
        myp[(m * 16 + l4 * 4 + r) * 65 + j * 16 + l15] = f2bfu(acc2[m][j][r] * inv[m][r]);
#pragma unroll
  for (int dstep = 0; dstep < 8; ++dstep) {
    const int d = dstep * 8 + (lane >> 3);
    const int nseg = (lane & 7) * 8;
    union { uint4 v; unsigned short u[8]; } pk;
#pragma unroll
    for (int t = 0; t < 8; ++t) pk.u[t] = myp[(nseg + t) * 65 + d];
    *reinterpret_cast<uint4*>(
        &x_sa[((size_t)(b * 64 + d) * 4 + h) * (size_t)N_ + n0 + nseg]) = pk.v;
  }
}

// ---------------------------------------------------------------------------
// MFMA channel-attention apply: x_ca[n][c] = sum_d attn_b[c][d]*vtok[n][d].
// grid = (64 bh, 16), block = 256.
// ---------------------------------------------------------------------------
__global__ __launch_bounds__(256) void xca_mfma(
    const unsigned short* __restrict__ attn_b, const unsigned short* __restrict__ vtok,
    unsigned short* __restrict__ x_ca)
{
  __shared__ unsigned short co[4][64 * LDW];
  const int tid = threadIdx.x;
  const int lane = tid & 63, wid = tid >> 6;
  const int l15 = lane & 15, l4 = lane >> 4;
  const int bh = blockIdx.x, b = bh >> 2, h = bh & 3;
  const int n0 = blockIdx.y * 256 + wid * 64;
  unsigned short* myco = &co[wid][0];

  fx4 acc[4][4];
#pragma unroll
  for (int m = 0; m < 4; ++m)
#pragma unroll
    for (int j = 0; j < 4; ++j) acc[m][j] = (fx4){0.f, 0.f, 0.f, 0.f};
  const size_t abase = (size_t)bh * 4096;
  const size_t vbase = ((size_t)bh * 4096 + n0) * 64;
#pragma unroll
  for (int kk = 0; kk < 2; ++kk) {
    const int kb = kk * 32 + l4 * 8;
    bh8 af[4], bf[4];
#pragma unroll
    for (int m = 0; m < 4; ++m)   // A rows = c
      af[m] = *reinterpret_cast<const bh8*>(&attn_b[abase + (size_t)(m * 16 + l15) * 64 + kb]);
#pragma unroll
    for (int j = 0; j < 4; ++j)   // B rows = n
      bf[j] = *reinterpret_cast<const bh8*>(&vtok[vbase + (size_t)(j * 16 + l15) * 64 + kb]);
#pragma unroll
    for (int m = 0; m < 4; ++m)
#pragma unroll
      for (int j = 0; j < 4; ++j)
        acc[m][j] = __builtin_amdgcn_mfma_f32_16x16x32_bf16(af[m], bf[j], acc[m][j], 0, 0, 0);
  }

  // transpose via per-wave LDS: co[n][c], then coalesced store to x_ca[B,N,C]
#pragma unroll
  for (int m = 0; m < 4; ++m)
#pragma unroll
    for (int j = 0; j < 4; ++j)
#pragma unroll
      for (int r = 0; r < 4; ++r)
        myco[(j * 16 + l15) * LDW + m * 16 + l4 * 4 + r] = f2bfu(acc[m][j][r]);
#pragma unroll
  for (int p = 0; p < 8; ++p) {
    const int nloc = p * 8 + (lane >> 3);
    const int cseg = (lane & 7) * 8;
    const uint4 v = *reinterpret_cast<const uint4*>(&myco[nloc * LDW + cseg]);
    *reinterpret_cast<uint4*>(
        &x_ca[((size_t)b * N_ + n0 + nloc) * 256 + h * 64 + cseg]) = v;
  }
}

extern "C" void kernel_launch(void* const* d_in, const int* in_sizes, int n_in,
                              void* d_out, int out_size, void* d_ws, size_t ws_size,
                              hipStream_t stream)
{
  const float* x     = (const float*)d_in[0];
  const float* ref   = (const float*)d_in[1];
  const float* Wq    = (const float*)d_in[2];
  const float* bq    = (const float*)d_in[3];
  const float* Wkvv  = (const float*)d_in[4];
  const float* bkvv  = (const float*)d_in[5];
  const float* WE    = (const float*)d_in[6];
  const float* bE    = (const float*)d_in[7];
  const float* Wo1   = (const float*)d_in[8];
  const float* bo1   = (const float*)d_in[9];
  const float* Wo2   = (const float*)d_in[10];
  const float* bo2   = (const float*)d_in[11];
  const float* temp  = (const float*)d_in[12];
  const float* temp2 = (const float*)d_in[13];
  float* out = (float*)d_out;

  // ---- workspace plan (total ~237.9 MB; R5-proven budget 264 MB) ----
  char* ws = (char*)d_ws;
  unsigned short* qT      = (unsigned short*)(ws);             // [4096][4096] bf16
  unsigned short* kvv2T   = (unsigned short*)(ws + 33554432);  // [2][4096][4096] bf16 (k, v_sa)
  unsigned short* qtok    = (unsigned short*)(ws + 100663296); // [64bh][4096][64] bf16
  unsigned short* refb    = (unsigned short*)(ws + 134217728); // ref bf16 (dead after proj)
  unsigned short* x_sa    = (unsigned short*)(ws + 134217728); //  -> [B,hd,H,N] bf16
  unsigned short* vca_tok = (unsigned short*)(ws + 167772160); // [64bh][4096][64] bf16
  unsigned short* xb      = (unsigned short*)(ws + 201326592); // x bf16 (dead after proj)
  float*          part    = (float*)(ws + 201326592);          //  -> [8][64][3][64][64] f32 (24 MB)
  unsigned short* x_ca    = (unsigned short*)(ws + 201326592); //  -> [B,N,C] bf16
  float*          partN   = (float*)(ws + 226492416);          // [8][64][2][64] f32 (256 KB)
  unsigned short* Wb      = (unsigned short*)(ws + 234881024); // weights bf16 (655,360 B)
  unsigned short* wEb     = (unsigned short*)(ws + 235536384); // [64][4096] bf16
  unsigned short* attn_b  = (unsigned short*)(ws + 236093440); // [64bh][64c][64d] bf16
  unsigned short* kp2t    = (unsigned short*)(ws + 236617728); // [64bh][64p][64c] bf16
  unsigned short* vpb     = (unsigned short*)(ws + 237142016); // [64bh][64d][64p] bf16

  const dim3 blk(256);
  cast_xref<<<dim3(16384), blk, 0, stream>>>(x, ref, xb, refb);
  cast_w<<<dim3(288), blk, 0, stream>>>(Wq, Wkvv, Wo2, Wo1, WE, Wb, wEb);
  proj_fused<<<dim3(32, 8, 16), blk, 0, stream>>>(xb, refb, Wb, bq, bkvv,
                                                  qT, kvv2T, qtok, vca_tok);
  stats_mfma<<<dim3(64, 8), blk, 0, stream>>>(qT, kvv2T, kvv2T + QSZ, wEb, part, partN);
  postproc_kernel<<<dim3(64), blk, 0, stream>>>(part, partN, bE, temp, temp2,
                                                attn_b, kp2t, vpb);
  sa_mfma<<<dim3(64, 16), blk, 0, stream>>>(qtok, kp2t, vpb, x_sa);
  xca_mfma<<<dim3(64, 16), blk, 0, stream>>>(attn_b, vca_tok, x_ca);
  gemm_outm2<<<dim3(512, 1, 2), blk, 0, stream>>>(x_sa, x_ca, Wb + 262144, bo2, bo1, out);
}